// Round 6
// baseline (1437.540 us; speedup 1.0000x reference)
//
#include <hip/hip_runtime.h>
#include <cstdint>
#include <cstddef>

#define ND 8000
#define NL 16000
#define NE 60000
#define NM 50000

#define BM 64
#define BN 64
#define BK 16

// ---------------- GEMM: C = A[M,K] @ B[K,N] (+bias[n]) (+emb[nid[m],n]) ----------------
// input linears and layer-3 zs projections
__global__ __launch_bounds__(256) void gemm_kernel(
    const float* __restrict__ A, const float* __restrict__ B,
    const float* __restrict__ bias, const float* __restrict__ emb, const int* __restrict__ nid,
    float* __restrict__ Cm, int M, int N, int K)
{
    __shared__ float As[BK][BM + 4];
    __shared__ float Bs[BK][BN + 4];
    const int tid = threadIdx.x;
    const int tx = tid & 15, ty = tid >> 4;
    const int bm = blockIdx.y * BM, bn = blockIdx.x * BN;
    float acc[4][4] = {};
    for (int k0 = 0; k0 < K; k0 += BK) {
#pragma unroll
        for (int i = 0; i < 4; ++i) {
            int idx = tid + i * 256;
            int ml = idx >> 4, kl = idx & 15;
            int gm = bm + ml, gk = k0 + kl;
            As[kl][ml] = (gm < M && gk < K) ? A[(size_t)gm * K + gk] : 0.f;
        }
#pragma unroll
        for (int i = 0; i < 4; ++i) {
            int idx = tid + i * 256;
            int kl = idx >> 6, nl = idx & 63;
            int gk = k0 + kl, gn = bn + nl;
            Bs[kl][nl] = (gk < K && gn < N) ? B[(size_t)gk * N + gn] : 0.f;
        }
        __syncthreads();
#pragma unroll
        for (int k = 0; k < BK; ++k) {
            float4 av = *(const float4*)&As[k][ty * 4];
            float4 bv = *(const float4*)&Bs[k][tx * 4];
            float a4[4] = {av.x, av.y, av.z, av.w};
            float b4[4] = {bv.x, bv.y, bv.z, bv.w};
#pragma unroll
            for (int i = 0; i < 4; ++i)
#pragma unroll
                for (int j = 0; j < 4; ++j)
                    acc[i][j] += a4[i] * b4[j];
        }
        __syncthreads();
    }
#pragma unroll
    for (int i = 0; i < 4; ++i) {
        int gm = bm + ty * 4 + i;
        if (gm >= M) continue;
        int gn0 = bn + tx * 4;
        float4 v;
        float* vp = &v.x;
#pragma unroll
        for (int j = 0; j < 4; ++j) {
            float x = acc[i][j];
            int gn = gn0 + j;
            if (bias) x += bias[gn];
            if (emb) x += emb[(size_t)nid[gm] * N + gn];
            vp[j] = x;
        }
        if (gn0 + 3 < N) *(float4*)&Cm[(size_t)gm * N + gn0] = v;
    }
}

// ---------------- per-head projection GEMM, IN-PLACE, 128-row tile (layers 1-2) -------
// hagg[m, h*128 + c] <- relu( hagg[m, h, :] @ W[:, h*128 + c] + bias[h*128 + c] )
// Block owns full head width (128) for a 128-row m-tile of one head: all K reads are
// barrier-ordered before the in-place stores; blocks disjoint in (m-tile, head).
// grid: (1, ceil(M/128), 16). K fixed at 128. A/out alias intentionally.
__global__ __launch_bounds__(256) void gemm2_kernel(
    float* hagg,                     // [M, 16*128], in/out
    const float* __restrict__ W,     // [128, 2048]
    const float* __restrict__ bias,  // [2048]
    int M)
{
    const int TM = 128;              // rows per block
    const int RM = 16;               // rows per thread
    __shared__ float As[16][TM + 4];
    __shared__ float Bs[16][128 + 4];
    const int tid = threadIdx.x;
    const int tx = tid & 31, ty = tid >> 5;   // 32 x 8
    const int bm = blockIdx.y * TM;
    const int h = blockIdx.z;
    float acc[RM][4] = {};

    for (int k0 = 0; k0 < 128; k0 += 16) {
#pragma unroll
        for (int i = 0; i < 8; ++i) {
            int idx = tid + i * 256;
            int ml = idx >> 4, kl = idx & 15;
            int gm = bm + ml;
            As[kl][ml] = (gm < M) ? hagg[(size_t)gm * 2048 + h * 128 + k0 + kl] : 0.f;
        }
#pragma unroll
        for (int i = 0; i < 8; ++i) {
            int idx = tid + i * 256;
            int kl = idx >> 7, nl = idx & 127;
            Bs[kl][nl] = W[(size_t)(k0 + kl) * 2048 + h * 128 + nl];
        }
        __syncthreads();
#pragma unroll
        for (int k = 0; k < 16; ++k) {
            float a[RM];
#pragma unroll
            for (int i = 0; i < RM; ++i) a[i] = As[k][ty * RM + i];
            float4 bv = *(const float4*)&Bs[k][tx * 4];
            float b4[4] = {bv.x, bv.y, bv.z, bv.w};
#pragma unroll
            for (int i = 0; i < RM; ++i)
#pragma unroll
                for (int j = 0; j < 4; ++j)
                    acc[i][j] += a[i] * b4[j];
        }
        __syncthreads();
    }

#pragma unroll
    for (int i = 0; i < RM; ++i) {
        int gm = bm + ty * RM + i;
        if (gm >= M) continue;
        float4 v;
        float* vp = &v.x;
#pragma unroll
        for (int j = 0; j < 4; ++j)
            vp[j] = fmaxf(acc[i][j] + bias[h * 128 + tx * 4 + j], 0.f);
        *(float4*)&hagg[(size_t)gm * 2048 + h * 128 + tx * 4] = v;
    }
}

// ---------------- stage 3 (layers 1-2): mean over 16 heads, [m][h*128+c] layout -------
__global__ __launch_bounds__(256) void reduce16_kernel(
    const float* __restrict__ z, float* __restrict__ out, int M)
{
    int i4 = blockIdx.x * 256 + threadIdx.x;
    if (i4 >= M * 32) return;
    int m = i4 >> 5, c4 = i4 & 31;
    const float4* zp = (const float4*)(z + (size_t)m * 2048) + c4;
    float4 s = make_float4(0.f, 0.f, 0.f, 0.f);
#pragma unroll
    for (int h = 0; h < 16; ++h) {
        float4 v = zp[h * 32];
        s.x += v.x; s.y += v.y; s.z += v.z; s.w += v.w;
    }
    s.x *= (1.f / 16.f); s.y *= (1.f / 16.f); s.z *= (1.f / 16.f); s.w *= (1.f / 16.f);
    ((float4*)out)[i4] = s;
}

// ---------------- fold for ALL 3 layers: fw3[l][f][k][h] = sum_c W[k,h*C+c]*a[h,c] ----
__global__ void fold3_kernel(
    const float* __restrict__ Ws1, const float* __restrict__ Wd1,
    const float* __restrict__ as1, const float* __restrict__ ad1,
    const float* __restrict__ Ws2, const float* __restrict__ Wd2,
    const float* __restrict__ as2, const float* __restrict__ ad2,
    const float* __restrict__ Ws3, const float* __restrict__ Wd3,
    const float* __restrict__ as3, const float* __restrict__ ad3,
    float* __restrict__ fw3)
{
    int gid = blockIdx.x * blockDim.x + threadIdx.x;
    if (gid >= 3 * 4 * 128 * 16) return;
    int l = gid / 8192, rem1 = gid % 8192;
    int f = rem1 / 2048, rem = rem1 % 2048;
    int k = rem >> 4, h = rem & 15;
    int Ntot = (l == 2) ? 512 : 2048;
    int C = Ntot >> 4;
    const float* W;
    const float* a;
    if (l == 0) { W = (f & 1) ? Wd1 : Ws1; a = (f & 1) ? ad1 : as1; }
    else if (l == 1) { W = (f & 1) ? Wd2 : Ws2; a = (f & 1) ? ad2 : as2; }
    else { W = (f & 1) ? Wd3 : Ws3; a = (f & 1) ? ad3 : as3; }
    if (f >= 2) { W += 128 * Ntot; a += 16 * C; }
    float s = 0.f;
    for (int c = 0; c < C; ++c) s += W[(size_t)k * Ntot + h * C + c] * a[h * C + c];
    fw3[gid] = s;
}

// ---------------- score2: two folded projections of the same H in one pass ----------------
// NOTE: fold layout here is fw[f][k][h]; f pairs are (src=f*2+0? no) -- caller passes slices.
__global__ __launch_bounds__(256) void score2_kernel(
    const float* __restrict__ Hf, const float* __restrict__ WfA, const float* __restrict__ WfB,
    float* __restrict__ outA, float* __restrict__ outB, int n)
{
    __shared__ float hs[16 * 128];
    __shared__ float wa[128 * 16];
    __shared__ float wb[128 * 16];
    int tid = threadIdx.x;
    int n0 = blockIdx.x * 16;
#pragma unroll
    for (int i = 0; i < 8; ++i) {
        int idx = tid + i * 256;
        int nl = idx >> 7, k = idx & 127;
        int gn = n0 + nl;
        hs[idx] = (gn < n) ? Hf[(size_t)gn * 128 + k] : 0.f;
        wa[idx] = WfA[idx];
        wb[idx] = WfB[idx];
    }
    __syncthreads();
    int nl = tid >> 4, h = tid & 15;
    float sa = 0.f, sb = 0.f;
    for (int k = 0; k < 128; ++k) {
        float hv = hs[nl * 128 + k];
        sa += hv * wa[k * 16 + h];
        sb += hv * wb[k * 16 + h];
    }
    int gn = n0 + nl;
    if (gn < n) { outA[gn * 16 + h] = sa; outB[gn * 16 + h] = sb; }
}

// ---------------- CSR build ----------------
__global__ void hist_kernel(const int* __restrict__ esrc, const int* __restrict__ edst,
                            int* __restrict__ degl, int* __restrict__ degd)
{
    int e = blockIdx.x * blockDim.x + threadIdx.x;
    if (e >= NE) return;
    atomicAdd(&degl[edst[e]], 1);
    atomicAdd(&degd[esrc[e]], 1);
}

// block 0: (degA,offA,nA); block 1: (degB,offB,nB)
__global__ __launch_bounds__(1024) void scan2_kernel(
    const int* __restrict__ degA, int* __restrict__ offA, int nA,
    const int* __restrict__ degB, int* __restrict__ offB, int nB)
{
    __shared__ int ps[1024];
    const int* deg = blockIdx.x ? degB : degA;
    int* off = blockIdx.x ? offB : offA;
    int n = blockIdx.x ? nB : nA;
    int tid = threadIdx.x;
    int chunk = (n + 1023) >> 10;
    int start = tid * chunk, end = min(start + chunk, n);
    int p = 0;
    for (int i = start; i < end; ++i) p += deg[i];
    ps[tid] = p;
    __syncthreads();
    for (int o = 1; o < 1024; o <<= 1) {
        int v = (tid >= o) ? ps[tid - o] : 0;
        __syncthreads();
        ps[tid] += v;
        __syncthreads();
    }
    int run = ps[tid] - p;
    for (int i = start; i < end; ++i) { off[i] = run; run += deg[i]; }
    if (tid == 1023) off[n] = ps[1023];
}

__global__ void scatter_kernel(const int* __restrict__ esrc, const int* __restrict__ edst,
                               const int* __restrict__ offl, const int* __restrict__ offd,
                               int* __restrict__ curl, int* __restrict__ curd,
                               int* __restrict__ csrl, int* __restrict__ csrd)
{
    int e = blockIdx.x * blockDim.x + threadIdx.x;
    if (e >= NE) return;
    int dl = edst[e]; int p = atomicAdd(&curl[dl], 1); csrl[offl[dl] + p] = e;
    int dd = esrc[e]; int q = atomicAdd(&curd[dd], 1); csrd[offd[dd] + q] = e;
}

// ---------------- fused softmax + per-head aggregation of raw src features (L1-2) ------
// hagg[d, h, k] = sum_{e: dst(e)=d} alpha[e,h] * h_src[src(e), k]
__global__ __launch_bounds__(256) void hagg_kernel(
    const float* __restrict__ hsrc,  // [n_src, 128]
    const float* __restrict__ ss,    // [n_src, 16]
    const float* __restrict__ sd,    // [n_dst, 16]
    const int* __restrict__ off, const int* __restrict__ csr, const int* __restrict__ srcidx,
    float* __restrict__ hagg)        // [n_dst, 16, 128]
{
    __shared__ float m_s[16], s_s[16];
    __shared__ float alpha_s[16][17];
    __shared__ int src_s[16];
    const int d = blockIdx.x;
    const int tid = threadIdx.x;
    const int e0 = off[d], e1 = off[d + 1];

    if (tid < 16) {
        int h = tid;
        float sdv = sd[d * 16 + h];
        float m = -1e30f;
        for (int e = e0; e < e1; ++e) {
            int sn = srcidx[csr[e]];
            float al = ss[sn * 16 + h] + sdv;
            al = al >= 0.f ? al : 0.2f * al;
            m = fmaxf(m, al);
        }
        float s = 0.f;
        for (int e = e0; e < e1; ++e) {
            int sn = srcidx[csr[e]];
            float al = ss[sn * 16 + h] + sdv;
            al = al >= 0.f ? al : 0.2f * al;
            s += expf(al - m);
        }
        m_s[h] = m;
        s_s[h] = s + 1e-16f;
    }
    __syncthreads();

    float acc[8] = {};
    const int c = tid & 127;
    const int hbase = (tid >> 7) * 8;

    for (int ce = e0; ce < e1; ce += 16) {
        int nc = min(16, e1 - ce);
        if (tid < nc * 16) {
            int ei = tid >> 4, h = tid & 15;
            int sn = srcidx[csr[ce + ei]];
            float al = ss[sn * 16 + h] + sd[d * 16 + h];
            al = al >= 0.f ? al : 0.2f * al;
            alpha_s[ei][h] = expf(al - m_s[h]) / s_s[h];
            if (h == 0) src_s[ei] = sn;
        }
        __syncthreads();
        for (int ei = 0; ei < nc; ++ei) {
            float v = hsrc[(size_t)src_s[ei] * 128 + c];
#pragma unroll
            for (int hh = 0; hh < 8; ++hh)
                acc[hh] += alpha_s[ei][hbase + hh] * v;
        }
        __syncthreads();
    }

#pragma unroll
    for (int hh = 0; hh < 8; ++hh)
        hagg[(size_t)d * 2048 + (size_t)(hbase + hh) * 128 + c] = acc[hh];
}

// ---------------- layer 3: fused softmax + gather(zs) + bias + relu + head-mean + penalty
// zs: [n_src, 512] pre-projected. Writes out[d, 32] = penalty( mean_h relu(agg + bias) ).
__global__ __launch_bounds__(256) void agg32_kernel(
    const float* __restrict__ zs,    // [n_src, 512]
    const float* __restrict__ ss, const float* __restrict__ sd,
    const int* __restrict__ off, const int* __restrict__ csr, const int* __restrict__ srcidx,
    const float* __restrict__ bias,  // [512]
    const float* __restrict__ pwt, const float* __restrict__ pbt,  // [32], [1]
    float* __restrict__ out)         // [n_dst, 32]
{
    __shared__ float m_s[16], s_s[16];
    __shared__ float alpha_s[16][17];
    __shared__ int src_s[16];
    __shared__ float lds_out[512];
    __shared__ float hrow[32];
    const int d = blockIdx.x;
    const int tid = threadIdx.x;
    const int e0 = off[d], e1 = off[d + 1];

    if (tid < 16) {
        int h = tid;
        float sdv = sd[d * 16 + h];
        float m = -1e30f;
        for (int e = e0; e < e1; ++e) {
            int sn = srcidx[csr[e]];
            float al = ss[sn * 16 + h] + sdv;
            al = al >= 0.f ? al : 0.2f * al;
            m = fmaxf(m, al);
        }
        float s = 0.f;
        for (int e = e0; e < e1; ++e) {
            int sn = srcidx[csr[e]];
            float al = ss[sn * 16 + h] + sdv;
            al = al >= 0.f ? al : 0.2f * al;
            s += expf(al - m);
        }
        m_s[h] = m;
        s_s[h] = s + 1e-16f;
    }
    __syncthreads();

    float acc0 = 0.f, acc1 = 0.f;
    const int hsel = tid >> 4;  // head of channels (2*tid, 2*tid+1)

    for (int ce = e0; ce < e1; ce += 16) {
        int nc = min(16, e1 - ce);
        if (tid < nc * 16) {
            int ei = tid >> 4, h = tid & 15;
            int sn = srcidx[csr[ce + ei]];
            float al = ss[sn * 16 + h] + sd[d * 16 + h];
            al = al >= 0.f ? al : 0.2f * al;
            alpha_s[ei][h] = expf(al - m_s[h]) / s_s[h];
            if (h == 0) src_s[ei] = sn;
        }
        __syncthreads();
        for (int ei = 0; ei < nc; ++ei) {
            float a = alpha_s[ei][hsel];
            float2 v = *(const float2*)(zs + (size_t)src_s[ei] * 512 + tid * 2);
            acc0 += a * v.x;
            acc1 += a * v.y;
        }
        __syncthreads();
    }

    lds_out[tid * 2] = fmaxf(acc0 + bias[tid * 2], 0.f);
    lds_out[tid * 2 + 1] = fmaxf(acc1 + bias[tid * 2 + 1], 0.f);
    __syncthreads();
    if (tid < 32) {
        float s = 0.f;
#pragma unroll
        for (int hh = 0; hh < 16; ++hh) s += lds_out[hh * 32 + tid];
        hrow[tid] = s * (1.f / 16.f);
    }
    __syncthreads();
    if (tid < 32) {
        float t = pbt[0];
#pragma unroll
        for (int c = 0; c < 32; ++c) t += hrow[c] * pwt[c];
        out[(size_t)d * 32 + tid] = hrow[tid] * expf(t);
    }
}

// ---------------- final MLP on label edges ----------------
__global__ __launch_bounds__(256) void mlp_kernel(
    const float* __restrict__ hd, const float* __restrict__ hl,
    const int* __restrict__ ls, const int* __restrict__ ld,
    const float* __restrict__ w1, const float* __restrict__ b1,
    const float* __restrict__ w2, const float* __restrict__ b2,
    float* __restrict__ out, int M)
{
    __shared__ float w1s[64 * 64];
    __shared__ float b1s[64];
    __shared__ float w2s[64];
    int tid = threadIdx.x;
#pragma unroll
    for (int i = 0; i < 16; ++i) w1s[tid + i * 256] = w1[tid + i * 256];
    if (tid < 64) { b1s[tid] = b1[tid]; w2s[tid] = w2[tid]; }
    __syncthreads();
    int m = blockIdx.x * 256 + tid;
    if (m >= M) return;
    float f[64];
    const float* hp = hd + (size_t)ls[m] * 32;
    const float* lp = hl + (size_t)ld[m] * 32;
#pragma unroll
    for (int c = 0; c < 32; ++c) { f[c] = hp[c]; f[32 + c] = lp[c]; }
    float o = b2[0];
    for (int j = 0; j < 64; ++j) {
        float hj = b1s[j];
#pragma unroll
        for (int k = 0; k < 64; ++k) hj += f[k] * w1s[k * 64 + j];
        hj = fmaxf(hj, 0.f);
        o += hj * w2s[j];
    }
    out[m] = o;
}

extern "C" void kernel_launch(void* const* d_in, const int* in_sizes, int n_in,
                              void* d_out, int out_size, void* d_ws, size_t ws_size,
                              hipStream_t stream)
{
    const float* x_d = (const float*)d_in[0];
    const float* x_l = (const float*)d_in[1];
    const int* node_id_d = (const int*)d_in[2];
    const int* node_id_l = (const int*)d_in[3];
    const int* edge_src = (const int*)d_in[4];
    const int* edge_dst = (const int*)d_in[5];
    const int* label_src = (const int*)d_in[6];
    const int* label_dst = (const int*)d_in[7];
    const float* emb_d = (const float*)d_in[8];
    const float* emb_l = (const float*)d_in[9];
    const float* lin_dw = (const float*)d_in[10];
    const float* lin_db = (const float*)d_in[11];
    const float* lin_lw = (const float*)d_in[12];
    const float* lin_lb = (const float*)d_in[13];
    const float* Ws[3] = {(const float*)d_in[14], (const float*)d_in[19], (const float*)d_in[24]};
    const float* Wd[3] = {(const float*)d_in[15], (const float*)d_in[20], (const float*)d_in[25]};
    const float* as_[3] = {(const float*)d_in[16], (const float*)d_in[21], (const float*)d_in[26]};
    const float* ad_[3] = {(const float*)d_in[17], (const float*)d_in[22], (const float*)d_in[27]};
    const float* bb[3] = {(const float*)d_in[18], (const float*)d_in[23], (const float*)d_in[28]};
    const float* pw = (const float*)d_in[29];
    const float* pb = (const float*)d_in[30];
    const float* fc1w = (const float*)d_in[31];
    const float* fc1b = (const float*)d_in[32];
    const float* fc2w = (const float*)d_in[33];
    const float* fc2b = (const float*)d_in[34];

    char* wsb = (char*)d_ws;
    size_t woff = 0;
    auto carve = [&](size_t bytes) -> void* {
        woff = (woff + 255) & ~(size_t)255;
        void* p = wsb + woff;
        woff += bytes;
        return p;
    };
    float* hdA = (float*)carve((size_t)ND * 128 * 4);
    float* hdB = (float*)carve((size_t)ND * 128 * 4);
    float* hlA = (float*)carve((size_t)NL * 128 * 4);
    float* hlB = (float*)carve((size_t)NL * 128 * 4);
    float* hagg = (float*)carve((size_t)NL * 2048 * 4);   // also reused as zs [*,512] in L3
    float* ssb0 = (float*)carve((size_t)ND * 16 * 4);
    float* sdb0 = (float*)carve((size_t)NL * 16 * 4);
    float* ssb1 = (float*)carve((size_t)NL * 16 * 4);
    float* sdb1 = (float*)carve((size_t)ND * 16 * 4);
    float* fw3 = (float*)carve((size_t)3 * 4 * 2048 * 4);
    // deg/cur contiguous for a single memset
    int* degl = (int*)carve((size_t)(2 * (NL + ND)) * 4);
    int* degd = degl + NL;
    int* curl = degd + ND;
    int* curd = curl + NL;
    int* offl = (int*)carve((size_t)(NL + 1) * 4);
    int* offd = (int*)carve((size_t)(ND + 1) * 4);
    int* csrl = (int*)carve((size_t)NE * 4);
    int* csrd = (int*)carve((size_t)NE * 4);
    float* hdp = (float*)carve((size_t)ND * 32 * 4);
    float* hlp = (float*)carve((size_t)NL * 32 * 4);

    hipMemsetAsync(degl, 0, (size_t)2 * (NL + ND) * 4, stream);

    hist_kernel<<<(NE + 255) / 256, 256, 0, stream>>>(edge_src, edge_dst, degl, degd);
    scan2_kernel<<<2, 1024, 0, stream>>>(degl, offl, NL, degd, offd, ND);
    scatter_kernel<<<(NE + 255) / 256, 256, 0, stream>>>(edge_src, edge_dst, offl, offd, curl, curd, csrl, csrd);

    fold3_kernel<<<(3 * 8192 + 255) / 256, 256, 0, stream>>>(
        Ws[0], Wd[0], as_[0], ad_[0], Ws[1], Wd[1], as_[1], ad_[1],
        Ws[2], Wd[2], as_[2], ad_[2], fw3);

    // input linears + embedding add
    gemm_kernel<<<dim3(128 / BN, ND / BM), 256, 0, stream>>>(x_d, lin_dw, lin_db, emb_d, node_id_d, hdA, ND, 128, 412);
    gemm_kernel<<<dim3(128 / BN, NL / BM), 256, 0, stream>>>(x_l, lin_lw, lin_lb, emb_l, node_id_l, hlA, NL, 128, 240);

    float* hd_cur = hdA; float* hd_nxt = hdB;
    float* hl_cur = hlA; float* hl_nxt = hlB;

    // ---- layers 1-2: aggregate-then-project ----
    for (int L = 0; L < 2; ++L) {
        const float* fw = fw3 + (size_t)L * 8192;
        // scores: hd needs fold0 (src type0) + fold3 (dst type1); hl needs fold1 (dst type0) + fold2 (src type1)
        score2_kernel<<<ND / 16, 256, 0, stream>>>(hd_cur, fw + 0 * 2048, fw + 3 * 2048, ssb0, sdb1, ND);
        score2_kernel<<<NL / 16, 256, 0, stream>>>(hl_cur, fw + 1 * 2048, fw + 2 * 2048, sdb0, ssb1, NL);

        // edge type 0: disease -> lncrna (dst = lncrna)
        hagg_kernel<<<NL, 256, 0, stream>>>(hd_cur, ssb0, sdb0, offl, csrl, edge_src, hagg);
        gemm2_kernel<<<dim3(1, NL / 128, 16), 256, 0, stream>>>(hagg, Ws[L], bb[L], NL);
        reduce16_kernel<<<(NL * 32 + 255) / 256, 256, 0, stream>>>(hagg, hl_nxt, NL);

        // edge type 1: lncrna -> disease (dst = disease)
        hagg_kernel<<<ND, 256, 0, stream>>>(hl_cur, ssb1, sdb1, offd, csrd, edge_dst, hagg);
        gemm2_kernel<<<dim3(1, (ND + 127) / 128, 16), 256, 0, stream>>>(hagg, Ws[L] + 128 * 2048, bb[L] + 2048, ND);
        reduce16_kernel<<<(ND * 32 + 255) / 256, 256, 0, stream>>>(hagg, hd_nxt, ND);

        float* t;
        t = hd_cur; hd_cur = hd_nxt; hd_nxt = t;
        t = hl_cur; hl_cur = hl_nxt; hl_nxt = t;
    }

    // ---- layer 3: project-then-aggregate, fused epilogue incl. penalty ----
    {
        const float* fw = fw3 + 2 * 8192;
        score2_kernel<<<ND / 16, 256, 0, stream>>>(hd_cur, fw + 0 * 2048, fw + 3 * 2048, ssb0, sdb1, ND);
        score2_kernel<<<NL / 16, 256, 0, stream>>>(hl_cur, fw + 1 * 2048, fw + 2 * 2048, sdb0, ssb1, NL);

        // edge type 0: zs = hd @ Ws3[0]  [ND, 512]; dst = lncrna -> hlp (penalty: lncrna pw[1],pb[1])
        gemm_kernel<<<dim3(512 / BN, ND / BM), 256, 0, stream>>>(hd_cur, Ws[2], nullptr, nullptr, nullptr, hagg, ND, 512, 128);
        agg32_kernel<<<NL, 256, 0, stream>>>(hagg, ssb0, sdb0, offl, csrl, edge_src,
                                             bb[2], pw + 32, pb + 1, hlp);

        // edge type 1: zs = hl @ Ws3[1]  [NL, 512]; dst = disease -> hdp (penalty: disease pw[0],pb[0])
        gemm_kernel<<<dim3(512 / BN, NL / BM), 256, 0, stream>>>(hl_cur, Ws[2] + 128 * 512, nullptr, nullptr, nullptr, hagg, NL, 512, 128);
        agg32_kernel<<<ND, 256, 0, stream>>>(hagg, ssb1, sdb1, offd, csrd, edge_dst,
                                             bb[2] + 512, pw, pb, hdp);
    }

    mlp_kernel<<<(NM + 255) / 256, 256, 0, stream>>>(hdp, hlp, label_src, label_dst,
                                                     fc1w, fc1b, fc2w, fc2b, (float*)d_out, NM);
}

// Round 7
// 1390.388 us; speedup vs baseline: 1.0339x; 1.0339x over previous
//
#include <hip/hip_runtime.h>
#include <cstdint>
#include <cstddef>

#define ND 8000
#define NL 16000
#define NE 60000
#define NM 50000

#define BM 64
#define BN 64
#define BK 16

typedef __attribute__((ext_vector_type(8))) short bf16x8;
typedef __attribute__((ext_vector_type(4))) float f32x4;

__device__ __forceinline__ unsigned short f2bf(float x) {
    unsigned int u = __float_as_uint(x);
    unsigned int r = (u + 0x7FFFu + ((u >> 16) & 1u)) >> 16;
    return (unsigned short)r;
}
__device__ __forceinline__ float bf2f(unsigned short b) {
    return __uint_as_float(((unsigned int)b) << 16);
}

// ---------------- GEMM: C = A[M,K] @ B[K,N] (+bias[n]) (+emb[nid[m],n]) ----------------
// input linears and layer-3 zs projections
__global__ __launch_bounds__(256) void gemm_kernel(
    const float* __restrict__ A, const float* __restrict__ B,
    const float* __restrict__ bias, const float* __restrict__ emb, const int* __restrict__ nid,
    float* __restrict__ Cm, int M, int N, int K)
{
    __shared__ float As[BK][BM + 4];
    __shared__ float Bs[BK][BN + 4];
    const int tid = threadIdx.x;
    const int tx = tid & 15, ty = tid >> 4;
    const int bm = blockIdx.y * BM, bn = blockIdx.x * BN;
    float acc[4][4] = {};
    for (int k0 = 0; k0 < K; k0 += BK) {
#pragma unroll
        for (int i = 0; i < 4; ++i) {
            int idx = tid + i * 256;
            int ml = idx >> 4, kl = idx & 15;
            int gm = bm + ml, gk = k0 + kl;
            As[kl][ml] = (gm < M && gk < K) ? A[(size_t)gm * K + gk] : 0.f;
        }
#pragma unroll
        for (int i = 0; i < 4; ++i) {
            int idx = tid + i * 256;
            int kl = idx >> 6, nl = idx & 63;
            int gk = k0 + kl, gn = bn + nl;
            Bs[kl][nl] = (gk < K && gn < N) ? B[(size_t)gk * N + gn] : 0.f;
        }
        __syncthreads();
#pragma unroll
        for (int k = 0; k < BK; ++k) {
            float4 av = *(const float4*)&As[k][ty * 4];
            float4 bv = *(const float4*)&Bs[k][tx * 4];
            float a4[4] = {av.x, av.y, av.z, av.w};
            float b4[4] = {bv.x, bv.y, bv.z, bv.w};
#pragma unroll
            for (int i = 0; i < 4; ++i)
#pragma unroll
                for (int j = 0; j < 4; ++j)
                    acc[i][j] += a4[i] * b4[j];
        }
        __syncthreads();
    }
#pragma unroll
    for (int i = 0; i < 4; ++i) {
        int gm = bm + ty * 4 + i;
        if (gm >= M) continue;
        int gn0 = bn + tx * 4;
        float4 v;
        float* vp = &v.x;
#pragma unroll
        for (int j = 0; j < 4; ++j) {
            float x = acc[i][j];
            int gn = gn0 + j;
            if (bias) x += bias[gn];
            if (emb) x += emb[(size_t)nid[gm] * N + gn];
            vp[j] = x;
        }
        if (gn0 + 3 < N) *(float4*)&Cm[(size_t)gm * N + gn0] = v;
    }
}

// ---------------- W transpose + split-bf16 (per layer, both directions) ----------------
// W [2,128,2048] fp32 -> WtH/WtL [2][2048 n][128 k] bf16
__global__ void wt_kernel(const float* __restrict__ W,
                          unsigned short* __restrict__ WtH, unsigned short* __restrict__ WtL)
{
    int gid = blockIdx.x * 256 + threadIdx.x;
    if (gid >= 2 * 128 * 2048) return;
    int dir = gid >> 18;
    int rem = gid & 262143;
    int k = rem >> 11, n = rem & 2047;   // n fast -> coalesced read
    float v = W[(size_t)dir * 262144 + (size_t)k * 2048 + n];
    unsigned short hb = f2bf(v);
    unsigned short lb = f2bf(v - bf2f(hb));
    size_t o = (size_t)dir * 262144 + (size_t)n * 128 + k;
    WtH[o] = hb;
    WtL[o] = lb;
}

// ---------------- per-head projection via split-bf16 MFMA, IN-PLACE (layers 1-2) ------
// z[m, h*128+c] = relu( hagg[m,h,:] @ W[:, h*128+c] + bias[h*128+c] ), stored as hi/lo bf16
// A = haggH/L [M, 2048] (k-contiguous per head). B = WtH/L [2048 n][128 k].
// grid (M/64, 16); 4 waves, wave w owns rows bm + w*16 .. +15 of head blockIdx.y.
// In-place safe: each wave reads exactly the slice it writes; MFMA data-dep orders loads
// before the epilogue stores; waves/blocks disjoint in (rows, head).
__global__ __launch_bounds__(256) void gemm2_mfma_kernel(
    unsigned short* haggH, unsigned short* haggL,            // [M, 2048], in/out (aliased)
    const unsigned short* __restrict__ WtH, const unsigned short* __restrict__ WtL,
    const float* __restrict__ bias, int M)
{
    const int wave = threadIdx.x >> 6;
    const int lane = threadIdx.x & 63;
    const int h = blockIdx.y;
    const int m0 = blockIdx.x * 64 + wave * 16;
    const int row = lane & 15;     // A: m-offset; B: n-offset; D: col
    const int quad = lane >> 4;    // k chunk /8; D: row = quad*4 + r

    const size_t abase = (size_t)(m0 + row) * 2048 + h * 128 + quad * 8;
    const size_t bbase = ((size_t)(h * 128 + row)) * 128 + quad * 8;

    f32x4 acc[8];
#pragma unroll
    for (int ct = 0; ct < 8; ++ct) {
        float bv = bias[h * 128 + ct * 16 + row];
        acc[ct] = (f32x4){bv, bv, bv, bv};
    }

#pragma unroll
    for (int kc = 0; kc < 4; ++kc) {
        bf16x8 aH = *(const bf16x8*)(haggH + abase + kc * 32);
        bf16x8 aL = *(const bf16x8*)(haggL + abase + kc * 32);
#pragma unroll
        for (int ct = 0; ct < 8; ++ct) {
            bf16x8 bH = *(const bf16x8*)(WtH + bbase + (size_t)ct * 2048 + kc * 32);
            bf16x8 bL = *(const bf16x8*)(WtL + bbase + (size_t)ct * 2048 + kc * 32);
            acc[ct] = __builtin_amdgcn_mfma_f32_16x16x32_bf16(aH, bH, acc[ct], 0, 0, 0);
            acc[ct] = __builtin_amdgcn_mfma_f32_16x16x32_bf16(aH, bL, acc[ct], 0, 0, 0);
            acc[ct] = __builtin_amdgcn_mfma_f32_16x16x32_bf16(aL, bH, acc[ct], 0, 0, 0);
        }
    }

#pragma unroll
    for (int ct = 0; ct < 8; ++ct) {
        int col = h * 128 + ct * 16 + row;
#pragma unroll
        for (int r = 0; r < 4; ++r) {
            int gm = m0 + quad * 4 + r;
            float v = fmaxf(acc[ct][r], 0.f);
            unsigned short hb = f2bf(v);
            unsigned short lb = f2bf(v - bf2f(hb));
            size_t idx = (size_t)gm * 2048 + col;
            haggH[idx] = hb;
            haggL[idx] = lb;
        }
    }
}

// ---------------- stage 3 (layers 1-2): mean over 16 heads from hi/lo pairs ----------
__global__ __launch_bounds__(256) void reduce16_kernel(
    const unsigned short* __restrict__ zH, const unsigned short* __restrict__ zL,
    float* __restrict__ out, int M)
{
    int i4 = blockIdx.x * 256 + threadIdx.x;
    if (i4 >= M * 32) return;
    int m = i4 >> 5, c4 = i4 & 31;
    size_t base = (size_t)m * 2048 + c4 * 4;
    float4 s = make_float4(0.f, 0.f, 0.f, 0.f);
#pragma unroll
    for (int h = 0; h < 16; ++h) {
        ushort4 vh = *(const ushort4*)(zH + base + h * 128);
        ushort4 vl = *(const ushort4*)(zL + base + h * 128);
        s.x += bf2f(vh.x) + bf2f(vl.x);
        s.y += bf2f(vh.y) + bf2f(vl.y);
        s.z += bf2f(vh.z) + bf2f(vl.z);
        s.w += bf2f(vh.w) + bf2f(vl.w);
    }
    s.x *= (1.f / 16.f); s.y *= (1.f / 16.f); s.z *= (1.f / 16.f); s.w *= (1.f / 16.f);
    ((float4*)out)[i4] = s;
}

// ---------------- fold for ALL 3 layers: fw3[l][f][k][h] = sum_c W[k,h*C+c]*a[h,c] ----
__global__ void fold3_kernel(
    const float* __restrict__ Ws1, const float* __restrict__ Wd1,
    const float* __restrict__ as1, const float* __restrict__ ad1,
    const float* __restrict__ Ws2, const float* __restrict__ Wd2,
    const float* __restrict__ as2, const float* __restrict__ ad2,
    const float* __restrict__ Ws3, const float* __restrict__ Wd3,
    const float* __restrict__ as3, const float* __restrict__ ad3,
    float* __restrict__ fw3)
{
    int gid = blockIdx.x * blockDim.x + threadIdx.x;
    if (gid >= 3 * 4 * 128 * 16) return;
    int l = gid / 8192, rem1 = gid % 8192;
    int f = rem1 / 2048, rem = rem1 % 2048;
    int k = rem >> 4, h = rem & 15;
    int Ntot = (l == 2) ? 512 : 2048;
    int C = Ntot >> 4;
    const float* W;
    const float* a;
    if (l == 0) { W = (f & 1) ? Wd1 : Ws1; a = (f & 1) ? ad1 : as1; }
    else if (l == 1) { W = (f & 1) ? Wd2 : Ws2; a = (f & 1) ? ad2 : as2; }
    else { W = (f & 1) ? Wd3 : Ws3; a = (f & 1) ? ad3 : as3; }
    if (f >= 2) { W += 128 * Ntot; a += 16 * C; }
    float s = 0.f;
    for (int c = 0; c < C; ++c) s += W[(size_t)k * Ntot + h * C + c] * a[h * C + c];
    fw3[gid] = s;
}

// ---------------- score2: two folded projections of the same H in one pass ------------
__global__ __launch_bounds__(256) void score2_kernel(
    const float* __restrict__ Hf, const float* __restrict__ WfA, const float* __restrict__ WfB,
    float* __restrict__ outA, float* __restrict__ outB, int n)
{
    __shared__ float hs[16 * 128];
    __shared__ float wa[128 * 16];
    __shared__ float wb[128 * 16];
    int tid = threadIdx.x;
    int n0 = blockIdx.x * 16;
#pragma unroll
    for (int i = 0; i < 8; ++i) {
        int idx = tid + i * 256;
        int nl = idx >> 7, k = idx & 127;
        int gn = n0 + nl;
        hs[idx] = (gn < n) ? Hf[(size_t)gn * 128 + k] : 0.f;
        wa[idx] = WfA[idx];
        wb[idx] = WfB[idx];
    }
    __syncthreads();
    int nl = tid >> 4, h = tid & 15;
    float sa = 0.f, sb = 0.f;
    for (int k = 0; k < 128; ++k) {
        float hv = hs[nl * 128 + k];
        sa += hv * wa[k * 16 + h];
        sb += hv * wb[k * 16 + h];
    }
    int gn = n0 + nl;
    if (gn < n) { outA[gn * 16 + h] = sa; outB[gn * 16 + h] = sb; }
}

// ---------------- CSR build ----------------
__global__ void hist_kernel(const int* __restrict__ esrc, const int* __restrict__ edst,
                            int* __restrict__ degl, int* __restrict__ degd)
{
    int e = blockIdx.x * blockDim.x + threadIdx.x;
    if (e >= NE) return;
    atomicAdd(&degl[edst[e]], 1);
    atomicAdd(&degd[esrc[e]], 1);
}

__global__ __launch_bounds__(1024) void scan2_kernel(
    const int* __restrict__ degA, int* __restrict__ offA, int nA,
    const int* __restrict__ degB, int* __restrict__ offB, int nB)
{
    __shared__ int ps[1024];
    const int* deg = blockIdx.x ? degB : degA;
    int* off = blockIdx.x ? offB : offA;
    int n = blockIdx.x ? nB : nA;
    int tid = threadIdx.x;
    int chunk = (n + 1023) >> 10;
    int start = tid * chunk, end = min(start + chunk, n);
    int p = 0;
    for (int i = start; i < end; ++i) p += deg[i];
    ps[tid] = p;
    __syncthreads();
    for (int o = 1; o < 1024; o <<= 1) {
        int v = (tid >= o) ? ps[tid - o] : 0;
        __syncthreads();
        ps[tid] += v;
        __syncthreads();
    }
    int run = ps[tid] - p;
    for (int i = start; i < end; ++i) { off[i] = run; run += deg[i]; }
    if (tid == 1023) off[n] = ps[1023];
}

__global__ void scatter_kernel(const int* __restrict__ esrc, const int* __restrict__ edst,
                               const int* __restrict__ offl, const int* __restrict__ offd,
                               int* __restrict__ curl, int* __restrict__ curd,
                               int* __restrict__ csrl, int* __restrict__ csrd)
{
    int e = blockIdx.x * blockDim.x + threadIdx.x;
    if (e >= NE) return;
    int dl = edst[e]; int p = atomicAdd(&curl[dl], 1); csrl[offl[dl] + p] = e;
    int dd = esrc[e]; int q = atomicAdd(&curd[dd], 1); csrd[offd[dd] + q] = e;
}

// ---------------- fused softmax + per-head aggregation -> split-bf16 hagg (L1-2) -------
__global__ __launch_bounds__(256) void hagg_kernel(
    const float* __restrict__ hsrc,  // [n_src, 128]
    const float* __restrict__ ss,    // [n_src, 16]
    const float* __restrict__ sd,    // [n_dst, 16]
    const int* __restrict__ off, const int* __restrict__ csr, const int* __restrict__ srcidx,
    unsigned short* __restrict__ haggH, unsigned short* __restrict__ haggL)  // [n_dst, 2048]
{
    __shared__ float m_s[16], s_s[16];
    __shared__ float alpha_s[16][17];
    __shared__ int src_s[16];
    const int d = blockIdx.x;
    const int tid = threadIdx.x;
    const int e0 = off[d], e1 = off[d + 1];

    if (tid < 16) {
        int h = tid;
        float sdv = sd[d * 16 + h];
        float m = -1e30f;
        for (int e = e0; e < e1; ++e) {
            int sn = srcidx[csr[e]];
            float al = ss[sn * 16 + h] + sdv;
            al = al >= 0.f ? al : 0.2f * al;
            m = fmaxf(m, al);
        }
        float s = 0.f;
        for (int e = e0; e < e1; ++e) {
            int sn = srcidx[csr[e]];
            float al = ss[sn * 16 + h] + sdv;
            al = al >= 0.f ? al : 0.2f * al;
            s += expf(al - m);
        }
        m_s[h] = m;
        s_s[h] = s + 1e-16f;
    }
    __syncthreads();

    float acc[8] = {};
    const int c = tid & 127;
    const int hbase = (tid >> 7) * 8;

    for (int ce = e0; ce < e1; ce += 16) {
        int nc = min(16, e1 - ce);
        if (tid < nc * 16) {
            int ei = tid >> 4, h = tid & 15;
            int sn = srcidx[csr[ce + ei]];
            float al = ss[sn * 16 + h] + sd[d * 16 + h];
            al = al >= 0.f ? al : 0.2f * al;
            alpha_s[ei][h] = expf(al - m_s[h]) / s_s[h];
            if (h == 0) src_s[ei] = sn;
        }
        __syncthreads();
        for (int ei = 0; ei < nc; ++ei) {
            float v = hsrc[(size_t)src_s[ei] * 128 + c];
#pragma unroll
            for (int hh = 0; hh < 8; ++hh)
                acc[hh] += alpha_s[ei][hbase + hh] * v;
        }
        __syncthreads();
    }

#pragma unroll
    for (int hh = 0; hh < 8; ++hh) {
        float v = acc[hh];
        unsigned short hb = f2bf(v);
        unsigned short lb = f2bf(v - bf2f(hb));
        size_t idx = (size_t)d * 2048 + (size_t)(hbase + hh) * 128 + c;
        haggH[idx] = hb;
        haggL[idx] = lb;
    }
}

// ---------------- layer 3: fused softmax + gather(zs) + bias + relu + mean + penalty --
__global__ __launch_bounds__(256) void agg32_kernel(
    const float* __restrict__ zs,    // [n_src, 512]
    const float* __restrict__ ss, const float* __restrict__ sd,
    const int* __restrict__ off, const int* __restrict__ csr, const int* __restrict__ srcidx,
    const float* __restrict__ bias,  // [512]
    const float* __restrict__ pwt, const float* __restrict__ pbt,  // [32], [1]
    float* __restrict__ out)         // [n_dst, 32]
{
    __shared__ float m_s[16], s_s[16];
    __shared__ float alpha_s[16][17];
    __shared__ int src_s[16];
    __shared__ float lds_out[512];
    __shared__ float hrow[32];
    const int d = blockIdx.x;
    const int tid = threadIdx.x;
    const int e0 = off[d], e1 = off[d + 1];

    if (tid < 16) {
        int h = tid;
        float sdv = sd[d * 16 + h];
        float m = -1e30f;
        for (int e = e0; e < e1; ++e) {
            int sn = srcidx[csr[e]];
            float al = ss[sn * 16 + h] + sdv;
            al = al >= 0.f ? al : 0.2f * al;
            m = fmaxf(m, al);
        }
        float s = 0.f;
        for (int e = e0; e < e1; ++e) {
            int sn = srcidx[csr[e]];
            float al = ss[sn * 16 + h] + sdv;
            al = al >= 0.f ? al : 0.2f * al;
            s += expf(al - m);
        }
        m_s[h] = m;
        s_s[h] = s + 1e-16f;
    }
    __syncthreads();

    float acc0 = 0.f, acc1 = 0.f;
    const int hsel = tid >> 4;

    for (int ce = e0; ce < e1; ce += 16) {
        int nc = min(16, e1 - ce);
        if (tid < nc * 16) {
            int ei = tid >> 4, h = tid & 15;
            int sn = srcidx[csr[ce + ei]];
            float al = ss[sn * 16 + h] + sd[d * 16 + h];
            al = al >= 0.f ? al : 0.2f * al;
            alpha_s[ei][h] = expf(al - m_s[h]) / s_s[h];
            if (h == 0) src_s[ei] = sn;
        }
        __syncthreads();
        for (int ei = 0; ei < nc; ++ei) {
            float a = alpha_s[ei][hsel];
            float2 v = *(const float2*)(zs + (size_t)src_s[ei] * 512 + tid * 2);
            acc0 += a * v.x;
            acc1 += a * v.y;
        }
        __syncthreads();
    }

    lds_out[tid * 2] = fmaxf(acc0 + bias[tid * 2], 0.f);
    lds_out[tid * 2 + 1] = fmaxf(acc1 + bias[tid * 2 + 1], 0.f);
    __syncthreads();
    if (tid < 32) {
        float s = 0.f;
#pragma unroll
        for (int hh = 0; hh < 16; ++hh) s += lds_out[hh * 32 + tid];
        hrow[tid] = s * (1.f / 16.f);
    }
    __syncthreads();
    if (tid < 32) {
        float t = pbt[0];
#pragma unroll
        for (int c = 0; c < 32; ++c) t += hrow[c] * pwt[c];
        out[(size_t)d * 32 + tid] = hrow[tid] * expf(t);
    }
}

// ---------------- final MLP on label edges ----------------
__global__ __launch_bounds__(256) void mlp_kernel(
    const float* __restrict__ hd, const float* __restrict__ hl,
    const int* __restrict__ ls, const int* __restrict__ ld,
    const float* __restrict__ w1, const float* __restrict__ b1,
    const float* __restrict__ w2, const float* __restrict__ b2,
    float* __restrict__ out, int M)
{
    __shared__ float w1s[64 * 64];
    __shared__ float b1s[64];
    __shared__ float w2s[64];
    int tid = threadIdx.x;
#pragma unroll
    for (int i = 0; i < 16; ++i) w1s[tid + i * 256] = w1[tid + i * 256];
    if (tid < 64) { b1s[tid] = b1[tid]; w2s[tid] = w2[tid]; }
    __syncthreads();
    int m = blockIdx.x * 256 + tid;
    if (m >= M) return;
    float f[64];
    const float* hp = hd + (size_t)ls[m] * 32;
    const float* lp = hl + (size_t)ld[m] * 32;
#pragma unroll
    for (int c = 0; c < 32; ++c) { f[c] = hp[c]; f[32 + c] = lp[c]; }
    float o = b2[0];
    for (int j = 0; j < 64; ++j) {
        float hj = b1s[j];
#pragma unroll
        for (int k = 0; k < 64; ++k) hj += f[k] * w1s[k * 64 + j];
        hj = fmaxf(hj, 0.f);
        o += hj * w2s[j];
    }
    out[m] = o;
}

extern "C" void kernel_launch(void* const* d_in, const int* in_sizes, int n_in,
                              void* d_out, int out_size, void* d_ws, size_t ws_size,
                              hipStream_t stream)
{
    const float* x_d = (const float*)d_in[0];
    const float* x_l = (const float*)d_in[1];
    const int* node_id_d = (const int*)d_in[2];
    const int* node_id_l = (const int*)d_in[3];
    const int* edge_src = (const int*)d_in[4];
    const int* edge_dst = (const int*)d_in[5];
    const int* label_src = (const int*)d_in[6];
    const int* label_dst = (const int*)d_in[7];
    const float* emb_d = (const float*)d_in[8];
    const float* emb_l = (const float*)d_in[9];
    const float* lin_dw = (const float*)d_in[10];
    const float* lin_db = (const float*)d_in[11];
    const float* lin_lw = (const float*)d_in[12];
    const float* lin_lb = (const float*)d_in[13];
    const float* Ws[3] = {(const float*)d_in[14], (const float*)d_in[19], (const float*)d_in[24]};
    const float* Wd[3] = {(const float*)d_in[15], (const float*)d_in[20], (const float*)d_in[25]};
    const float* as_[3] = {(const float*)d_in[16], (const float*)d_in[21], (const float*)d_in[26]};
    const float* ad_[3] = {(const float*)d_in[17], (const float*)d_in[22], (const float*)d_in[27]};
    const float* bb[3] = {(const float*)d_in[18], (const float*)d_in[23], (const float*)d_in[28]};
    const float* pw = (const float*)d_in[29];
    const float* pb = (const float*)d_in[30];
    const float* fc1w = (const float*)d_in[31];
    const float* fc1b = (const float*)d_in[32];
    const float* fc2w = (const float*)d_in[33];
    const float* fc2b = (const float*)d_in[34];

    char* wsb = (char*)d_ws;
    size_t woff = 0;
    auto carve = [&](size_t bytes) -> void* {
        woff = (woff + 255) & ~(size_t)255;
        void* p = wsb + woff;
        woff += bytes;
        return p;
    };
    float* hdA = (float*)carve((size_t)ND * 128 * 4);
    float* hdB = (float*)carve((size_t)ND * 128 * 4);
    float* hlA = (float*)carve((size_t)NL * 128 * 4);
    float* hlB = (float*)carve((size_t)NL * 128 * 4);
    unsigned short* haggH = (unsigned short*)carve((size_t)NL * 2048 * 2);  // L3 reuses as fp32 zs [*,512]
    unsigned short* haggL = (unsigned short*)carve((size_t)NL * 2048 * 2);
    unsigned short* WtH = (unsigned short*)carve((size_t)2 * 2048 * 128 * 2);
    unsigned short* WtL = (unsigned short*)carve((size_t)2 * 2048 * 128 * 2);
    float* ssb0 = (float*)carve((size_t)ND * 16 * 4);
    float* sdb0 = (float*)carve((size_t)NL * 16 * 4);
    float* ssb1 = (float*)carve((size_t)NL * 16 * 4);
    float* sdb1 = (float*)carve((size_t)ND * 16 * 4);
    float* fw3 = (float*)carve((size_t)3 * 4 * 2048 * 4);
    int* degl = (int*)carve((size_t)(2 * (NL + ND)) * 4);
    int* degd = degl + NL;
    int* curl = degd + ND;
    int* curd = curl + NL;
    int* offl = (int*)carve((size_t)(NL + 1) * 4);
    int* offd = (int*)carve((size_t)(ND + 1) * 4);
    int* csrl = (int*)carve((size_t)NE * 4);
    int* csrd = (int*)carve((size_t)NE * 4);
    float* hdp = (float*)carve((size_t)ND * 32 * 4);
    float* hlp = (float*)carve((size_t)NL * 32 * 4);

    hipMemsetAsync(degl, 0, (size_t)2 * (NL + ND) * 4, stream);

    hist_kernel<<<(NE + 255) / 256, 256, 0, stream>>>(edge_src, edge_dst, degl, degd);
    scan2_kernel<<<2, 1024, 0, stream>>>(degl, offl, NL, degd, offd, ND);
    scatter_kernel<<<(NE + 255) / 256, 256, 0, stream>>>(edge_src, edge_dst, offl, offd, curl, curd, csrl, csrd);

    fold3_kernel<<<(3 * 8192 + 255) / 256, 256, 0, stream>>>(
        Ws[0], Wd[0], as_[0], ad_[0], Ws[1], Wd[1], as_[1], ad_[1],
        Ws[2], Wd[2], as_[2], ad_[2], fw3);

    // input linears + embedding add
    gemm_kernel<<<dim3(128 / BN, ND / BM), 256, 0, stream>>>(x_d, lin_dw, lin_db, emb_d, node_id_d, hdA, ND, 128, 412);
    gemm_kernel<<<dim3(128 / BN, NL / BM), 256, 0, stream>>>(x_l, lin_lw, lin_lb, emb_l, node_id_l, hlA, NL, 128, 240);

    float* hd_cur = hdA; float* hd_nxt = hdB;
    float* hl_cur = hlA; float* hl_nxt = hlB;

    // ---- layers 1-2: aggregate-then-project (split-bf16 MFMA projection) ----
    for (int L = 0; L < 2; ++L) {
        const float* fw = fw3 + (size_t)L * 8192;
        wt_kernel<<<(2 * 128 * 2048 + 255) / 256, 256, 0, stream>>>(Ws[L], WtH, WtL);

        score2_kernel<<<ND / 16, 256, 0, stream>>>(hd_cur, fw + 0 * 2048, fw + 3 * 2048, ssb0, sdb1, ND);
        score2_kernel<<<NL / 16, 256, 0, stream>>>(hl_cur, fw + 1 * 2048, fw + 2 * 2048, sdb0, ssb1, NL);

        // edge type 0: disease -> lncrna (dst = lncrna)
        hagg_kernel<<<NL, 256, 0, stream>>>(hd_cur, ssb0, sdb0, offl, csrl, edge_src, haggH, haggL);
        gemm2_mfma_kernel<<<dim3(NL / 64, 16), 256, 0, stream>>>(haggH, haggL, WtH, WtL, bb[L], NL);
        reduce16_kernel<<<(NL * 32 + 255) / 256, 256, 0, stream>>>(haggH, haggL, hl_nxt, NL);

        // edge type 1: lncrna -> disease (dst = disease)
        hagg_kernel<<<ND, 256, 0, stream>>>(hl_cur, ssb1, sdb1, offd, csrd, edge_dst, haggH, haggL);
        gemm2_mfma_kernel<<<dim3(ND / 64, 16), 256, 0, stream>>>(haggH, haggL,
                                                                 WtH + (size_t)2048 * 128, WtL + (size_t)2048 * 128,
                                                                 bb[L] + 2048, ND);
        reduce16_kernel<<<(ND * 32 + 255) / 256, 256, 0, stream>>>(haggH, haggL, hd_nxt, ND);

        float* t;
        t = hd_cur; hd_cur = hd_nxt; hd_nxt = t;
        t = hl_cur; hl_cur = hl_nxt; hl_nxt = t;
    }

    // ---- layer 3: project-then-aggregate (fp32), fused epilogue incl. penalty ----
    {
        const float* fw = fw3 + 2 * 8192;
        float* zs3 = (float*)haggH;  // 32.8 MB needed, 65.5 MB available; haggH free here
        score2_kernel<<<ND / 16, 256, 0, stream>>>(hd_cur, fw + 0 * 2048, fw + 3 * 2048, ssb0, sdb1, ND);
        score2_kernel<<<NL / 16, 256, 0, stream>>>(hl_cur, fw + 1 * 2048, fw + 2 * 2048, sdb0, ssb1, NL);

        // edge type 0: zs = hd @ Ws3[0] [ND,512]; dst = lncrna -> hlp (penalty pw[1],pb[1])
        gemm_kernel<<<dim3(512 / BN, ND / BM), 256, 0, stream>>>(hd_cur, Ws[2], nullptr, nullptr, nullptr, zs3, ND, 512, 128);
        agg32_kernel<<<NL, 256, 0, stream>>>(zs3, ssb0, sdb0, offl, csrl, edge_src,
                                             bb[2], pw + 32, pb + 1, hlp);

        // edge type 1: zs = hl @ Ws3[1] [NL,512]; dst = disease -> hdp (penalty pw[0],pb[0])
        gemm_kernel<<<dim3(512 / BN, NL / BM), 256, 0, stream>>>(hl_cur, Ws[2] + 128 * 512, nullptr, nullptr, nullptr, zs3, NL, 512, 128);
        agg32_kernel<<<ND, 256, 0, stream>>>(zs3, ssb1, sdb1, offd, csrd, edge_dst,
                                             bb[2] + 512, pw, pb, hdp);
    }

    mlp_kernel<<<(NM + 255) / 256, 256, 0, stream>>>(hdp, hlp, label_src, label_dst,
                                                     fc1w, fc1b, fc2w, fc2b, (float*)d_out, NM);
}

// Round 8
// 1332.412 us; speedup vs baseline: 1.0789x; 1.0435x over previous
//
#include <hip/hip_runtime.h>
#include <cstdint>
#include <cstddef>

#define ND 8000
#define NL 16000
#define NE 60000
#define NM 50000

#define BM 64
#define BN 64
#define BK 16

typedef __attribute__((ext_vector_type(8))) short bf16x8;
typedef __attribute__((ext_vector_type(4))) float f32x4;

__device__ __forceinline__ unsigned short f2bf(float x) {
    unsigned int u = __float_as_uint(x);
    unsigned int r = (u + 0x7FFFu + ((u >> 16) & 1u)) >> 16;
    return (unsigned short)r;
}
__device__ __forceinline__ float bf2f(unsigned short b) {
    return __uint_as_float(((unsigned int)b) << 16);
}

// ---------------- GEMM: C = A[M,K] @ B[K,N] (+bias[n]) (+emb[nid[m],n]) ----------------
// input linears and layer-3 zs projections
__global__ __launch_bounds__(256) void gemm_kernel(
    const float* __restrict__ A, const float* __restrict__ B,
    const float* __restrict__ bias, const float* __restrict__ emb, const int* __restrict__ nid,
    float* __restrict__ Cm, int M, int N, int K)
{
    __shared__ float As[BK][BM + 4];
    __shared__ float Bs[BK][BN + 4];
    const int tid = threadIdx.x;
    const int tx = tid & 15, ty = tid >> 4;
    const int bm = blockIdx.y * BM, bn = blockIdx.x * BN;
    float acc[4][4] = {};
    for (int k0 = 0; k0 < K; k0 += BK) {
#pragma unroll
        for (int i = 0; i < 4; ++i) {
            int idx = tid + i * 256;
            int ml = idx >> 4, kl = idx & 15;
            int gm = bm + ml, gk = k0 + kl;
            As[kl][ml] = (gm < M && gk < K) ? A[(size_t)gm * K + gk] : 0.f;
        }
#pragma unroll
        for (int i = 0; i < 4; ++i) {
            int idx = tid + i * 256;
            int kl = idx >> 6, nl = idx & 63;
            int gk = k0 + kl, gn = bn + nl;
            Bs[kl][nl] = (gk < K && gn < N) ? B[(size_t)gk * N + gn] : 0.f;
        }
        __syncthreads();
#pragma unroll
        for (int k = 0; k < BK; ++k) {
            float4 av = *(const float4*)&As[k][ty * 4];
            float4 bv = *(const float4*)&Bs[k][tx * 4];
            float a4[4] = {av.x, av.y, av.z, av.w};
            float b4[4] = {bv.x, bv.y, bv.z, bv.w};
#pragma unroll
            for (int i = 0; i < 4; ++i)
#pragma unroll
                for (int j = 0; j < 4; ++j)
                    acc[i][j] += a4[i] * b4[j];
        }
        __syncthreads();
    }
#pragma unroll
    for (int i = 0; i < 4; ++i) {
        int gm = bm + ty * 4 + i;
        if (gm >= M) continue;
        int gn0 = bn + tx * 4;
        float4 v;
        float* vp = &v.x;
#pragma unroll
        for (int j = 0; j < 4; ++j) {
            float x = acc[i][j];
            int gn = gn0 + j;
            if (bias) x += bias[gn];
            if (emb) x += emb[(size_t)nid[gm] * N + gn];
            vp[j] = x;
        }
        if (gn0 + 3 < N) *(float4*)&Cm[(size_t)gm * N + gn0] = v;
    }
}

// ---------------- W transpose + split-bf16 (per layer, both directions) ----------------
// W [2,128,2048] fp32 -> WtH/WtL [2][2048 n][128 k] bf16
__global__ void wt_kernel(const float* __restrict__ W,
                          unsigned short* __restrict__ WtH, unsigned short* __restrict__ WtL)
{
    int gid = blockIdx.x * 256 + threadIdx.x;
    if (gid >= 2 * 128 * 2048) return;
    int dir = gid >> 18;
    int rem = gid & 262143;
    int k = rem >> 11, n = rem & 2047;   // n fast -> coalesced read
    float v = W[(size_t)dir * 262144 + (size_t)k * 2048 + n];
    unsigned short hb = f2bf(v);
    unsigned short lb = f2bf(v - bf2f(hb));
    size_t o = (size_t)dir * 262144 + (size_t)n * 128 + k;
    WtH[o] = hb;
    WtL[o] = lb;
}

// ---------------- fused per-head projection + bias + relu + HEAD-MEAN (layers 1-2) ----
// out[m, c] = (1/16) * sum_h relu( hagg[m,h,:] @ W[:, h*128+c] + bias[h*128+c] )
// Split-bf16 MFMA (3-product). A = haggH/L [M,2048]; B = WtH/L [2048 n][128 k].
// grid (M/64, 2): 4 waves per block, wave w owns rows bm + w*16..+15; blockIdx.y picks
// 64 of the 128 output cols. Heads are looped in-register (mean accumulates in VGPRs),
// so neither the per-head z nor a separate reduction ever touches memory.
__global__ __launch_bounds__(256) void gemm2r_kernel(
    const unsigned short* __restrict__ haggH, const unsigned short* __restrict__ haggL,
    const unsigned short* __restrict__ WtH, const unsigned short* __restrict__ WtL,
    const float* __restrict__ bias, float* __restrict__ out, int M)
{
    const int wave = threadIdx.x >> 6;
    const int lane = threadIdx.x & 63;
    const int cb = blockIdx.y;               // column half (0/1)
    const int m0 = blockIdx.x * 64 + wave * 16;
    const int row = lane & 15;               // A m-offset / B n-offset / D col
    const int quad = lane >> 4;              // A,B k-chunk; D row = quad*4 + r

    f32x4 mean[4] = {};

    const size_t arow = (size_t)(m0 + row) * 2048 + quad * 8;

    for (int h = 0; h < 16; ++h) {
        f32x4 acc[4];
#pragma unroll
        for (int ctl = 0; ctl < 4; ++ctl) {
            float bv = bias[h * 128 + cb * 64 + ctl * 16 + row];
            acc[ctl] = (f32x4){bv, bv, bv, bv};
        }
#pragma unroll
        for (int kc = 0; kc < 4; ++kc) {
            const size_t aoff = arow + h * 128 + kc * 32;
            bf16x8 aH = *(const bf16x8*)(haggH + aoff);
            bf16x8 aL = *(const bf16x8*)(haggL + aoff);
#pragma unroll
            for (int ctl = 0; ctl < 4; ++ctl) {
                const size_t boff = (size_t)(h * 128 + cb * 64 + ctl * 16 + row) * 128 + quad * 8 + kc * 32;
                bf16x8 bH = *(const bf16x8*)(WtH + boff);
                bf16x8 bL = *(const bf16x8*)(WtL + boff);
                acc[ctl] = __builtin_amdgcn_mfma_f32_16x16x32_bf16(aH, bH, acc[ctl], 0, 0, 0);
                acc[ctl] = __builtin_amdgcn_mfma_f32_16x16x32_bf16(aH, bL, acc[ctl], 0, 0, 0);
                acc[ctl] = __builtin_amdgcn_mfma_f32_16x16x32_bf16(aL, bH, acc[ctl], 0, 0, 0);
            }
        }
#pragma unroll
        for (int ctl = 0; ctl < 4; ++ctl) {
#pragma unroll
            for (int r = 0; r < 4; ++r)
                mean[ctl][r] += fmaxf(acc[ctl][r], 0.f);
        }
    }

#pragma unroll
    for (int ctl = 0; ctl < 4; ++ctl) {
        int c = cb * 64 + ctl * 16 + row;
#pragma unroll
        for (int r = 0; r < 4; ++r) {
            int gm = m0 + quad * 4 + r;
            out[(size_t)gm * 128 + c] = mean[ctl][r] * (1.f / 16.f);
        }
    }
}

// ---------------- fold for ALL 3 layers: fw3[l][f][k][h] = sum_c W[k,h*C+c]*a[h,c] ----
__global__ void fold3_kernel(
    const float* __restrict__ Ws1, const float* __restrict__ Wd1,
    const float* __restrict__ as1, const float* __restrict__ ad1,
    const float* __restrict__ Ws2, const float* __restrict__ Wd2,
    const float* __restrict__ as2, const float* __restrict__ ad2,
    const float* __restrict__ Ws3, const float* __restrict__ Wd3,
    const float* __restrict__ as3, const float* __restrict__ ad3,
    float* __restrict__ fw3)
{
    int gid = blockIdx.x * blockDim.x + threadIdx.x;
    if (gid >= 3 * 4 * 128 * 16) return;
    int l = gid / 8192, rem1 = gid % 8192;
    int f = rem1 / 2048, rem = rem1 % 2048;
    int k = rem >> 4, h = rem & 15;
    int Ntot = (l == 2) ? 512 : 2048;
    int C = Ntot >> 4;
    const float* W;
    const float* a;
    if (l == 0) { W = (f & 1) ? Wd1 : Ws1; a = (f & 1) ? ad1 : as1; }
    else if (l == 1) { W = (f & 1) ? Wd2 : Ws2; a = (f & 1) ? ad2 : as2; }
    else { W = (f & 1) ? Wd3 : Ws3; a = (f & 1) ? ad3 : as3; }
    if (f >= 2) { W += 128 * Ntot; a += 16 * C; }
    float s = 0.f;
    for (int c = 0; c < C; ++c) s += W[(size_t)k * Ntot + h * C + c] * a[h * C + c];
    fw3[gid] = s;
}

// ---------------- score2: two folded projections of the same H in one pass ------------
__global__ __launch_bounds__(256) void score2_kernel(
    const float* __restrict__ Hf, const float* __restrict__ WfA, const float* __restrict__ WfB,
    float* __restrict__ outA, float* __restrict__ outB, int n)
{
    __shared__ float hs[16 * 128];
    __shared__ float wa[128 * 16];
    __shared__ float wb[128 * 16];
    int tid = threadIdx.x;
    int n0 = blockIdx.x * 16;
#pragma unroll
    for (int i = 0; i < 8; ++i) {
        int idx = tid + i * 256;
        int nl = idx >> 7, k = idx & 127;
        int gn = n0 + nl;
        hs[idx] = (gn < n) ? Hf[(size_t)gn * 128 + k] : 0.f;
        wa[idx] = WfA[idx];
        wb[idx] = WfB[idx];
    }
    __syncthreads();
    int nl = tid >> 4, h = tid & 15;
    float sa = 0.f, sb = 0.f;
    for (int k = 0; k < 128; ++k) {
        float hv = hs[nl * 128 + k];
        sa += hv * wa[k * 16 + h];
        sb += hv * wb[k * 16 + h];
    }
    int gn = n0 + nl;
    if (gn < n) { outA[gn * 16 + h] = sa; outB[gn * 16 + h] = sb; }
}

// ---------------- CSR build ----------------
__global__ void hist_kernel(const int* __restrict__ esrc, const int* __restrict__ edst,
                            int* __restrict__ degl, int* __restrict__ degd)
{
    int e = blockIdx.x * blockDim.x + threadIdx.x;
    if (e >= NE) return;
    atomicAdd(&degl[edst[e]], 1);
    atomicAdd(&degd[esrc[e]], 1);
}

__global__ __launch_bounds__(1024) void scan2_kernel(
    const int* __restrict__ degA, int* __restrict__ offA, int nA,
    const int* __restrict__ degB, int* __restrict__ offB, int nB)
{
    __shared__ int ps[1024];
    const int* deg = blockIdx.x ? degB : degA;
    int* off = blockIdx.x ? offB : offA;
    int n = blockIdx.x ? nB : nA;
    int tid = threadIdx.x;
    int chunk = (n + 1023) >> 10;
    int start = tid * chunk, end = min(start + chunk, n);
    int p = 0;
    for (int i = start; i < end; ++i) p += deg[i];
    ps[tid] = p;
    __syncthreads();
    for (int o = 1; o < 1024; o <<= 1) {
        int v = (tid >= o) ? ps[tid - o] : 0;
        __syncthreads();
        ps[tid] += v;
        __syncthreads();
    }
    int run = ps[tid] - p;
    for (int i = start; i < end; ++i) { off[i] = run; run += deg[i]; }
    if (tid == 1023) off[n] = ps[1023];
}

__global__ void scatter_kernel(const int* __restrict__ esrc, const int* __restrict__ edst,
                               const int* __restrict__ offl, const int* __restrict__ offd,
                               int* __restrict__ curl, int* __restrict__ curd,
                               int* __restrict__ csrl, int* __restrict__ csrd)
{
    int e = blockIdx.x * blockDim.x + threadIdx.x;
    if (e >= NE) return;
    int dl = edst[e]; int p = atomicAdd(&curl[dl], 1); csrl[offl[dl] + p] = e;
    int dd = esrc[e]; int q = atomicAdd(&curd[dd], 1); csrd[offd[dd] + q] = e;
}

// ---------------- fused softmax + per-head aggregation -> split-bf16 hagg (L1-2) -------
__global__ __launch_bounds__(256) void hagg_kernel(
    const float* __restrict__ hsrc,  // [n_src, 128]
    const float* __restrict__ ss,    // [n_src, 16]
    const float* __restrict__ sd,    // [n_dst, 16]
    const int* __restrict__ off, const int* __restrict__ csr, const int* __restrict__ srcidx,
    unsigned short* __restrict__ haggH, unsigned short* __restrict__ haggL)  // [n_dst, 2048]
{
    __shared__ float m_s[16], s_s[16];
    __shared__ float alpha_s[16][17];
    __shared__ int src_s[16];
    const int d = blockIdx.x;
    const int tid = threadIdx.x;
    const int e0 = off[d], e1 = off[d + 1];

    if (tid < 16) {
        int h = tid;
        float sdv = sd[d * 16 + h];
        float m = -1e30f;
        for (int e = e0; e < e1; ++e) {
            int sn = srcidx[csr[e]];
            float al = ss[sn * 16 + h] + sdv;
            al = al >= 0.f ? al : 0.2f * al;
            m = fmaxf(m, al);
        }
        float s = 0.f;
        for (int e = e0; e < e1; ++e) {
            int sn = srcidx[csr[e]];
            float al = ss[sn * 16 + h] + sdv;
            al = al >= 0.f ? al : 0.2f * al;
            s += expf(al - m);
        }
        m_s[h] = m;
        s_s[h] = s + 1e-16f;
    }
    __syncthreads();

    float acc[8] = {};
    const int c = tid & 127;
    const int hbase = (tid >> 7) * 8;

    for (int ce = e0; ce < e1; ce += 16) {
        int nc = min(16, e1 - ce);
        if (tid < nc * 16) {
            int ei = tid >> 4, h = tid & 15;
            int sn = srcidx[csr[ce + ei]];
            float al = ss[sn * 16 + h] + sd[d * 16 + h];
            al = al >= 0.f ? al : 0.2f * al;
            alpha_s[ei][h] = expf(al - m_s[h]) / s_s[h];
            if (h == 0) src_s[ei] = sn;
        }
        __syncthreads();
        for (int ei = 0; ei < nc; ++ei) {
            float v = hsrc[(size_t)src_s[ei] * 128 + c];
#pragma unroll
            for (int hh = 0; hh < 8; ++hh)
                acc[hh] += alpha_s[ei][hbase + hh] * v;
        }
        __syncthreads();
    }

#pragma unroll
    for (int hh = 0; hh < 8; ++hh) {
        float v = acc[hh];
        unsigned short hb = f2bf(v);
        unsigned short lb = f2bf(v - bf2f(hb));
        size_t idx = (size_t)d * 2048 + (size_t)(hbase + hh) * 128 + c;
        haggH[idx] = hb;
        haggL[idx] = lb;
    }
}

// ---------------- layer 3: fused softmax + gather(zs) + bias + relu + mean + penalty --
__global__ __launch_bounds__(256) void agg32_kernel(
    const float* __restrict__ zs,    // [n_src, 512]
    const float* __restrict__ ss, const float* __restrict__ sd,
    const int* __restrict__ off, const int* __restrict__ csr, const int* __restrict__ srcidx,
    const float* __restrict__ bias,  // [512]
    const float* __restrict__ pwt, const float* __restrict__ pbt,  // [32], [1]
    float* __restrict__ out)         // [n_dst, 32]
{
    __shared__ float m_s[16], s_s[16];
    __shared__ float alpha_s[16][17];
    __shared__ int src_s[16];
    __shared__ float lds_out[512];
    __shared__ float hrow[32];
    const int d = blockIdx.x;
    const int tid = threadIdx.x;
    const int e0 = off[d], e1 = off[d + 1];

    if (tid < 16) {
        int h = tid;
        float sdv = sd[d * 16 + h];
        float m = -1e30f;
        for (int e = e0; e < e1; ++e) {
            int sn = srcidx[csr[e]];
            float al = ss[sn * 16 + h] + sdv;
            al = al >= 0.f ? al : 0.2f * al;
            m = fmaxf(m, al);
        }
        float s = 0.f;
        for (int e = e0; e < e1; ++e) {
            int sn = srcidx[csr[e]];
            float al = ss[sn * 16 + h] + sdv;
            al = al >= 0.f ? al : 0.2f * al;
            s += expf(al - m);
        }
        m_s[h] = m;
        s_s[h] = s + 1e-16f;
    }
    __syncthreads();

    float acc0 = 0.f, acc1 = 0.f;
    const int hsel = tid >> 4;

    for (int ce = e0; ce < e1; ce += 16) {
        int nc = min(16, e1 - ce);
        if (tid < nc * 16) {
            int ei = tid >> 4, h = tid & 15;
            int sn = srcidx[csr[ce + ei]];
            float al = ss[sn * 16 + h] + sd[d * 16 + h];
            al = al >= 0.f ? al : 0.2f * al;
            alpha_s[ei][h] = expf(al - m_s[h]) / s_s[h];
            if (h == 0) src_s[ei] = sn;
        }
        __syncthreads();
        for (int ei = 0; ei < nc; ++ei) {
            float a = alpha_s[ei][hsel];
            float2 v = *(const float2*)(zs + (size_t)src_s[ei] * 512 + tid * 2);
            acc0 += a * v.x;
            acc1 += a * v.y;
        }
        __syncthreads();
    }

    lds_out[tid * 2] = fmaxf(acc0 + bias[tid * 2], 0.f);
    lds_out[tid * 2 + 1] = fmaxf(acc1 + bias[tid * 2 + 1], 0.f);
    __syncthreads();
    if (tid < 32) {
        float s = 0.f;
#pragma unroll
        for (int hh = 0; hh < 16; ++hh) s += lds_out[hh * 32 + tid];
        hrow[tid] = s * (1.f / 16.f);
    }
    __syncthreads();
    if (tid < 32) {
        float t = pbt[0];
#pragma unroll
        for (int c = 0; c < 32; ++c) t += hrow[c] * pwt[c];
        out[(size_t)d * 32 + tid] = hrow[tid] * expf(t);
    }
}

// ---------------- final MLP on label edges ----------------
__global__ __launch_bounds__(256) void mlp_kernel(
    const float* __restrict__ hd, const float* __restrict__ hl,
    const int* __restrict__ ls, const int* __restrict__ ld,
    const float* __restrict__ w1, const float* __restrict__ b1,
    const float* __restrict__ w2, const float* __restrict__ b2,
    float* __restrict__ out, int M)
{
    __shared__ float w1s[64 * 64];
    __shared__ float b1s[64];
    __shared__ float w2s[64];
    int tid = threadIdx.x;
#pragma unroll
    for (int i = 0; i < 16; ++i) w1s[tid + i * 256] = w1[tid + i * 256];
    if (tid < 64) { b1s[tid] = b1[tid]; w2s[tid] = w2[tid]; }
    __syncthreads();
    int m = blockIdx.x * 256 + tid;
    if (m >= M) return;
    float f[64];
    const float* hp = hd + (size_t)ls[m] * 32;
    const float* lp = hl + (size_t)ld[m] * 32;
#pragma unroll
    for (int c = 0; c < 32; ++c) { f[c] = hp[c]; f[32 + c] = lp[c]; }
    float o = b2[0];
    for (int j = 0; j < 64; ++j) {
        float hj = b1s[j];
#pragma unroll
        for (int k = 0; k < 64; ++k) hj += f[k] * w1s[k * 64 + j];
        hj = fmaxf(hj, 0.f);
        o += hj * w2s[j];
    }
    out[m] = o;
}

extern "C" void kernel_launch(void* const* d_in, const int* in_sizes, int n_in,
                              void* d_out, int out_size, void* d_ws, size_t ws_size,
                              hipStream_t stream)
{
    const float* x_d = (const float*)d_in[0];
    const float* x_l = (const float*)d_in[1];
    const int* node_id_d = (const int*)d_in[2];
    const int* node_id_l = (const int*)d_in[3];
    const int* edge_src = (const int*)d_in[4];
    const int* edge_dst = (const int*)d_in[5];
    const int* label_src = (const int*)d_in[6];
    const int* label_dst = (const int*)d_in[7];
    const float* emb_d = (const float*)d_in[8];
    const float* emb_l = (const float*)d_in[9];
    const float* lin_dw = (const float*)d_in[10];
    const float* lin_db = (const float*)d_in[11];
    const float* lin_lw = (const float*)d_in[12];
    const float* lin_lb = (const float*)d_in[13];
    const float* Ws[3] = {(const float*)d_in[14], (const float*)d_in[19], (const float*)d_in[24]};
    const float* Wd[3] = {(const float*)d_in[15], (const float*)d_in[20], (const float*)d_in[25]};
    const float* as_[3] = {(const float*)d_in[16], (const float*)d_in[21], (const float*)d_in[26]};
    const float* ad_[3] = {(const float*)d_in[17], (const float*)d_in[22], (const float*)d_in[27]};
    const float* bb[3] = {(const float*)d_in[18], (const float*)d_in[23], (const float*)d_in[28]};
    const float* pw = (const float*)d_in[29];
    const float* pb = (const float*)d_in[30];
    const float* fc1w = (const float*)d_in[31];
    const float* fc1b = (const float*)d_in[32];
    const float* fc2w = (const float*)d_in[33];
    const float* fc2b = (const float*)d_in[34];

    char* wsb = (char*)d_ws;
    size_t woff = 0;
    auto carve = [&](size_t bytes) -> void* {
        woff = (woff + 255) & ~(size_t)255;
        void* p = wsb + woff;
        woff += bytes;
        return p;
    };
    float* hdA = (float*)carve((size_t)ND * 128 * 4);
    float* hdB = (float*)carve((size_t)ND * 128 * 4);
    float* hlA = (float*)carve((size_t)NL * 128 * 4);
    float* hlB = (float*)carve((size_t)NL * 128 * 4);
    unsigned short* haggH = (unsigned short*)carve((size_t)NL * 2048 * 2);  // L3 reuses as fp32 zs [*,512]
    unsigned short* haggL = (unsigned short*)carve((size_t)NL * 2048 * 2);
    unsigned short* WtH = (unsigned short*)carve((size_t)2 * 2048 * 128 * 2);
    unsigned short* WtL = (unsigned short*)carve((size_t)2 * 2048 * 128 * 2);
    float* ssb0 = (float*)carve((size_t)ND * 16 * 4);
    float* sdb0 = (float*)carve((size_t)NL * 16 * 4);
    float* ssb1 = (float*)carve((size_t)NL * 16 * 4);
    float* sdb1 = (float*)carve((size_t)ND * 16 * 4);
    float* fw3 = (float*)carve((size_t)3 * 4 * 2048 * 4);
    int* degl = (int*)carve((size_t)(2 * (NL + ND)) * 4);
    int* degd = degl + NL;
    int* curl = degd + ND;
    int* curd = curl + NL;
    int* offl = (int*)carve((size_t)(NL + 1) * 4);
    int* offd = (int*)carve((size_t)(ND + 1) * 4);
    int* csrl = (int*)carve((size_t)NE * 4);
    int* csrd = (int*)carve((size_t)NE * 4);
    float* hdp = (float*)carve((size_t)ND * 32 * 4);
    float* hlp = (float*)carve((size_t)NL * 32 * 4);

    hipMemsetAsync(degl, 0, (size_t)2 * (NL + ND) * 4, stream);

    hist_kernel<<<(NE + 255) / 256, 256, 0, stream>>>(edge_src, edge_dst, degl, degd);
    scan2_kernel<<<2, 1024, 0, stream>>>(degl, offl, NL, degd, offd, ND);
    scatter_kernel<<<(NE + 255) / 256, 256, 0, stream>>>(edge_src, edge_dst, offl, offd, curl, curd, csrl, csrd);

    fold3_kernel<<<(3 * 8192 + 255) / 256, 256, 0, stream>>>(
        Ws[0], Wd[0], as_[0], ad_[0], Ws[1], Wd[1], as_[1], ad_[1],
        Ws[2], Wd[2], as_[2], ad_[2], fw3);

    // input linears + embedding add
    gemm_kernel<<<dim3(128 / BN, ND / BM), 256, 0, stream>>>(x_d, lin_dw, lin_db, emb_d, node_id_d, hdA, ND, 128, 412);
    gemm_kernel<<<dim3(128 / BN, NL / BM), 256, 0, stream>>>(x_l, lin_lw, lin_lb, emb_l, node_id_l, hlA, NL, 128, 240);

    float* hd_cur = hdA; float* hd_nxt = hdB;
    float* hl_cur = hlA; float* hl_nxt = hlB;

    // ---- layers 1-2: aggregate-then-project (split-bf16 MFMA, fused head-mean) ----
    for (int L = 0; L < 2; ++L) {
        const float* fw = fw3 + (size_t)L * 8192;
        wt_kernel<<<(2 * 128 * 2048 + 255) / 256, 256, 0, stream>>>(Ws[L], WtH, WtL);

        score2_kernel<<<ND / 16, 256, 0, stream>>>(hd_cur, fw + 0 * 2048, fw + 3 * 2048, ssb0, sdb1, ND);
        score2_kernel<<<NL / 16, 256, 0, stream>>>(hl_cur, fw + 1 * 2048, fw + 2 * 2048, sdb0, ssb1, NL);

        // edge type 0: disease -> lncrna (dst = lncrna)
        hagg_kernel<<<NL, 256, 0, stream>>>(hd_cur, ssb0, sdb0, offl, csrl, edge_src, haggH, haggL);
        gemm2r_kernel<<<dim3(NL / 64, 2), 256, 0, stream>>>(haggH, haggL, WtH, WtL, bb[L], hl_nxt, NL);

        // edge type 1: lncrna -> disease (dst = disease)
        hagg_kernel<<<ND, 256, 0, stream>>>(hl_cur, ssb1, sdb1, offd, csrd, edge_dst, haggH, haggL);
        gemm2r_kernel<<<dim3(ND / 64, 2), 256, 0, stream>>>(haggH, haggL,
                                                            WtH + (size_t)2048 * 128, WtL + (size_t)2048 * 128,
                                                            bb[L] + 2048, hd_nxt, ND);

        float* t;
        t = hd_cur; hd_cur = hd_nxt; hd_nxt = t;
        t = hl_cur; hl_cur = hl_nxt; hl_nxt = t;
    }

    // ---- layer 3: project-then-aggregate (fp32), fused epilogue incl. penalty ----
    {
        const float* fw = fw3 + 2 * 8192;
        float* zs3 = (float*)haggH;  // 32.8 MB needed; hagg buffers free here
        score2_kernel<<<ND / 16, 256, 0, stream>>>(hd_cur, fw + 0 * 2048, fw + 3 * 2048, ssb0, sdb1, ND);
        score2_kernel<<<NL / 16, 256, 0, stream>>>(hl_cur, fw + 1 * 2048, fw + 2 * 2048, sdb0, ssb1, NL);

        // edge type 0: zs = hd @ Ws3[0] [ND,512]; dst = lncrna -> hlp (penalty pw[1],pb[1])
        gemm_kernel<<<dim3(512 / BN, ND / BM), 256, 0, stream>>>(hd_cur, Ws[2], nullptr, nullptr, nullptr, zs3, ND, 512, 128);
        agg32_kernel<<<NL, 256, 0, stream>>>(zs3, ssb0, sdb0, offl, csrl, edge_src,
                                             bb[2], pw + 32, pb + 1, hlp);

        // edge type 1: zs = hl @ Ws3[1] [NL,512]; dst = disease -> hdp (penalty pw[0],pb[0])
        gemm_kernel<<<dim3(512 / BN, NL / BM), 256, 0, stream>>>(hl_cur, Ws[2] + 128 * 512, nullptr, nullptr, nullptr, zs3, NL, 512, 128);
        agg32_kernel<<<ND, 256, 0, stream>>>(zs3, ssb1, sdb1, offd, csrd, edge_dst,
                                             bb[2] + 512, pw, pb, hdp);
    }

    mlp_kernel<<<(NM + 255) / 256, 256, 0, stream>>>(hdp, hlp, label_src, label_dst,
                                                     fc1w, fc1b, fc2w, fc2b, (float*)d_out, NM);
}

// Round 9
// 1204.134 us; speedup vs baseline: 1.1938x; 1.1065x over previous
//
#include <hip/hip_runtime.h>
#include <cstdint>
#include <cstddef>

#define ND 8000
#define NL 16000
#define NE 60000
#define NM 50000

#define BM 64
#define BN 64
#define BK 16

typedef __attribute__((ext_vector_type(8))) short bf16x8;
typedef __attribute__((ext_vector_type(4))) float f32x4;

__device__ __forceinline__ unsigned short f2bf(float x) {
    unsigned int u = __float_as_uint(x);
    unsigned int r = (u + 0x7FFFu + ((u >> 16) & 1u)) >> 16;
    return (unsigned short)r;
}
__device__ __forceinline__ float bf2f(unsigned short b) {
    return __uint_as_float(((unsigned int)b) << 16);
}

// ---------------- GEMM: C = A[M,K] @ B[K,N] (+bias[n]) (+emb[nid[m],n]) ----------------
// input linears and layer-3 zs projections
__global__ __launch_bounds__(256) void gemm_kernel(
    const float* __restrict__ A, const float* __restrict__ B,
    const float* __restrict__ bias, const float* __restrict__ emb, const int* __restrict__ nid,
    float* __restrict__ Cm, int M, int N, int K)
{
    __shared__ float As[BK][BM + 4];
    __shared__ float Bs[BK][BN + 4];
    const int tid = threadIdx.x;
    const int tx = tid & 15, ty = tid >> 4;
    const int bm = blockIdx.y * BM, bn = blockIdx.x * BN;
    float acc[4][4] = {};
    for (int k0 = 0; k0 < K; k0 += BK) {
#pragma unroll
        for (int i = 0; i < 4; ++i) {
            int idx = tid + i * 256;
            int ml = idx >> 4, kl = idx & 15;
            int gm = bm + ml, gk = k0 + kl;
            As[kl][ml] = (gm < M && gk < K) ? A[(size_t)gm * K + gk] : 0.f;
        }
#pragma unroll
        for (int i = 0; i < 4; ++i) {
            int idx = tid + i * 256;
            int kl = idx >> 6, nl = idx & 63;
            int gk = k0 + kl, gn = bn + nl;
            Bs[kl][nl] = (gk < K && gn < N) ? B[(size_t)gk * N + gn] : 0.f;
        }
        __syncthreads();
#pragma unroll
        for (int k = 0; k < BK; ++k) {
            float4 av = *(const float4*)&As[k][ty * 4];
            float4 bv = *(const float4*)&Bs[k][tx * 4];
            float a4[4] = {av.x, av.y, av.z, av.w};
            float b4[4] = {bv.x, bv.y, bv.z, bv.w};
#pragma unroll
            for (int i = 0; i < 4; ++i)
#pragma unroll
                for (int j = 0; j < 4; ++j)
                    acc[i][j] += a4[i] * b4[j];
        }
        __syncthreads();
    }
#pragma unroll
    for (int i = 0; i < 4; ++i) {
        int gm = bm + ty * 4 + i;
        if (gm >= M) continue;
        int gn0 = bn + tx * 4;
        float4 v;
        float* vp = &v.x;
#pragma unroll
        for (int j = 0; j < 4; ++j) {
            float x = acc[i][j];
            int gn = gn0 + j;
            if (bias) x += bias[gn];
            if (emb) x += emb[(size_t)nid[gm] * N + gn];
            vp[j] = x;
        }
        if (gn0 + 3 < N) *(float4*)&Cm[(size_t)gm * N + gn0] = v;
    }
}

// ---------------- W transpose + split-bf16 into MFMA-fragment tiling ------------------
// W [2,128,2048] fp32 -> WtH/WtL tiled: for n-tile u (16 cols), kc (32 k):
//   idx = dir*262144 + (u*4 + kc)*512 + lane*8 + (k&7), lane = (n&15) + 16*((k>>3)&3)
__global__ void wt_kernel(const float* __restrict__ W,
                          unsigned short* __restrict__ WtH, unsigned short* __restrict__ WtL)
{
    int gid = blockIdx.x * 256 + threadIdx.x;
    if (gid >= 2 * 128 * 2048) return;
    int dir = gid >> 18;
    int rem = gid & 262143;
    int k = rem >> 11, n = rem & 2047;   // n fast -> coalesced read
    float v = W[(size_t)dir * 262144 + (size_t)k * 2048 + n];
    unsigned short hb = f2bf(v);
    unsigned short lb = f2bf(v - bf2f(hb));
    int u = n >> 4;
    int lane = (n & 15) + 16 * ((k >> 3) & 3);
    size_t o = (size_t)dir * 262144 + ((size_t)u * 4 + (k >> 5)) * 512 + lane * 8 + (k & 7);
    WtH[o] = hb;
    WtL[o] = lb;
}

// ---------------- fused per-head projection + bias + relu + HEAD-MEAN (layers 1-2) ----
// out[m, c] = (1/16) * sum_h relu( hagg[m,h,:] @ W[:, h*128+c] + bias[h*128+c] )
// Split-bf16 MFMA. A = haggT fragment-tiled; B = WtT fragment-tiled. Every global load
// is 64 lanes x 16B fully contiguous (1 KB). grid (M/64, 2), 4 waves x 16 rows.
// Split accumulators (hi 4-chain, lo 8-chain) give 8 independent MFMA chains per wave.
__global__ __launch_bounds__(256) void gemm2r_kernel(
    const unsigned short* __restrict__ haggH, const unsigned short* __restrict__ haggL,
    const unsigned short* __restrict__ WtH, const unsigned short* __restrict__ WtL,
    const float* __restrict__ bias, float* __restrict__ out, int M)
{
    const int wave = threadIdx.x >> 6;
    const int lane = threadIdx.x & 63;
    const int cb = blockIdx.y;               // column half (0/1)
    const int m0 = blockIdx.x * 64 + wave * 16;
    const int t = m0 >> 4;                   // m-tile index
    const int row = lane & 15;               // D col within 16-col tile
    const int quad = lane >> 4;              // D row = quad*4 + r

    f32x4 mean[4] = {};

    for (int h = 0; h < 16; ++h) {
        f32x4 accH[4], accL[4];
#pragma unroll
        for (int ctl = 0; ctl < 4; ++ctl) {
            float bv = bias[h * 128 + cb * 64 + ctl * 16 + row];
            accH[ctl] = (f32x4){bv, bv, bv, bv};
            accL[ctl] = (f32x4){0.f, 0.f, 0.f, 0.f};
        }
#pragma unroll
        for (int kc = 0; kc < 4; ++kc) {
            const size_t aoff = (((size_t)t * 16 + h) * 4 + kc) * 512 + lane * 8;
            bf16x8 aH = *(const bf16x8*)(haggH + aoff);
            bf16x8 aL = *(const bf16x8*)(haggL + aoff);
#pragma unroll
            for (int ctl = 0; ctl < 4; ++ctl) {
                const int u = h * 8 + cb * 4 + ctl;
                const size_t boff = ((size_t)u * 4 + kc) * 512 + lane * 8;
                bf16x8 bH = *(const bf16x8*)(WtH + boff);
                bf16x8 bL = *(const bf16x8*)(WtL + boff);
                accH[ctl] = __builtin_amdgcn_mfma_f32_16x16x32_bf16(aH, bH, accH[ctl], 0, 0, 0);
                accL[ctl] = __builtin_amdgcn_mfma_f32_16x16x32_bf16(aH, bL, accL[ctl], 0, 0, 0);
                accL[ctl] = __builtin_amdgcn_mfma_f32_16x16x32_bf16(aL, bH, accL[ctl], 0, 0, 0);
            }
        }
#pragma unroll
        for (int ctl = 0; ctl < 4; ++ctl)
#pragma unroll
            for (int r = 0; r < 4; ++r)
                mean[ctl][r] += fmaxf(accH[ctl][r] + accL[ctl][r], 0.f);
    }

#pragma unroll
    for (int ctl = 0; ctl < 4; ++ctl) {
        int c = cb * 64 + ctl * 16 + row;
#pragma unroll
        for (int r = 0; r < 4; ++r) {
            int gm = m0 + quad * 4 + r;
            out[(size_t)gm * 128 + c] = mean[ctl][r] * (1.f / 16.f);
        }
    }
}

// ---------------- fold for ALL 3 layers: fw3[l][f][k][h] = sum_c W[k,h*C+c]*a[h,c] ----
__global__ void fold3_kernel(
    const float* __restrict__ Ws1, const float* __restrict__ Wd1,
    const float* __restrict__ as1, const float* __restrict__ ad1,
    const float* __restrict__ Ws2, const float* __restrict__ Wd2,
    const float* __restrict__ as2, const float* __restrict__ ad2,
    const float* __restrict__ Ws3, const float* __restrict__ Wd3,
    const float* __restrict__ as3, const float* __restrict__ ad3,
    float* __restrict__ fw3)
{
    int gid = blockIdx.x * blockDim.x + threadIdx.x;
    if (gid >= 3 * 4 * 128 * 16) return;
    int l = gid / 8192, rem1 = gid % 8192;
    int f = rem1 / 2048, rem = rem1 % 2048;
    int k = rem >> 4, h = rem & 15;
    int Ntot = (l == 2) ? 512 : 2048;
    int C = Ntot >> 4;
    const float* W;
    const float* a;
    if (l == 0) { W = (f & 1) ? Wd1 : Ws1; a = (f & 1) ? ad1 : as1; }
    else if (l == 1) { W = (f & 1) ? Wd2 : Ws2; a = (f & 1) ? ad2 : as2; }
    else { W = (f & 1) ? Wd3 : Ws3; a = (f & 1) ? ad3 : as3; }
    if (f >= 2) { W += 128 * Ntot; a += 16 * C; }
    float s = 0.f;
    for (int c = 0; c < C; ++c) s += W[(size_t)k * Ntot + h * C + c] * a[h * C + c];
    fw3[gid] = s;
}

// ---------------- score2: two folded projections of the same H in one pass ------------
__global__ __launch_bounds__(256) void score2_kernel(
    const float* __restrict__ Hf, const float* __restrict__ WfA, const float* __restrict__ WfB,
    float* __restrict__ outA, float* __restrict__ outB, int n)
{
    __shared__ float hs[16 * 128];
    __shared__ float wa[128 * 16];
    __shared__ float wb[128 * 16];
    int tid = threadIdx.x;
    int n0 = blockIdx.x * 16;
#pragma unroll
    for (int i = 0; i < 8; ++i) {
        int idx = tid + i * 256;
        int nl = idx >> 7, k = idx & 127;
        int gn = n0 + nl;
        hs[idx] = (gn < n) ? Hf[(size_t)gn * 128 + k] : 0.f;
        wa[idx] = WfA[idx];
        wb[idx] = WfB[idx];
    }
    __syncthreads();
    int nl = tid >> 4, h = tid & 15;
    float sa = 0.f, sb = 0.f;
    for (int k = 0; k < 128; ++k) {
        float hv = hs[nl * 128 + k];
        sa += hv * wa[k * 16 + h];
        sb += hv * wb[k * 16 + h];
    }
    int gn = n0 + nl;
    if (gn < n) { outA[gn * 16 + h] = sa; outB[gn * 16 + h] = sb; }
}

// ---------------- CSR build ----------------
__global__ void hist_kernel(const int* __restrict__ esrc, const int* __restrict__ edst,
                            int* __restrict__ degl, int* __restrict__ degd)
{
    int e = blockIdx.x * blockDim.x + threadIdx.x;
    if (e >= NE) return;
    atomicAdd(&degl[edst[e]], 1);
    atomicAdd(&degd[esrc[e]], 1);
}

__global__ __launch_bounds__(1024) void scan2_kernel(
    const int* __restrict__ degA, int* __restrict__ offA, int nA,
    const int* __restrict__ degB, int* __restrict__ offB, int nB)
{
    __shared__ int ps[1024];
    const int* deg = blockIdx.x ? degB : degA;
    int* off = blockIdx.x ? offB : offA;
    int n = blockIdx.x ? nB : nA;
    int tid = threadIdx.x;
    int chunk = (n + 1023) >> 10;
    int start = tid * chunk, end = min(start + chunk, n);
    int p = 0;
    for (int i = start; i < end; ++i) p += deg[i];
    ps[tid] = p;
    __syncthreads();
    for (int o = 1; o < 1024; o <<= 1) {
        int v = (tid >= o) ? ps[tid - o] : 0;
        __syncthreads();
        ps[tid] += v;
        __syncthreads();
    }
    int run = ps[tid] - p;
    for (int i = start; i < end; ++i) { off[i] = run; run += deg[i]; }
    if (tid == 1023) off[n] = ps[1023];
}

__global__ void scatter_kernel(const int* __restrict__ esrc, const int* __restrict__ edst,
                               const int* __restrict__ offl, const int* __restrict__ offd,
                               int* __restrict__ curl, int* __restrict__ curd,
                               int* __restrict__ csrl, int* __restrict__ csrd)
{
    int e = blockIdx.x * blockDim.x + threadIdx.x;
    if (e >= NE) return;
    int dl = edst[e]; int p = atomicAdd(&curl[dl], 1); csrl[offl[dl] + p] = e;
    int dd = esrc[e]; int q = atomicAdd(&curd[dd], 1); csrd[offd[dd] + q] = e;
}

// ---------------- fused softmax + per-head aggregation -> fragment-tiled hagg (L1-2) ---
// haggT idx for (d, h, k): t=d>>4, lane=(d&15)+16*((k>>3)&3):
//   ((t*16 + h)*4 + (k>>5))*512 + lane*8 + (k&7)
__global__ __launch_bounds__(256) void hagg_kernel(
    const float* __restrict__ hsrc,  // [n_src, 128]
    const float* __restrict__ ss,    // [n_src, 16]
    const float* __restrict__ sd,    // [n_dst, 16]
    const int* __restrict__ off, const int* __restrict__ csr, const int* __restrict__ srcidx,
    unsigned short* __restrict__ haggH, unsigned short* __restrict__ haggL)
{
    __shared__ float m_s[16], s_s[16];
    __shared__ float alpha_s[16][17];
    __shared__ int src_s[16];
    const int d = blockIdx.x;
    const int tid = threadIdx.x;
    const int e0 = off[d], e1 = off[d + 1];

    if (tid < 16) {
        int h = tid;
        float sdv = sd[d * 16 + h];
        float m = -1e30f;
        for (int e = e0; e < e1; ++e) {
            int sn = srcidx[csr[e]];
            float al = ss[sn * 16 + h] + sdv;
            al = al >= 0.f ? al : 0.2f * al;
            m = fmaxf(m, al);
        }
        float s = 0.f;
        for (int e = e0; e < e1; ++e) {
            int sn = srcidx[csr[e]];
            float al = ss[sn * 16 + h] + sdv;
            al = al >= 0.f ? al : 0.2f * al;
            s += expf(al - m);
        }
        m_s[h] = m;
        s_s[h] = s + 1e-16f;
    }
    __syncthreads();

    float acc[8] = {};
    const int c = tid & 127;
    const int hbase = (tid >> 7) * 8;

    for (int ce = e0; ce < e1; ce += 16) {
        int nc = min(16, e1 - ce);
        if (tid < nc * 16) {
            int ei = tid >> 4, h = tid & 15;
            int sn = srcidx[csr[ce + ei]];
            float al = ss[sn * 16 + h] + sd[d * 16 + h];
            al = al >= 0.f ? al : 0.2f * al;
            alpha_s[ei][h] = expf(al - m_s[h]) / s_s[h];
            if (h == 0) src_s[ei] = sn;
        }
        __syncthreads();
        for (int ei = 0; ei < nc; ++ei) {
            float v = hsrc[(size_t)src_s[ei] * 128 + c];
#pragma unroll
            for (int hh = 0; hh < 8; ++hh)
                acc[hh] += alpha_s[ei][hbase + hh] * v;
        }
        __syncthreads();
    }

    const int t = d >> 4;
    const int lane8 = ((d & 15) + 16 * ((c >> 3) & 3)) * 8 + (c & 7);
    const int kc = c >> 5;
#pragma unroll
    for (int hh = 0; hh < 8; ++hh) {
        float v = acc[hh];
        unsigned short hb = f2bf(v);
        unsigned short lb = f2bf(v - bf2f(hb));
        size_t idx = (((size_t)t * 16 + (hbase + hh)) * 4 + kc) * 512 + lane8;
        haggH[idx] = hb;
        haggL[idx] = lb;
    }
}

// ---------------- layer 3: fused softmax + gather(zs) + bias + relu + mean + penalty --
__global__ __launch_bounds__(256) void agg32_kernel(
    const float* __restrict__ zs,    // [n_src, 512]
    const float* __restrict__ ss, const float* __restrict__ sd,
    const int* __restrict__ off, const int* __restrict__ csr, const int* __restrict__ srcidx,
    const float* __restrict__ bias,  // [512]
    const float* __restrict__ pwt, const float* __restrict__ pbt,  // [32], [1]
    float* __restrict__ out)         // [n_dst, 32]
{
    __shared__ float m_s[16], s_s[16];
    __shared__ float alpha_s[16][17];
    __shared__ int src_s[16];
    __shared__ float lds_out[512];
    __shared__ float hrow[32];
    const int d = blockIdx.x;
    const int tid = threadIdx.x;
    const int e0 = off[d], e1 = off[d + 1];

    if (tid < 16) {
        int h = tid;
        float sdv = sd[d * 16 + h];
        float m = -1e30f;
        for (int e = e0; e < e1; ++e) {
            int sn = srcidx[csr[e]];
            float al = ss[sn * 16 + h] + sdv;
            al = al >= 0.f ? al : 0.2f * al;
            m = fmaxf(m, al);
        }
        float s = 0.f;
        for (int e = e0; e < e1; ++e) {
            int sn = srcidx[csr[e]];
            float al = ss[sn * 16 + h] + sdv;
            al = al >= 0.f ? al : 0.2f * al;
            s += expf(al - m);
        }
        m_s[h] = m;
        s_s[h] = s + 1e-16f;
    }
    __syncthreads();

    float acc0 = 0.f, acc1 = 0.f;
    const int hsel = tid >> 4;

    for (int ce = e0; ce < e1; ce += 16) {
        int nc = min(16, e1 - ce);
        if (tid < nc * 16) {
            int ei = tid >> 4, h = tid & 15;
            int sn = srcidx[csr[ce + ei]];
            float al = ss[sn * 16 + h] + sd[d * 16 + h];
            al = al >= 0.f ? al : 0.2f * al;
            alpha_s[ei][h] = expf(al - m_s[h]) / s_s[h];
            if (h == 0) src_s[ei] = sn;
        }
        __syncthreads();
        for (int ei = 0; ei < nc; ++ei) {
            float a = alpha_s[ei][hsel];
            float2 v = *(const float2*)(zs + (size_t)src_s[ei] * 512 + tid * 2);
            acc0 += a * v.x;
            acc1 += a * v.y;
        }
        __syncthreads();
    }

    lds_out[tid * 2] = fmaxf(acc0 + bias[tid * 2], 0.f);
    lds_out[tid * 2 + 1] = fmaxf(acc1 + bias[tid * 2 + 1], 0.f);
    __syncthreads();
    if (tid < 32) {
        float s = 0.f;
#pragma unroll
        for (int hh = 0; hh < 16; ++hh) s += lds_out[hh * 32 + tid];
        hrow[tid] = s * (1.f / 16.f);
    }
    __syncthreads();
    if (tid < 32) {
        float t = pbt[0];
#pragma unroll
        for (int c = 0; c < 32; ++c) t += hrow[c] * pwt[c];
        out[(size_t)d * 32 + tid] = hrow[tid] * expf(t);
    }
}

// ---------------- final MLP on label edges ----------------
__global__ __launch_bounds__(256) void mlp_kernel(
    const float* __restrict__ hd, const float* __restrict__ hl,
    const int* __restrict__ ls, const int* __restrict__ ld,
    const float* __restrict__ w1, const float* __restrict__ b1,
    const float* __restrict__ w2, const float* __restrict__ b2,
    float* __restrict__ out, int M)
{
    __shared__ float w1s[64 * 64];
    __shared__ float b1s[64];
    __shared__ float w2s[64];
    int tid = threadIdx.x;
#pragma unroll
    for (int i = 0; i < 16; ++i) w1s[tid + i * 256] = w1[tid + i * 256];
    if (tid < 64) { b1s[tid] = b1[tid]; w2s[tid] = w2[tid]; }
    __syncthreads();
    int m = blockIdx.x * 256 + tid;
    if (m >= M) return;
    float f[64];
    const float* hp = hd + (size_t)ls[m] * 32;
    const float* lp = hl + (size_t)ld[m] * 32;
#pragma unroll
    for (int c = 0; c < 32; ++c) { f[c] = hp[c]; f[32 + c] = lp[c]; }
    float o = b2[0];
    for (int j = 0; j < 64; ++j) {
        float hj = b1s[j];
#pragma unroll
        for (int k = 0; k < 64; ++k) hj += f[k] * w1s[k * 64 + j];
        hj = fmaxf(hj, 0.f);
        o += hj * w2s[j];
    }
    out[m] = o;
}

extern "C" void kernel_launch(void* const* d_in, const int* in_sizes, int n_in,
                              void* d_out, int out_size, void* d_ws, size_t ws_size,
                              hipStream_t stream)
{
    const float* x_d = (const float*)d_in[0];
    const float* x_l = (const float*)d_in[1];
    const int* node_id_d = (const int*)d_in[2];
    const int* node_id_l = (const int*)d_in[3];
    const int* edge_src = (const int*)d_in[4];
    const int* edge_dst = (const int*)d_in[5];
    const int* label_src = (const int*)d_in[6];
    const int* label_dst = (const int*)d_in[7];
    const float* emb_d = (const float*)d_in[8];
    const float* emb_l = (const float*)d_in[9];
    const float* lin_dw = (const float*)d_in[10];
    const float* lin_db = (const float*)d_in[11];
    const float* lin_lw = (const float*)d_in[12];
    const float* lin_lb = (const float*)d_in[13];
    const float* Ws[3] = {(const float*)d_in[14], (const float*)d_in[19], (const float*)d_in[24]};
    const float* Wd[3] = {(const float*)d_in[15], (const float*)d_in[20], (const float*)d_in[25]};
    const float* as_[3] = {(const float*)d_in[16], (const float*)d_in[21], (const float*)d_in[26]};
    const float* ad_[3] = {(const float*)d_in[17], (const float*)d_in[22], (const float*)d_in[27]};
    const float* bb[3] = {(const float*)d_in[18], (const float*)d_in[23], (const float*)d_in[28]};
    const float* pw = (const float*)d_in[29];
    const float* pb = (const float*)d_in[30];
    const float* fc1w = (const float*)d_in[31];
    const float* fc1b = (const float*)d_in[32];
    const float* fc2w = (const float*)d_in[33];
    const float* fc2b = (const float*)d_in[34];

    char* wsb = (char*)d_ws;
    size_t woff = 0;
    auto carve = [&](size_t bytes) -> void* {
        woff = (woff + 255) & ~(size_t)255;
        void* p = wsb + woff;
        woff += bytes;
        return p;
    };
    float* hdA = (float*)carve((size_t)ND * 128 * 4);
    float* hdB = (float*)carve((size_t)ND * 128 * 4);
    float* hlA = (float*)carve((size_t)NL * 128 * 4);
    float* hlB = (float*)carve((size_t)NL * 128 * 4);
    unsigned short* haggH = (unsigned short*)carve((size_t)NL * 2048 * 2);  // L3 reuses as fp32 zs [*,512]
    unsigned short* haggL = (unsigned short*)carve((size_t)NL * 2048 * 2);
    unsigned short* WtH = (unsigned short*)carve((size_t)2 * 2048 * 128 * 2);
    unsigned short* WtL = (unsigned short*)carve((size_t)2 * 2048 * 128 * 2);
    float* ssb0 = (float*)carve((size_t)ND * 16 * 4);
    float* sdb0 = (float*)carve((size_t)NL * 16 * 4);
    float* ssb1 = (float*)carve((size_t)NL * 16 * 4);
    float* sdb1 = (float*)carve((size_t)ND * 16 * 4);
    float* fw3 = (float*)carve((size_t)3 * 4 * 2048 * 4);
    int* degl = (int*)carve((size_t)(2 * (NL + ND)) * 4);
    int* degd = degl + NL;
    int* curl = degd + ND;
    int* curd = curl + NL;
    int* offl = (int*)carve((size_t)(NL + 1) * 4);
    int* offd = (int*)carve((size_t)(ND + 1) * 4);
    int* csrl = (int*)carve((size_t)NE * 4);
    int* csrd = (int*)carve((size_t)NE * 4);
    float* hdp = (float*)carve((size_t)ND * 32 * 4);
    float* hlp = (float*)carve((size_t)NL * 32 * 4);

    hipMemsetAsync(degl, 0, (size_t)2 * (NL + ND) * 4, stream);

    hist_kernel<<<(NE + 255) / 256, 256, 0, stream>>>(edge_src, edge_dst, degl, degd);
    scan2_kernel<<<2, 1024, 0, stream>>>(degl, offl, NL, degd, offd, ND);
    scatter_kernel<<<(NE + 255) / 256, 256, 0, stream>>>(edge_src, edge_dst, offl, offd, curl, curd, csrl, csrd);

    fold3_kernel<<<(3 * 8192 + 255) / 256, 256, 0, stream>>>(
        Ws[0], Wd[0], as_[0], ad_[0], Ws[1], Wd[1], as_[1], ad_[1],
        Ws[2], Wd[2], as_[2], ad_[2], fw3);

    // input linears + embedding add
    gemm_kernel<<<dim3(128 / BN, ND / BM), 256, 0, stream>>>(x_d, lin_dw, lin_db, emb_d, node_id_d, hdA, ND, 128, 412);
    gemm_kernel<<<dim3(128 / BN, NL / BM), 256, 0, stream>>>(x_l, lin_lw, lin_lb, emb_l, node_id_l, hlA, NL, 128, 240);

    float* hd_cur = hdA; float* hd_nxt = hdB;
    float* hl_cur = hlA; float* hl_nxt = hlB;

    // ---- layers 1-2: aggregate-then-project (split-bf16 MFMA, fused head-mean) ----
    for (int L = 0; L < 2; ++L) {
        const float* fw = fw3 + (size_t)L * 8192;
        wt_kernel<<<(2 * 128 * 2048 + 255) / 256, 256, 0, stream>>>(Ws[L], WtH, WtL);

        score2_kernel<<<ND / 16, 256, 0, stream>>>(hd_cur, fw + 0 * 2048, fw + 3 * 2048, ssb0, sdb1, ND);
        score2_kernel<<<NL / 16, 256, 0, stream>>>(hl_cur, fw + 1 * 2048, fw + 2 * 2048, sdb0, ssb1, NL);

        // edge type 0: disease -> lncrna (dst = lncrna)
        hagg_kernel<<<NL, 256, 0, stream>>>(hd_cur, ssb0, sdb0, offl, csrl, edge_src, haggH, haggL);
        gemm2r_kernel<<<dim3(NL / 64, 2), 256, 0, stream>>>(haggH, haggL, WtH, WtL, bb[L], hl_nxt, NL);

        // edge type 1: lncrna -> disease (dst = disease)
        hagg_kernel<<<ND, 256, 0, stream>>>(hl_cur, ssb1, sdb1, offd, csrd, edge_dst, haggH, haggL);
        gemm2r_kernel<<<dim3(ND / 64, 2), 256, 0, stream>>>(haggH, haggL,
                                                            WtH + (size_t)2048 * 128, WtL + (size_t)2048 * 128,
                                                            bb[L] + 2048, hd_nxt, ND);

        float* t;
        t = hd_cur; hd_cur = hd_nxt; hd_nxt = t;
        t = hl_cur; hl_cur = hl_nxt; hl_nxt = t;
    }

    // ---- layer 3: project-then-aggregate (fp32), fused epilogue incl. penalty ----
    {
        const float* fw = fw3 + 2 * 8192;
        float* zs3 = (float*)haggH;  // 32.8 MB needed; hagg buffers free here
        score2_kernel<<<ND / 16, 256, 0, stream>>>(hd_cur, fw + 0 * 2048, fw + 3 * 2048, ssb0, sdb1, ND);
        score2_kernel<<<NL / 16, 256, 0, stream>>>(hl_cur, fw + 1 * 2048, fw + 2 * 2048, sdb0, ssb1, NL);

        // edge type 0: zs = hd @ Ws3[0] [ND,512]; dst = lncrna -> hlp (penalty pw[1],pb[1])
        gemm_kernel<<<dim3(512 / BN, ND / BM), 256, 0, stream>>>(hd_cur, Ws[2], nullptr, nullptr, nullptr, zs3, ND, 512, 128);
        agg32_kernel<<<NL, 256, 0, stream>>>(zs3, ssb0, sdb0, offl, csrl, edge_src,
                                             bb[2], pw + 32, pb + 1, hlp);

        // edge type 1: zs = hl @ Ws3[1] [NL,512]; dst = disease -> hdp (penalty pw[0],pb[0])
        gemm_kernel<<<dim3(512 / BN, NL / BM), 256, 0, stream>>>(hl_cur, Ws[2] + 128 * 512, nullptr, nullptr, nullptr, zs3, NL, 512, 128);
        agg32_kernel<<<ND, 256, 0, stream>>>(zs3, ssb1, sdb1, offd, csrd, edge_dst,
                                             bb[2] + 512, pw, pb, hdp);
    }

    mlp_kernel<<<(NM + 255) / 256, 256, 0, stream>>>(hdp, hlp, label_src, label_dst,
                                                     fc1w, fc1b, fc2w, fc2b, (float*)d_out, NM);
}

// Round 10
// 1083.465 us; speedup vs baseline: 1.3268x; 1.1114x over previous
//
#include <hip/hip_runtime.h>
#include <cstdint>
#include <cstddef>

#define ND 8000
#define NL 16000
#define NE 60000
#define NM 50000

#define BM 64
#define BN 64
#define BK 16

typedef __attribute__((ext_vector_type(8))) short bf16x8;
typedef __attribute__((ext_vector_type(4))) float f32x4;
typedef __attribute__((ext_vector_type(8))) unsigned int u32x8;

__device__ __forceinline__ unsigned short f2bf(float x) {
    unsigned int u = __float_as_uint(x);
    unsigned int r = (u + 0x7FFFu + ((u >> 16) & 1u)) >> 16;
    return (unsigned short)r;
}
__device__ __forceinline__ float bf2f(unsigned short b) {
    return __uint_as_float(((unsigned int)b) << 16);
}

// ---------------- GEMM: C = A[M,K] @ B[K,N] (+bias[n]) (+emb[nid[m],n]) ----------------
// input linears and layer-3 zs projections
__global__ __launch_bounds__(256) void gemm_kernel(
    const float* __restrict__ A, const float* __restrict__ B,
    const float* __restrict__ bias, const float* __restrict__ emb, const int* __restrict__ nid,
    float* __restrict__ Cm, int M, int N, int K)
{
    __shared__ float As[BK][BM + 4];
    __shared__ float Bs[BK][BN + 4];
    const int tid = threadIdx.x;
    const int tx = tid & 15, ty = tid >> 4;
    const int bm = blockIdx.y * BM, bn = blockIdx.x * BN;
    float acc[4][4] = {};
    for (int k0 = 0; k0 < K; k0 += BK) {
#pragma unroll
        for (int i = 0; i < 4; ++i) {
            int idx = tid + i * 256;
            int ml = idx >> 4, kl = idx & 15;
            int gm = bm + ml, gk = k0 + kl;
            As[kl][ml] = (gm < M && gk < K) ? A[(size_t)gm * K + gk] : 0.f;
        }
#pragma unroll
        for (int i = 0; i < 4; ++i) {
            int idx = tid + i * 256;
            int kl = idx >> 6, nl = idx & 63;
            int gk = k0 + kl, gn = bn + nl;
            Bs[kl][nl] = (gk < K && gn < N) ? B[(size_t)gk * N + gn] : 0.f;
        }
        __syncthreads();
#pragma unroll
        for (int k = 0; k < BK; ++k) {
            float4 av = *(const float4*)&As[k][ty * 4];
            float4 bv = *(const float4*)&Bs[k][tx * 4];
            float a4[4] = {av.x, av.y, av.z, av.w};
            float b4[4] = {bv.x, bv.y, bv.z, bv.w};
#pragma unroll
            for (int i = 0; i < 4; ++i)
#pragma unroll
                for (int j = 0; j < 4; ++j)
                    acc[i][j] += a4[i] * b4[j];
        }
        __syncthreads();
    }
#pragma unroll
    for (int i = 0; i < 4; ++i) {
        int gm = bm + ty * 4 + i;
        if (gm >= M) continue;
        int gn0 = bn + tx * 4;
        float4 v;
        float* vp = &v.x;
#pragma unroll
        for (int j = 0; j < 4; ++j) {
            float x = acc[i][j];
            int gn = gn0 + j;
            if (bias) x += bias[gn];
            if (emb) x += emb[(size_t)nid[gm] * N + gn];
            vp[j] = x;
        }
        if (gn0 + 3 < N) *(float4*)&Cm[(size_t)gm * N + gn0] = v;
    }
}

// ---------------- W transpose + split-bf16 into MFMA-fragment tiling ------------------
// W [2,128,2048] fp32 -> WtH/WtL tiled: for n-tile u (16 cols), kc (32 k):
//   idx = dir*262144 + (u*4 + kc)*512 + lane*8 + (k&7), lane = (n&15) + 16*((k>>3)&3)
__global__ void wt_kernel(const float* __restrict__ W,
                          unsigned short* __restrict__ WtH, unsigned short* __restrict__ WtL)
{
    int gid = blockIdx.x * 256 + threadIdx.x;
    if (gid >= 2 * 128 * 2048) return;
    int dir = gid >> 18;
    int rem = gid & 262143;
    int k = rem >> 11, n = rem & 2047;   // n fast -> coalesced read
    float v = W[(size_t)dir * 262144 + (size_t)k * 2048 + n];
    unsigned short hb = f2bf(v);
    unsigned short lb = f2bf(v - bf2f(hb));
    int u = n >> 4;
    int lane = (n & 15) + 16 * ((k >> 3) & 3);
    size_t o = (size_t)dir * 262144 + ((size_t)u * 4 + (k >> 5)) * 512 + lane * 8 + (k & 7);
    WtH[o] = hb;
    WtL[o] = lb;
}

// ---------------- fused per-head projection + bias + relu + HEAD-MEAN (layers 1-2) ----
// out[m, c] = (1/16) * sum_h relu( hagg[m,h,:] @ W[:, h*128+c] + bias[h*128+c] )
// Split-bf16 MFMA. A = haggP packed (H|L<<16) fragment-tiled; B = WtH/L fragment-tiled.
// grid (M/64, 2), 4 waves x 16 rows; heads looped in-register (mean in VGPRs).
__global__ __launch_bounds__(256) void gemm2r_kernel(
    const unsigned int* __restrict__ haggP,
    const unsigned short* __restrict__ WtH, const unsigned short* __restrict__ WtL,
    const float* __restrict__ bias, float* __restrict__ out, int M)
{
    const int wave = threadIdx.x >> 6;
    const int lane = threadIdx.x & 63;
    const int cb = blockIdx.y;               // column half (0/1)
    const int m0 = blockIdx.x * 64 + wave * 16;
    const int t = m0 >> 4;                   // m-tile index
    const int row = lane & 15;               // D col within 16-col tile
    const int quad = lane >> 4;              // D row = quad*4 + r

    f32x4 mean[4] = {};

    for (int h = 0; h < 16; ++h) {
        f32x4 accH[4], accL[4];
#pragma unroll
        for (int ctl = 0; ctl < 4; ++ctl) {
            float bv = bias[h * 128 + cb * 64 + ctl * 16 + row];
            accH[ctl] = (f32x4){bv, bv, bv, bv};
            accL[ctl] = (f32x4){0.f, 0.f, 0.f, 0.f};
        }
#pragma unroll
        for (int kc = 0; kc < 4; ++kc) {
            const size_t aoff = (((size_t)t * 16 + h) * 4 + kc) * 512 + lane * 8;
            u32x8 p = *(const u32x8*)(haggP + aoff);
            bf16x8 aH, aL;
#pragma unroll
            for (int i = 0; i < 8; ++i) {
                aH[i] = (short)(p[i] & 0xffffu);
                aL[i] = (short)(p[i] >> 16);
            }
#pragma unroll
            for (int ctl = 0; ctl < 4; ++ctl) {
                const int u = h * 8 + cb * 4 + ctl;
                const size_t boff = ((size_t)u * 4 + kc) * 512 + lane * 8;
                bf16x8 bH = *(const bf16x8*)(WtH + boff);
                bf16x8 bL = *(const bf16x8*)(WtL + boff);
                accH[ctl] = __builtin_amdgcn_mfma_f32_16x16x32_bf16(aH, bH, accH[ctl], 0, 0, 0);
                accL[ctl] = __builtin_amdgcn_mfma_f32_16x16x32_bf16(aH, bL, accL[ctl], 0, 0, 0);
                accL[ctl] = __builtin_amdgcn_mfma_f32_16x16x32_bf16(aL, bH, accL[ctl], 0, 0, 0);
            }
        }
#pragma unroll
        for (int ctl = 0; ctl < 4; ++ctl)
#pragma unroll
            for (int r = 0; r < 4; ++r)
                mean[ctl][r] += fmaxf(accH[ctl][r] + accL[ctl][r], 0.f);
    }

#pragma unroll
    for (int ctl = 0; ctl < 4; ++ctl) {
        int c = cb * 64 + ctl * 16 + row;
#pragma unroll
        for (int r = 0; r < 4; ++r) {
            int gm = m0 + quad * 4 + r;
            out[(size_t)gm * 128 + c] = mean[ctl][r] * (1.f / 16.f);
        }
    }
}

// ---------------- fold for ALL 3 layers: fw3[l][f][k][h] = sum_c W[k,h*C+c]*a[h,c] ----
__global__ void fold3_kernel(
    const float* __restrict__ Ws1, const float* __restrict__ Wd1,
    const float* __restrict__ as1, const float* __restrict__ ad1,
    const float* __restrict__ Ws2, const float* __restrict__ Wd2,
    const float* __restrict__ as2, const float* __restrict__ ad2,
    const float* __restrict__ Ws3, const float* __restrict__ Wd3,
    const float* __restrict__ as3, const float* __restrict__ ad3,
    float* __restrict__ fw3)
{
    int gid = blockIdx.x * blockDim.x + threadIdx.x;
    if (gid >= 3 * 4 * 128 * 16) return;
    int l = gid / 8192, rem1 = gid % 8192;
    int f = rem1 / 2048, rem = rem1 % 2048;
    int k = rem >> 4, h = rem & 15;
    int Ntot = (l == 2) ? 512 : 2048;
    int C = Ntot >> 4;
    const float* W;
    const float* a;
    if (l == 0) { W = (f & 1) ? Wd1 : Ws1; a = (f & 1) ? ad1 : as1; }
    else if (l == 1) { W = (f & 1) ? Wd2 : Ws2; a = (f & 1) ? ad2 : as2; }
    else { W = (f & 1) ? Wd3 : Ws3; a = (f & 1) ? ad3 : as3; }
    if (f >= 2) { W += 128 * Ntot; a += 16 * C; }
    float s = 0.f;
    for (int c = 0; c < C; ++c) s += W[(size_t)k * Ntot + h * C + c] * a[h * C + c];
    fw3[gid] = s;
}

// ---------------- score2: two folded projections of the same H in one pass ------------
__global__ __launch_bounds__(256) void score2_kernel(
    const float* __restrict__ Hf, const float* __restrict__ WfA, const float* __restrict__ WfB,
    float* __restrict__ outA, float* __restrict__ outB, int n)
{
    __shared__ float hs[16 * 128];
    __shared__ float wa[128 * 16];
    __shared__ float wb[128 * 16];
    int tid = threadIdx.x;
    int n0 = blockIdx.x * 16;
#pragma unroll
    for (int i = 0; i < 8; ++i) {
        int idx = tid + i * 256;
        int nl = idx >> 7, k = idx & 127;
        int gn = n0 + nl;
        hs[idx] = (gn < n) ? Hf[(size_t)gn * 128 + k] : 0.f;
        wa[idx] = WfA[idx];
        wb[idx] = WfB[idx];
    }
    __syncthreads();
    int nl = tid >> 4, h = tid & 15;
    float sa = 0.f, sb = 0.f;
    for (int k = 0; k < 128; ++k) {
        float hv = hs[nl * 128 + k];
        sa += hv * wa[k * 16 + h];
        sb += hv * wb[k * 16 + h];
    }
    int gn = n0 + nl;
    if (gn < n) { outA[gn * 16 + h] = sa; outB[gn * 16 + h] = sb; }
}

// ---------------- CSR build ----------------
__global__ void hist_kernel(const int* __restrict__ esrc, const int* __restrict__ edst,
                            int* __restrict__ degl, int* __restrict__ degd)
{
    int e = blockIdx.x * blockDim.x + threadIdx.x;
    if (e >= NE) return;
    atomicAdd(&degl[edst[e]], 1);
    atomicAdd(&degd[esrc[e]], 1);
}

__global__ __launch_bounds__(1024) void scan2_kernel(
    const int* __restrict__ degA, int* __restrict__ offA, int nA,
    const int* __restrict__ degB, int* __restrict__ offB, int nB)
{
    __shared__ int ps[1024];
    const int* deg = blockIdx.x ? degB : degA;
    int* off = blockIdx.x ? offB : offA;
    int n = blockIdx.x ? nB : nA;
    int tid = threadIdx.x;
    int chunk = (n + 1023) >> 10;
    int start = tid * chunk, end = min(start + chunk, n);
    int p = 0;
    for (int i = start; i < end; ++i) p += deg[i];
    ps[tid] = p;
    __syncthreads();
    for (int o = 1; o < 1024; o <<= 1) {
        int v = (tid >= o) ? ps[tid - o] : 0;
        __syncthreads();
        ps[tid] += v;
        __syncthreads();
    }
    int run = ps[tid] - p;
    for (int i = start; i < end; ++i) { off[i] = run; run += deg[i]; }
    if (tid == 1023) off[n] = ps[1023];
}

__global__ void scatter_kernel(const int* __restrict__ esrc, const int* __restrict__ edst,
                               const int* __restrict__ offl, const int* __restrict__ offd,
                               int* __restrict__ curl, int* __restrict__ curd,
                               int* __restrict__ csrl, int* __restrict__ csrd)
{
    int e = blockIdx.x * blockDim.x + threadIdx.x;
    if (e >= NE) return;
    int dl = edst[e]; int p = atomicAdd(&curl[dl], 1); csrl[offl[dl] + p] = e;
    int dd = esrc[e]; int q = atomicAdd(&curd[dd], 1); csrd[offd[dd] + q] = e;
}

// ---------------- fused softmax + per-head aggregation -> packed fragment-tiled hagg ---
// TWO consecutive dst nodes per block: waves 0-1 = node d0, waves 2-3 = node d0+1
// (adjacent nodes are adjacent lanes of the fragment tile -> packed 32B runs merge into
// full 64B sectors; no write amplification). Unified trip count keeps barriers uniform.
// haggP element (d, h, k): uint = H | L<<16 at
//   ((t*16 + h)*4 + (k>>5))*512 + ((d&15)+16*((k>>3)&3))*8 + (k&7),  t = d>>4
__global__ __launch_bounds__(256) void hagg_kernel(
    const float* __restrict__ hsrc,  // [n_src, 128]
    const float* __restrict__ ss,    // [n_src, 16]
    const float* __restrict__ sd,    // [n_dst, 16]
    const int* __restrict__ off, const int* __restrict__ csr, const int* __restrict__ srcidx,
    unsigned int* __restrict__ haggP)
{
    __shared__ float m_s[2][16], s_s[2][16];
    __shared__ float alpha_s[2][8][17];
    __shared__ int src_s[2][8];
    const int d0 = blockIdx.x * 2;
    const int tid = threadIdx.x;

    if (tid < 32) {
        int nd = tid >> 4, h = tid & 15;
        int dd = d0 + nd;
        int e0 = off[dd], e1 = off[dd + 1];
        float sdv = sd[dd * 16 + h];
        float m = -1e30f;
        for (int e = e0; e < e1; ++e) {
            int sn = srcidx[csr[e]];
            float al = ss[sn * 16 + h] + sdv;
            al = al >= 0.f ? al : 0.2f * al;
            m = fmaxf(m, al);
        }
        float s = 0.f;
        for (int e = e0; e < e1; ++e) {
            int sn = srcidx[csr[e]];
            float al = ss[sn * 16 + h] + sdv;
            al = al >= 0.f ? al : 0.2f * al;
            s += expf(al - m);
        }
        m_s[nd][h] = m;
        s_s[nd][h] = s + 1e-16f;
    }
    __syncthreads();

    const int half = tid >> 7;       // node within block (wave-uniform)
    const int c = tid & 127;         // channel
    const int d = d0 + half;
    const int my_e0 = off[d];
    const int my_deg = off[d + 1] - my_e0;
    const int deg0 = off[d0 + 1] - off[d0];
    const int deg1 = off[d0 + 2] - off[d0 + 1];
    const int degmax = deg0 > deg1 ? deg0 : deg1;
    const int ntrip = (degmax + 7) >> 3;

    float acc[16];
#pragma unroll
    for (int h = 0; h < 16; ++h) acc[h] = 0.f;

    for (int trip = 0; trip < ntrip; ++trip) {
        int ce = trip * 8;
        {
            int ei = c >> 4, h = c & 15;
            if (ce + ei < my_deg) {
                int sn = srcidx[csr[my_e0 + ce + ei]];
                float al = ss[sn * 16 + h] + sd[d * 16 + h];
                al = al >= 0.f ? al : 0.2f * al;
                alpha_s[half][ei][h] = expf(al - m_s[half][h]) / s_s[half][h];
                if (h == 0) src_s[half][ei] = sn;
            }
        }
        __syncthreads();
        int nc = min(8, my_deg - ce);
        for (int ei = 0; ei < nc; ++ei) {
            float v = hsrc[(size_t)src_s[half][ei] * 128 + c];
#pragma unroll
            for (int h = 0; h < 16; ++h)
                acc[h] += alpha_s[half][ei][h] * v;
        }
        __syncthreads();
    }

    const int t = d >> 4;
    const int lane8 = ((d & 15) + 16 * ((c >> 3) & 3)) * 8 + (c & 7);
    const int kc = c >> 5;
#pragma unroll
    for (int h = 0; h < 16; ++h) {
        float v = acc[h];
        unsigned short hb = f2bf(v);
        unsigned short lb = f2bf(v - bf2f(hb));
        size_t idx = (((size_t)t * 16 + h) * 4 + kc) * 512 + lane8;
        haggP[idx] = (unsigned int)hb | ((unsigned int)lb << 16);
    }
}

// ---------------- layer 3: fused softmax + gather(zs) + bias + relu + mean + penalty --
__global__ __launch_bounds__(256) void agg32_kernel(
    const float* __restrict__ zs,    // [n_src, 512]
    const float* __restrict__ ss, const float* __restrict__ sd,
    const int* __restrict__ off, const int* __restrict__ csr, const int* __restrict__ srcidx,
    const float* __restrict__ bias,  // [512]
    const float* __restrict__ pwt, const float* __restrict__ pbt,  // [32], [1]
    float* __restrict__ out)         // [n_dst, 32]
{
    __shared__ float m_s[16], s_s[16];
    __shared__ float alpha_s[16][17];
    __shared__ int src_s[16];
    __shared__ float lds_out[512];
    __shared__ float hrow[32];
    const int d = blockIdx.x;
    const int tid = threadIdx.x;
    const int e0 = off[d], e1 = off[d + 1];

    if (tid < 16) {
        int h = tid;
        float sdv = sd[d * 16 + h];
        float m = -1e30f;
        for (int e = e0; e < e1; ++e) {
            int sn = srcidx[csr[e]];
            float al = ss[sn * 16 + h] + sdv;
            al = al >= 0.f ? al : 0.2f * al;
            m = fmaxf(m, al);
        }
        float s = 0.f;
        for (int e = e0; e < e1; ++e) {
            int sn = srcidx[csr[e]];
            float al = ss[sn * 16 + h] + sdv;
            al = al >= 0.f ? al : 0.2f * al;
            s += expf(al - m);
        }
        m_s[h] = m;
        s_s[h] = s + 1e-16f;
    }
    __syncthreads();

    float acc0 = 0.f, acc1 = 0.f;
    const int hsel = tid >> 4;

    for (int ce = e0; ce < e1; ce += 16) {
        int nc = min(16, e1 - ce);
        if (tid < nc * 16) {
            int ei = tid >> 4, h = tid & 15;
            int sn = srcidx[csr[ce + ei]];
            float al = ss[sn * 16 + h] + sd[d * 16 + h];
            al = al >= 0.f ? al : 0.2f * al;
            alpha_s[ei][h] = expf(al - m_s[h]) / s_s[h];
            if (h == 0) src_s[ei] = sn;
        }
        __syncthreads();
        for (int ei = 0; ei < nc; ++ei) {
            float a = alpha_s[ei][hsel];
            float2 v = *(const float2*)(zs + (size_t)src_s[ei] * 512 + tid * 2);
            acc0 += a * v.x;
            acc1 += a * v.y;
        }
        __syncthreads();
    }

    lds_out[tid * 2] = fmaxf(acc0 + bias[tid * 2], 0.f);
    lds_out[tid * 2 + 1] = fmaxf(acc1 + bias[tid * 2 + 1], 0.f);
    __syncthreads();
    if (tid < 32) {
        float s = 0.f;
#pragma unroll
        for (int hh = 0; hh < 16; ++hh) s += lds_out[hh * 32 + tid];
        hrow[tid] = s * (1.f / 16.f);
    }
    __syncthreads();
    if (tid < 32) {
        float t = pbt[0];
#pragma unroll
        for (int c = 0; c < 32; ++c) t += hrow[c] * pwt[c];
        out[(size_t)d * 32 + tid] = hrow[tid] * expf(t);
    }
}

// ---------------- final MLP on label edges ----------------
__global__ __launch_bounds__(256) void mlp_kernel(
    const float* __restrict__ hd, const float* __restrict__ hl,
    const int* __restrict__ ls, const int* __restrict__ ld,
    const float* __restrict__ w1, const float* __restrict__ b1,
    const float* __restrict__ w2, const float* __restrict__ b2,
    float* __restrict__ out, int M)
{
    __shared__ float w1s[64 * 64];
    __shared__ float b1s[64];
    __shared__ float w2s[64];
    int tid = threadIdx.x;
#pragma unroll
    for (int i = 0; i < 16; ++i) w1s[tid + i * 256] = w1[tid + i * 256];
    if (tid < 64) { b1s[tid] = b1[tid]; w2s[tid] = w2[tid]; }
    __syncthreads();
    int m = blockIdx.x * 256 + tid;
    if (m >= M) return;
    float f[64];
    const float* hp = hd + (size_t)ls[m] * 32;
    const float* lp = hl + (size_t)ld[m] * 32;
#pragma unroll
    for (int c = 0; c < 32; ++c) { f[c] = hp[c]; f[32 + c] = lp[c]; }
    float o = b2[0];
    for (int j = 0; j < 64; ++j) {
        float hj = b1s[j];
#pragma unroll
        for (int k = 0; k < 64; ++k) hj += f[k] * w1s[k * 64 + j];
        hj = fmaxf(hj, 0.f);
        o += hj * w2s[j];
    }
    out[m] = o;
}

extern "C" void kernel_launch(void* const* d_in, const int* in_sizes, int n_in,
                              void* d_out, int out_size, void* d_ws, size_t ws_size,
                              hipStream_t stream)
{
    const float* x_d = (const float*)d_in[0];
    const float* x_l = (const float*)d_in[1];
    const int* node_id_d = (const int*)d_in[2];
    const int* node_id_l = (const int*)d_in[3];
    const int* edge_src = (const int*)d_in[4];
    const int* edge_dst = (const int*)d_in[5];
    const int* label_src = (const int*)d_in[6];
    const int* label_dst = (const int*)d_in[7];
    const float* emb_d = (const float*)d_in[8];
    const float* emb_l = (const float*)d_in[9];
    const float* lin_dw = (const float*)d_in[10];
    const float* lin_db = (const float*)d_in[11];
    const float* lin_lw = (const float*)d_in[12];
    const float* lin_lb = (const float*)d_in[13];
    const float* Ws[3] = {(const float*)d_in[14], (const float*)d_in[19], (const float*)d_in[24]};
    const float* Wd[3] = {(const float*)d_in[15], (const float*)d_in[20], (const float*)d_in[25]};
    const float* as_[3] = {(const float*)d_in[16], (const float*)d_in[21], (const float*)d_in[26]};
    const float* ad_[3] = {(const float*)d_in[17], (const float*)d_in[22], (const float*)d_in[27]};
    const float* bb[3] = {(const float*)d_in[18], (const float*)d_in[23], (const float*)d_in[28]};
    const float* pw = (const float*)d_in[29];
    const float* pb = (const float*)d_in[30];
    const float* fc1w = (const float*)d_in[31];
    const float* fc1b = (const float*)d_in[32];
    const float* fc2w = (const float*)d_in[33];
    const float* fc2b = (const float*)d_in[34];

    char* wsb = (char*)d_ws;
    size_t woff = 0;
    auto carve = [&](size_t bytes) -> void* {
        woff = (woff + 255) & ~(size_t)255;
        void* p = wsb + woff;
        woff += bytes;
        return p;
    };
    float* hdA = (float*)carve((size_t)ND * 128 * 4);
    float* hdB = (float*)carve((size_t)ND * 128 * 4);
    float* hlA = (float*)carve((size_t)NL * 128 * 4);
    float* hlB = (float*)carve((size_t)NL * 128 * 4);
    unsigned int* haggP = (unsigned int*)carve((size_t)NL * 2048 * 4);  // L3 reuses as fp32 zs [*,512]
    unsigned short* WtH = (unsigned short*)carve((size_t)2 * 2048 * 128 * 2);
    unsigned short* WtL = (unsigned short*)carve((size_t)2 * 2048 * 128 * 2);
    float* ssb0 = (float*)carve((size_t)ND * 16 * 4);
    float* sdb0 = (float*)carve((size_t)NL * 16 * 4);
    float* ssb1 = (float*)carve((size_t)NL * 16 * 4);
    float* sdb1 = (float*)carve((size_t)ND * 16 * 4);
    float* fw3 = (float*)carve((size_t)3 * 4 * 2048 * 4);
    int* degl = (int*)carve((size_t)(2 * (NL + ND)) * 4);
    int* degd = degl + NL;
    int* curl = degd + ND;
    int* curd = curl + NL;
    int* offl = (int*)carve((size_t)(NL + 1) * 4);
    int* offd = (int*)carve((size_t)(ND + 1) * 4);
    int* csrl = (int*)carve((size_t)NE * 4);
    int* csrd = (int*)carve((size_t)NE * 4);
    float* hdp = (float*)carve((size_t)ND * 32 * 4);
    float* hlp = (float*)carve((size_t)NL * 32 * 4);

    hipMemsetAsync(degl, 0, (size_t)2 * (NL + ND) * 4, stream);

    hist_kernel<<<(NE + 255) / 256, 256, 0, stream>>>(edge_src, edge_dst, degl, degd);
    scan2_kernel<<<2, 1024, 0, stream>>>(degl, offl, NL, degd, offd, ND);
    scatter_kernel<<<(NE + 255) / 256, 256, 0, stream>>>(edge_src, edge_dst, offl, offd, curl, curd, csrl, csrd);

    fold3_kernel<<<(3 * 8192 + 255) / 256, 256, 0, stream>>>(
        Ws[0], Wd[0], as_[0], ad_[0], Ws[1], Wd[1], as_[1], ad_[1],
        Ws[2], Wd[2], as_[2], ad_[2], fw3);

    // input linears + embedding add
    gemm_kernel<<<dim3(128 / BN, ND / BM), 256, 0, stream>>>(x_d, lin_dw, lin_db, emb_d, node_id_d, hdA, ND, 128, 412);
    gemm_kernel<<<dim3(128 / BN, NL / BM), 256, 0, stream>>>(x_l, lin_lw, lin_lb, emb_l, node_id_l, hlA, NL, 128, 240);

    float* hd_cur = hdA; float* hd_nxt = hdB;
    float* hl_cur = hlA; float* hl_nxt = hlB;

    // ---- layers 1-2: aggregate-then-project (split-bf16 MFMA, fused head-mean) ----
    for (int L = 0; L < 2; ++L) {
        const float* fw = fw3 + (size_t)L * 8192;
        wt_kernel<<<(2 * 128 * 2048 + 255) / 256, 256, 0, stream>>>(Ws[L], WtH, WtL);

        score2_kernel<<<ND / 16, 256, 0, stream>>>(hd_cur, fw + 0 * 2048, fw + 3 * 2048, ssb0, sdb1, ND);
        score2_kernel<<<NL / 16, 256, 0, stream>>>(hl_cur, fw + 1 * 2048, fw + 2 * 2048, sdb0, ssb1, NL);

        // edge type 0: disease -> lncrna (dst = lncrna)
        hagg_kernel<<<NL / 2, 256, 0, stream>>>(hd_cur, ssb0, sdb0, offl, csrl, edge_src, haggP);
        gemm2r_kernel<<<dim3(NL / 64, 2), 256, 0, stream>>>(haggP, WtH, WtL, bb[L], hl_nxt, NL);

        // edge type 1: lncrna -> disease (dst = disease)
        hagg_kernel<<<ND / 2, 256, 0, stream>>>(hl_cur, ssb1, sdb1, offd, csrd, edge_dst, haggP);
        gemm2r_kernel<<<dim3(ND / 64, 2), 256, 0, stream>>>(haggP,
                                                            WtH + (size_t)2048 * 128, WtL + (size_t)2048 * 128,
                                                            bb[L] + 2048, hd_nxt, ND);

        float* t;
        t = hd_cur; hd_cur = hd_nxt; hd_nxt = t;
        t = hl_cur; hl_cur = hl_nxt; hl_nxt = t;
    }

    // ---- layer 3: project-then-aggregate (fp32), fused epilogue incl. penalty ----
    {
        const float* fw = fw3 + 2 * 8192;
        float* zs3 = (float*)haggP;  // 32.8 MB needed; hagg buffer free here
        score2_kernel<<<ND / 16, 256, 0, stream>>>(hd_cur, fw + 0 * 2048, fw + 3 * 2048, ssb0, sdb1, ND);
        score2_kernel<<<NL / 16, 256, 0, stream>>>(hl_cur, fw + 1 * 2048, fw + 2 * 2048, sdb0, ssb1, NL);

        // edge type 0: zs = hd @ Ws3[0] [ND,512]; dst = lncrna -> hlp (penalty pw[1],pb[1])
        gemm_kernel<<<dim3(512 / BN, ND / BM), 256, 0, stream>>>(hd_cur, Ws[2], nullptr, nullptr, nullptr, zs3, ND, 512, 128);
        agg32_kernel<<<NL, 256, 0, stream>>>(zs3, ssb0, sdb0, offl, csrl, edge_src,
                                             bb[2], pw + 32, pb + 1, hlp);

        // edge type 1: zs = hl @ Ws3[1] [NL,512]; dst = disease -> hdp (penalty pw[0],pb[0])
        gemm_kernel<<<dim3(512 / BN, NL / BM), 256, 0, stream>>>(hl_cur, Ws[2] + 128 * 512, nullptr, nullptr, nullptr, zs3, NL, 512, 128);
        agg32_kernel<<<ND, 256, 0, stream>>>(zs3, ssb1, sdb1, offd, csrd, edge_dst,
                                             bb[2] + 512, pw, pb, hdp);
    }

    mlp_kernel<<<(NM + 255) / 256, 256, 0, stream>>>(hdp, hlp, label_src, label_dst,
                                                     fc1w, fc1b, fc2w, fc2b, (float*)d_out, NM);
}

// Round 11
// 1046.358 us; speedup vs baseline: 1.3739x; 1.0355x over previous
//
#include <hip/hip_runtime.h>
#include <cstdint>
#include <cstddef>

#define ND 8000
#define NL 16000
#define NE 60000
#define NM 50000

#define BM 64
#define BN 64
#define BK 16

typedef __attribute__((ext_vector_type(8))) short bf16x8;
typedef __attribute__((ext_vector_type(4))) float f32x4;
typedef __attribute__((ext_vector_type(8))) unsigned int u32x8;

__device__ __forceinline__ unsigned short f2bf(float x) {
    unsigned int u = __float_as_uint(x);
    unsigned int r = (u + 0x7FFFu + ((u >> 16) & 1u)) >> 16;
    return (unsigned short)r;
}
__device__ __forceinline__ float bf2f(unsigned short b) {
    return __uint_as_float(((unsigned int)b) << 16);
}

// ---------------- GEMM: C = A[M,K] @ B[K,N] (layer-3 zs projections only) --------------
__global__ __launch_bounds__(256) void gemm_kernel(
    const float* __restrict__ A, const float* __restrict__ B,
    float* __restrict__ Cm, int M, int N, int K)
{
    __shared__ float As[BK][BM + 4];
    __shared__ float Bs[BK][BN + 4];
    const int tid = threadIdx.x;
    const int tx = tid & 15, ty = tid >> 4;
    const int bm = blockIdx.y * BM, bn = blockIdx.x * BN;
    float acc[4][4] = {};
    for (int k0 = 0; k0 < K; k0 += BK) {
#pragma unroll
        for (int i = 0; i < 4; ++i) {
            int idx = tid + i * 256;
            int ml = idx >> 4, kl = idx & 15;
            int gm = bm + ml, gk = k0 + kl;
            As[kl][ml] = (gm < M && gk < K) ? A[(size_t)gm * K + gk] : 0.f;
        }
#pragma unroll
        for (int i = 0; i < 4; ++i) {
            int idx = tid + i * 256;
            int kl = idx >> 6, nl = idx & 63;
            int gk = k0 + kl, gn = bn + nl;
            Bs[kl][nl] = (gk < K && gn < N) ? B[(size_t)gk * N + gn] : 0.f;
        }
        __syncthreads();
#pragma unroll
        for (int k = 0; k < BK; ++k) {
            float4 av = *(const float4*)&As[k][ty * 4];
            float4 bv = *(const float4*)&Bs[k][tx * 4];
            float a4[4] = {av.x, av.y, av.z, av.w};
            float b4[4] = {bv.x, bv.y, bv.z, bv.w};
#pragma unroll
            for (int i = 0; i < 4; ++i)
#pragma unroll
                for (int j = 0; j < 4; ++j)
                    acc[i][j] += a4[i] * b4[j];
        }
        __syncthreads();
    }
#pragma unroll
    for (int i = 0; i < 4; ++i) {
        int gm = bm + ty * 4 + i;
        if (gm >= M) continue;
        int gn0 = bn + tx * 4;
        float4 v;
        float* vp = &v.x;
#pragma unroll
        for (int j = 0; j < 4; ++j) vp[j] = acc[i][j];
        if (gn0 + 3 < N) *(float4*)&Cm[(size_t)gm * N + gn0] = v;
    }
}

// ---------------- fused split-K input linears: hd AND hl in one dispatch ---------------
// out[m,n] += partial( x[m, kz] @ W[kz, n] ), chunk 0 also adds bias[n] + emb[nid[m], n].
// grid (2, 125+250, 4); matrix 1 (x_l) uses only z<2. Outputs must be pre-zeroed.
__global__ __launch_bounds__(256) void inlin_kernel(
    const float* __restrict__ x_d, const float* __restrict__ x_l,
    const float* __restrict__ wd, const float* __restrict__ wl,
    const float* __restrict__ bd, const float* __restrict__ bl,
    const float* __restrict__ embd, const float* __restrict__ embl,
    const int* __restrict__ nidd, const int* __restrict__ nidl,
    float* __restrict__ hd, float* __restrict__ hl)
{
    __shared__ float As[BK][BM + 4];
    __shared__ float Bs[BK][BN + 4];
    int mt = blockIdx.y;
    const float* A; const float* B; const float* bias; const float* emb;
    const int* nid; float* out;
    int K, KC;
    if (mt < 125) {
        A = x_d; B = wd; bias = bd; emb = embd; nid = nidd; out = hd; K = 412; KC = 103;
    } else {
        if (blockIdx.z >= 2) return;
        mt -= 125;
        A = x_l; B = wl; bias = bl; emb = embl; nid = nidl; out = hl; K = 240; KC = 120;
    }
    const int k_begin = blockIdx.z * KC;
    const int k_end = min(k_begin + KC, K);
    const int tid = threadIdx.x;
    const int tx = tid & 15, ty = tid >> 4;
    const int bm = mt * BM, bn = blockIdx.x * BN;
    float acc[4][4] = {};
    for (int k0 = k_begin; k0 < k_end; k0 += BK) {
#pragma unroll
        for (int i = 0; i < 4; ++i) {
            int idx = tid + i * 256;
            int ml = idx >> 4, kl = idx & 15;
            int gk = k0 + kl;
            As[kl][ml] = (gk < k_end) ? A[(size_t)(bm + ml) * K + gk] : 0.f;
        }
#pragma unroll
        for (int i = 0; i < 4; ++i) {
            int idx = tid + i * 256;
            int kl = idx >> 6, nl = idx & 63;
            int gk = k0 + kl;
            Bs[kl][nl] = (gk < k_end) ? B[(size_t)gk * 128 + bn + nl] : 0.f;
        }
        __syncthreads();
#pragma unroll
        for (int k = 0; k < BK; ++k) {
            float4 av = *(const float4*)&As[k][ty * 4];
            float4 bv = *(const float4*)&Bs[k][tx * 4];
            float a4[4] = {av.x, av.y, av.z, av.w};
            float b4[4] = {bv.x, bv.y, bv.z, bv.w};
#pragma unroll
            for (int i = 0; i < 4; ++i)
#pragma unroll
                for (int j = 0; j < 4; ++j)
                    acc[i][j] += a4[i] * b4[j];
        }
        __syncthreads();
    }
#pragma unroll
    for (int i = 0; i < 4; ++i) {
        int gm = bm + ty * 4 + i;
#pragma unroll
        for (int j = 0; j < 4; ++j) {
            int gn = bn + tx * 4 + j;
            float x = acc[i][j];
            if (blockIdx.z == 0) x += bias[gn] + emb[(size_t)nid[gm] * 128 + gn];
            atomicAdd(&out[(size_t)gm * 128 + gn], x);
        }
    }
}

// ---------------- W transpose + split-bf16 into MFMA-fragment tiling, BOTH layers ------
// W[l] [2,128,2048] fp32 -> WtH/WtL [l][dir][u*4+kc][512]:
//   lane = (n&15) + 16*((k>>3)&3); idx = l*524288 + dir*262144 + (u*4+(k>>5))*512 + lane*8 + (k&7)
__global__ void wt2_kernel(const float* __restrict__ W0, const float* __restrict__ W1,
                           unsigned short* __restrict__ WtH, unsigned short* __restrict__ WtL)
{
    int gid = blockIdx.x * 256 + threadIdx.x;
    if (gid >= 2 * 2 * 128 * 2048) return;
    int l = gid >> 19;
    int rem0 = gid & 524287;
    int dir = rem0 >> 18;
    int rem = rem0 & 262143;
    int k = rem >> 11, n = rem & 2047;   // n fast -> coalesced read
    const float* W = l ? W1 : W0;
    float v = W[(size_t)dir * 262144 + (size_t)k * 2048 + n];
    unsigned short hb = f2bf(v);
    unsigned short lb = f2bf(v - bf2f(hb));
    int u = n >> 4;
    int lane = (n & 15) + 16 * ((k >> 3) & 3);
    size_t o = (size_t)l * 524288 + (size_t)dir * 262144 +
               ((size_t)u * 4 + (k >> 5)) * 512 + lane * 8 + (k & 7);
    WtH[o] = hb;
    WtL[o] = lb;
}

// ---------------- fused per-head projection + bias + relu + HEAD-MEAN (layers 1-2) ----
// out[m, c] = (1/16) * sum_h relu( hagg[m,h,:] @ W[:, h*128+c] + bias[h*128+c] )
// Split-bf16 MFMA. A = haggP packed (H|L<<16) fragment-tiled; B = WtH/L fragment-tiled.
// grid (M/64, 2), 4 waves x 16 rows; heads looped in-register (mean in VGPRs).
__global__ __launch_bounds__(256) void gemm2r_kernel(
    const unsigned int* __restrict__ haggP,
    const unsigned short* __restrict__ WtH, const unsigned short* __restrict__ WtL,
    const float* __restrict__ bias, float* __restrict__ out, int M)
{
    const int wave = threadIdx.x >> 6;
    const int lane = threadIdx.x & 63;
    const int cb = blockIdx.y;               // column half (0/1)
    const int m0 = blockIdx.x * 64 + wave * 16;
    const int t = m0 >> 4;                   // m-tile index
    const int row = lane & 15;               // D col within 16-col tile
    const int quad = lane >> 4;              // D row = quad*4 + r

    f32x4 mean[4] = {};

    for (int h = 0; h < 16; ++h) {
        f32x4 accH[4], accL[4];
#pragma unroll
        for (int ctl = 0; ctl < 4; ++ctl) {
            float bv = bias[h * 128 + cb * 64 + ctl * 16 + row];
            accH[ctl] = (f32x4){bv, bv, bv, bv};
            accL[ctl] = (f32x4){0.f, 0.f, 0.f, 0.f};
        }
#pragma unroll
        for (int kc = 0; kc < 4; ++kc) {
            const size_t aoff = (((size_t)t * 16 + h) * 4 + kc) * 512 + lane * 8;
            u32x8 p = *(const u32x8*)(haggP + aoff);
            bf16x8 aH, aL;
#pragma unroll
            for (int i = 0; i < 8; ++i) {
                aH[i] = (short)(p[i] & 0xffffu);
                aL[i] = (short)(p[i] >> 16);
            }
#pragma unroll
            for (int ctl = 0; ctl < 4; ++ctl) {
                const int u = h * 8 + cb * 4 + ctl;
                const size_t boff = ((size_t)u * 4 + kc) * 512 + lane * 8;
                bf16x8 bH = *(const bf16x8*)(WtH + boff);
                bf16x8 bL = *(const bf16x8*)(WtL + boff);
                accH[ctl] = __builtin_amdgcn_mfma_f32_16x16x32_bf16(aH, bH, accH[ctl], 0, 0, 0);
                accL[ctl] = __builtin_amdgcn_mfma_f32_16x16x32_bf16(aH, bL, accL[ctl], 0, 0, 0);
                accL[ctl] = __builtin_amdgcn_mfma_f32_16x16x32_bf16(aL, bH, accL[ctl], 0, 0, 0);
            }
        }
#pragma unroll
        for (int ctl = 0; ctl < 4; ++ctl)
#pragma unroll
            for (int r = 0; r < 4; ++r)
                mean[ctl][r] += fmaxf(accH[ctl][r] + accL[ctl][r], 0.f);
    }

#pragma unroll
    for (int ctl = 0; ctl < 4; ++ctl) {
        int c = cb * 64 + ctl * 16 + row;
#pragma unroll
        for (int r = 0; r < 4; ++r) {
            int gm = m0 + quad * 4 + r;
            out[(size_t)gm * 128 + c] = mean[ctl][r] * (1.f / 16.f);
        }
    }
}

// ---------------- fold for ALL 3 layers: fw3[l][f][k][h] = sum_c W[k,h*C+c]*a[h,c] ----
__global__ void fold3_kernel(
    const float* __restrict__ Ws1, const float* __restrict__ Wd1,
    const float* __restrict__ as1, const float* __restrict__ ad1,
    const float* __restrict__ Ws2, const float* __restrict__ Wd2,
    const float* __restrict__ as2, const float* __restrict__ ad2,
    const float* __restrict__ Ws3, const float* __restrict__ Wd3,
    const float* __restrict__ as3, const float* __restrict__ ad3,
    float* __restrict__ fw3)
{
    int gid = blockIdx.x * blockDim.x + threadIdx.x;
    if (gid >= 3 * 4 * 128 * 16) return;
    int l = gid / 8192, rem1 = gid % 8192;
    int f = rem1 / 2048, rem = rem1 % 2048;
    int k = rem >> 4, h = rem & 15;
    int Ntot = (l == 2) ? 512 : 2048;
    int C = Ntot >> 4;
    const float* W;
    const float* a;
    if (l == 0) { W = (f & 1) ? Wd1 : Ws1; a = (f & 1) ? ad1 : as1; }
    else if (l == 1) { W = (f & 1) ? Wd2 : Ws2; a = (f & 1) ? ad2 : as2; }
    else { W = (f & 1) ? Wd3 : Ws3; a = (f & 1) ? ad3 : as3; }
    if (f >= 2) { W += 128 * Ntot; a += 16 * C; }
    float s = 0.f;
    for (int c = 0; c < C; ++c) s += W[(size_t)k * Ntot + h * C + c] * a[h * C + c];
    fw3[gid] = s;
}

// ---------------- score2both: all four folded scores of a layer in one dispatch --------
// blocks [0, ND/16): hd -> ssb0, sdb1 ; blocks [ND/16, ND/16+NL/16): hl -> sdb0, ssb1
__global__ __launch_bounds__(256) void score2both_kernel(
    const float* __restrict__ Hd, const float* __restrict__ Hl,
    const float* __restrict__ fw,   // layer base [4][128][16]
    float* __restrict__ ssb0, float* __restrict__ sdb1,
    float* __restrict__ sdb0, float* __restrict__ ssb1)
{
    __shared__ float hs[16 * 128];
    __shared__ float wa[128 * 16];
    __shared__ float wb[128 * 16];
    int b = blockIdx.x;
    const float* Hf; const float* WfA; const float* WfB;
    float* outA; float* outB; int n0;
    if (b < ND / 16) {
        Hf = Hd; WfA = fw; WfB = fw + 3 * 2048; outA = ssb0; outB = sdb1; n0 = b * 16;
    } else {
        Hf = Hl; WfA = fw + 1 * 2048; WfB = fw + 2 * 2048; outA = sdb0; outB = ssb1;
        n0 = (b - ND / 16) * 16;
    }
    int tid = threadIdx.x;
#pragma unroll
    for (int i = 0; i < 8; ++i) {
        int idx = tid + i * 256;
        int nl = idx >> 7, k = idx & 127;
        hs[idx] = Hf[(size_t)(n0 + nl) * 128 + k];
        wa[idx] = WfA[idx];
        wb[idx] = WfB[idx];
    }
    __syncthreads();
    int nl = tid >> 4, h = tid & 15;
    float sa = 0.f, sb = 0.f;
    for (int k = 0; k < 128; ++k) {
        float hv = hs[nl * 128 + k];
        sa += hv * wa[k * 16 + h];
        sb += hv * wb[k * 16 + h];
    }
    int gn = n0 + nl;
    outA[gn * 16 + h] = sa;
    outB[gn * 16 + h] = sb;
}

// ---------------- CSR build ----------------
__global__ void hist_kernel(const int* __restrict__ esrc, const int* __restrict__ edst,
                            int* __restrict__ degl, int* __restrict__ degd)
{
    int e = blockIdx.x * blockDim.x + threadIdx.x;
    if (e >= NE) return;
    atomicAdd(&degl[edst[e]], 1);
    atomicAdd(&degd[esrc[e]], 1);
}

__global__ __launch_bounds__(1024) void scan2_kernel(
    const int* __restrict__ degA, int* __restrict__ offA, int nA,
    const int* __restrict__ degB, int* __restrict__ offB, int nB)
{
    __shared__ int ps[1024];
    const int* deg = blockIdx.x ? degB : degA;
    int* off = blockIdx.x ? offB : offA;
    int n = blockIdx.x ? nB : nA;
    int tid = threadIdx.x;
    int chunk = (n + 1023) >> 10;
    int start = tid * chunk, end = min(start + chunk, n);
    int p = 0;
    for (int i = start; i < end; ++i) p += deg[i];
    ps[tid] = p;
    __syncthreads();
    for (int o = 1; o < 1024; o <<= 1) {
        int v = (tid >= o) ? ps[tid - o] : 0;
        __syncthreads();
        ps[tid] += v;
        __syncthreads();
    }
    int run = ps[tid] - p;
    for (int i = start; i < end; ++i) { off[i] = run; run += deg[i]; }
    if (tid == 1023) off[n] = ps[1023];
}

__global__ void scatter_kernel(const int* __restrict__ esrc, const int* __restrict__ edst,
                               const int* __restrict__ offl, const int* __restrict__ offd,
                               int* __restrict__ curl, int* __restrict__ curd,
                               int* __restrict__ csrl, int* __restrict__ csrd)
{
    int e = blockIdx.x * blockDim.x + threadIdx.x;
    if (e >= NE) return;
    int dl = edst[e]; int p = atomicAdd(&curl[dl], 1); csrl[offl[dl] + p] = e;
    int dd = esrc[e]; int q = atomicAdd(&curd[dd], 1); csrd[offd[dd] + q] = e;
}

// ---------------- fused softmax + per-head aggregation -> packed fragment-tiled hagg ---
// TWO consecutive dst nodes per block (waves 0-1 node d0, waves 2-3 node d0+1).
__global__ __launch_bounds__(256) void hagg_kernel(
    const float* __restrict__ hsrc,  // [n_src, 128]
    const float* __restrict__ ss,    // [n_src, 16]
    const float* __restrict__ sd,    // [n_dst, 16]
    const int* __restrict__ off, const int* __restrict__ csr, const int* __restrict__ srcidx,
    unsigned int* __restrict__ haggP)
{
    __shared__ float m_s[2][16], s_s[2][16];
    __shared__ float alpha_s[2][8][17];
    __shared__ int src_s[2][8];
    const int d0 = blockIdx.x * 2;
    const int tid = threadIdx.x;

    if (tid < 32) {
        int nd = tid >> 4, h = tid & 15;
        int dd = d0 + nd;
        int e0 = off[dd], e1 = off[dd + 1];
        float sdv = sd[dd * 16 + h];
        float m = -1e30f;
        for (int e = e0; e < e1; ++e) {
            int sn = srcidx[csr[e]];
            float al = ss[sn * 16 + h] + sdv;
            al = al >= 0.f ? al : 0.2f * al;
            m = fmaxf(m, al);
        }
        float s = 0.f;
        for (int e = e0; e < e1; ++e) {
            int sn = srcidx[csr[e]];
            float al = ss[sn * 16 + h] + sdv;
            al = al >= 0.f ? al : 0.2f * al;
            s += expf(al - m);
        }
        m_s[nd][h] = m;
        s_s[nd][h] = s + 1e-16f;
    }
    __syncthreads();

    const int half = tid >> 7;       // node within block (wave-uniform)
    const int c = tid & 127;         // channel
    const int d = d0 + half;
    const int my_e0 = off[d];
    const int my_deg = off[d + 1] - my_e0;
    const int deg0 = off[d0 + 1] - off[d0];
    const int deg1 = off[d0 + 2] - off[d0 + 1];
    const int degmax = deg0 > deg1 ? deg0 : deg1;
    const int ntrip = (degmax + 7) >> 3;

    float acc[16];
#pragma unroll
    for (int h = 0; h < 16; ++h) acc[h] = 0.f;

    for (int trip = 0; trip < ntrip; ++trip) {
        int ce = trip * 8;
        {
            int ei = c >> 4, h = c & 15;
            if (ce + ei < my_deg) {
                int sn = srcidx[csr[my_e0 + ce + ei]];
                float al = ss[sn * 16 + h] + sd[d * 16 + h];
                al = al >= 0.f ? al : 0.2f * al;
                alpha_s[half][ei][h] = expf(al - m_s[half][h]) / s_s[half][h];
                if (h == 0) src_s[half][ei] = sn;
            }
        }
        __syncthreads();
        int nc = min(8, my_deg - ce);
        for (int ei = 0; ei < nc; ++ei) {
            float v = hsrc[(size_t)src_s[half][ei] * 128 + c];
#pragma unroll
            for (int h = 0; h < 16; ++h)
                acc[h] += alpha_s[half][ei][h] * v;
        }
        __syncthreads();
    }

    const int t = d >> 4;
    const int lane8 = ((d & 15) + 16 * ((c >> 3) & 3)) * 8 + (c & 7);
    const int kc = c >> 5;
#pragma unroll
    for (int h = 0; h < 16; ++h) {
        float v = acc[h];
        unsigned short hb = f2bf(v);
        unsigned short lb = f2bf(v - bf2f(hb));
        size_t idx = (((size_t)t * 16 + h) * 4 + kc) * 512 + lane8;
        haggP[idx] = (unsigned int)hb | ((unsigned int)lb << 16);
    }
}

// ---------------- layer 3: fused softmax + gather(zs) + bias + relu + mean + penalty --
__global__ __launch_bounds__(256) void agg32_kernel(
    const float* __restrict__ zs,    // [n_src, 512]
    const float* __restrict__ ss, const float* __restrict__ sd,
    const int* __restrict__ off, const int* __restrict__ csr, const int* __restrict__ srcidx,
    const float* __restrict__ bias,  // [512]
    const float* __restrict__ pwt, const float* __restrict__ pbt,  // [32], [1]
    float* __restrict__ out)         // [n_dst, 32]
{
    __shared__ float m_s[16], s_s[16];
    __shared__ float alpha_s[16][17];
    __shared__ int src_s[16];
    __shared__ float lds_out[512];
    __shared__ float hrow[32];
    const int d = blockIdx.x;
    const int tid = threadIdx.x;
    const int e0 = off[d], e1 = off[d + 1];

    if (tid < 16) {
        int h = tid;
        float sdv = sd[d * 16 + h];
        float m = -1e30f;
        for (int e = e0; e < e1; ++e) {
            int sn = srcidx[csr[e]];
            float al = ss[sn * 16 + h] + sdv;
            al = al >= 0.f ? al : 0.2f * al;
            m = fmaxf(m, al);
        }
        float s = 0.f;
        for (int e = e0; e < e1; ++e) {
            int sn = srcidx[csr[e]];
            float al = ss[sn * 16 + h] + sdv;
            al = al >= 0.f ? al : 0.2f * al;
            s += expf(al - m);
        }
        m_s[h] = m;
        s_s[h] = s + 1e-16f;
    }
    __syncthreads();

    float acc0 = 0.f, acc1 = 0.f;
    const int hsel = tid >> 4;

    for (int ce = e0; ce < e1; ce += 16) {
        int nc = min(16, e1 - ce);
        if (tid < nc * 16) {
            int ei = tid >> 4, h = tid & 15;
            int sn = srcidx[csr[ce + ei]];
            float al = ss[sn * 16 + h] + sd[d * 16 + h];
            al = al >= 0.f ? al : 0.2f * al;
            alpha_s[ei][h] = expf(al - m_s[h]) / s_s[h];
            if (h == 0) src_s[ei] = sn;
        }
        __syncthreads();
        for (int ei = 0; ei < nc; ++ei) {
            float a = alpha_s[ei][hsel];
            float2 v = *(const float2*)(zs + (size_t)src_s[ei] * 512 + tid * 2);
            acc0 += a * v.x;
            acc1 += a * v.y;
        }
        __syncthreads();
    }

    lds_out[tid * 2] = fmaxf(acc0 + bias[tid * 2], 0.f);
    lds_out[tid * 2 + 1] = fmaxf(acc1 + bias[tid * 2 + 1], 0.f);
    __syncthreads();
    if (tid < 32) {
        float s = 0.f;
#pragma unroll
        for (int hh = 0; hh < 16; ++hh) s += lds_out[hh * 32 + tid];
        hrow[tid] = s * (1.f / 16.f);
    }
    __syncthreads();
    if (tid < 32) {
        float t = pbt[0];
#pragma unroll
        for (int c = 0; c < 32; ++c) t += hrow[c] * pwt[c];
        out[(size_t)d * 32 + tid] = hrow[tid] * expf(t);
    }
}

// ---------------- final MLP on label edges ----------------
__global__ __launch_bounds__(256) void mlp_kernel(
    const float* __restrict__ hd, const float* __restrict__ hl,
    const int* __restrict__ ls, const int* __restrict__ ld,
    const float* __restrict__ w1, const float* __restrict__ b1,
    const float* __restrict__ w2, const float* __restrict__ b2,
    float* __restrict__ out, int M)
{
    __shared__ float w1s[64 * 64];
    __shared__ float b1s[64];
    __shared__ float w2s[64];
    int tid = threadIdx.x;
#pragma unroll
    for (int i = 0; i < 16; ++i) w1s[tid + i * 256] = w1[tid + i * 256];
    if (tid < 64) { b1s[tid] = b1[tid]; w2s[tid] = w2[tid]; }
    __syncthreads();
    int m = blockIdx.x * 256 + tid;
    if (m >= M) return;
    float f[64];
    const float* hp = hd + (size_t)ls[m] * 32;
    const float* lp = hl + (size_t)ld[m] * 32;
#pragma unroll
    for (int c = 0; c < 32; ++c) { f[c] = hp[c]; f[32 + c] = lp[c]; }
    float o = b2[0];
    for (int j = 0; j < 64; ++j) {
        float hj = b1s[j];
#pragma unroll
        for (int k = 0; k < 64; ++k) hj += f[k] * w1s[k * 64 + j];
        hj = fmaxf(hj, 0.f);
        o += hj * w2s[j];
    }
    out[m] = o;
}

extern "C" void kernel_launch(void* const* d_in, const int* in_sizes, int n_in,
                              void* d_out, int out_size, void* d_ws, size_t ws_size,
                              hipStream_t stream)
{
    const float* x_d = (const float*)d_in[0];
    const float* x_l = (const float*)d_in[1];
    const int* node_id_d = (const int*)d_in[2];
    const int* node_id_l = (const int*)d_in[3];
    const int* edge_src = (const int*)d_in[4];
    const int* edge_dst = (const int*)d_in[5];
    const int* label_src = (const int*)d_in[6];
    const int* label_dst = (const int*)d_in[7];
    const float* emb_d = (const float*)d_in[8];
    const float* emb_l = (const float*)d_in[9];
    const float* lin_dw = (const float*)d_in[10];
    const float* lin_db = (const float*)d_in[11];
    const float* lin_lw = (const float*)d_in[12];
    const float* lin_lb = (const float*)d_in[13];
    const float* Ws[3] = {(const float*)d_in[14], (const float*)d_in[19], (const float*)d_in[24]};
    const float* Wd[3] = {(const float*)d_in[15], (const float*)d_in[20], (const float*)d_in[25]};
    const float* as_[3] = {(const float*)d_in[16], (const float*)d_in[21], (const float*)d_in[26]};
    const float* ad_[3] = {(const float*)d_in[17], (const float*)d_in[22], (const float*)d_in[27]};
    const float* bb[3] = {(const float*)d_in[18], (const float*)d_in[23], (const float*)d_in[28]};
    const float* pw = (const float*)d_in[29];
    const float* pb = (const float*)d_in[30];
    const float* fc1w = (const float*)d_in[31];
    const float* fc1b = (const float*)d_in[32];
    const float* fc2w = (const float*)d_in[33];
    const float* fc2b = (const float*)d_in[34];

    char* wsb = (char*)d_ws;
    size_t woff = 0;
    auto carve = [&](size_t bytes) -> void* {
        woff = (woff + 255) & ~(size_t)255;
        void* p = wsb + woff;
        woff += bytes;
        return p;
    };
    // hdA and hlA adjacent -> single memset covers both
    float* hdA = (float*)carve((size_t)ND * 128 * 4);
    float* hlA = (float*)carve((size_t)NL * 128 * 4);
    float* hdB = (float*)carve((size_t)ND * 128 * 4);
    float* hlB = (float*)carve((size_t)NL * 128 * 4);
    unsigned int* haggP = (unsigned int*)carve((size_t)NL * 2048 * 4);  // L3 reuses as fp32 zs [*,512]
    unsigned short* WtH = (unsigned short*)carve((size_t)2 * 2 * 2048 * 128 * 2);  // [layer][dir]
    unsigned short* WtL = (unsigned short*)carve((size_t)2 * 2 * 2048 * 128 * 2);
    float* ssb0 = (float*)carve((size_t)ND * 16 * 4);
    float* sdb0 = (float*)carve((size_t)NL * 16 * 4);
    float* ssb1 = (float*)carve((size_t)NL * 16 * 4);
    float* sdb1 = (float*)carve((size_t)ND * 16 * 4);
    float* fw3 = (float*)carve((size_t)3 * 4 * 2048 * 4);
    int* degl = (int*)carve((size_t)(2 * (NL + ND)) * 4);
    int* degd = degl + NL;
    int* curl = degd + ND;
    int* curd = curl + NL;
    int* offl = (int*)carve((size_t)(NL + 1) * 4);
    int* offd = (int*)carve((size_t)(ND + 1) * 4);
    int* csrl = (int*)carve((size_t)NE * 4);
    int* csrd = (int*)carve((size_t)NE * 4);
    float* hdp = (float*)carve((size_t)ND * 32 * 4);
    float* hlp = (float*)carve((size_t)NL * 32 * 4);

    hipMemsetAsync(degl, 0, (size_t)2 * (NL + ND) * 4, stream);
    hipMemsetAsync(hdA, 0, (size_t)(ND + NL) * 128 * 4, stream);  // hdA+hlA contiguous

    hist_kernel<<<(NE + 255) / 256, 256, 0, stream>>>(edge_src, edge_dst, degl, degd);
    scan2_kernel<<<2, 1024, 0, stream>>>(degl, offl, NL, degd, offd, ND);
    scatter_kernel<<<(NE + 255) / 256, 256, 0, stream>>>(edge_src, edge_dst, offl, offd, curl, curd, csrl, csrd);

    fold3_kernel<<<(3 * 8192 + 255) / 256, 256, 0, stream>>>(
        Ws[0], Wd[0], as_[0], ad_[0], Ws[1], Wd[1], as_[1], ad_[1],
        Ws[2], Wd[2], as_[2], ad_[2], fw3);
    wt2_kernel<<<(2 * 524288 + 255) / 256, 256, 0, stream>>>(Ws[0], Ws[1], WtH, WtL);

    // input linears + embedding add (split-K, both matrices, one dispatch)
    inlin_kernel<<<dim3(2, 375, 4), 256, 0, stream>>>(
        x_d, x_l, lin_dw, lin_lw, lin_db, lin_lb, emb_d, emb_l,
        node_id_d, node_id_l, hdA, hlA);

    float* hd_cur = hdA; float* hd_nxt = hdB;
    float* hl_cur = hlA; float* hl_nxt = hlB;

    // ---- layers 1-2: aggregate-then-project (split-bf16 MFMA, fused head-mean) ----
    for (int L = 0; L < 2; ++L) {
        const float* fw = fw3 + (size_t)L * 8192;
        const unsigned short* wtH = WtH + (size_t)L * 524288;
        const unsigned short* wtL = WtL + (size_t)L * 524288;

        score2both_kernel<<<ND / 16 + NL / 16, 256, 0, stream>>>(
            hd_cur, hl_cur, fw, ssb0, sdb1, sdb0, ssb1);

        // edge type 0: disease -> lncrna (dst = lncrna)
        hagg_kernel<<<NL / 2, 256, 0, stream>>>(hd_cur, ssb0, sdb0, offl, csrl, edge_src, haggP);
        gemm2r_kernel<<<dim3(NL / 64, 2), 256, 0, stream>>>(haggP, wtH, wtL, bb[L], hl_nxt, NL);

        // edge type 1: lncrna -> disease (dst = disease)
        hagg_kernel<<<ND / 2, 256, 0, stream>>>(hl_cur, ssb1, sdb1, offd, csrd, edge_dst, haggP);
        gemm2r_kernel<<<dim3(ND / 64, 2), 256, 0, stream>>>(haggP,
                                                            wtH + (size_t)2048 * 128, wtL + (size_t)2048 * 128,
                                                            bb[L] + 2048, hd_nxt, ND);

        float* t;
        t = hd_cur; hd_cur = hd_nxt; hd_nxt = t;
        t = hl_cur; hl_cur = hl_nxt; hl_nxt = t;
    }

    // ---- layer 3: project-then-aggregate (fp32), fused epilogue incl. penalty ----
    {
        const float* fw = fw3 + 2 * 8192;
        float* zs3 = (float*)haggP;  // 32.8 MB needed; hagg buffer free here
        score2both_kernel<<<ND / 16 + NL / 16, 256, 0, stream>>>(
            hd_cur, hl_cur, fw, ssb0, sdb1, sdb0, ssb1);

        // edge type 0: zs = hd @ Ws3[0] [ND,512]; dst = lncrna -> hlp (penalty pw[1],pb[1])
        gemm_kernel<<<dim3(512 / BN, ND / BM), 256, 0, stream>>>(hd_cur, Ws[2], zs3, ND, 512, 128);
        agg32_kernel<<<NL, 256, 0, stream>>>(zs3, ssb0, sdb0, offl, csrl, edge_src,
                                             bb[2], pw + 32, pb + 1, hlp);

        // edge type 1: zs = hl @ Ws3[1] [NL,512]; dst = disease -> hdp (penalty pw[0],pb[0])
        gemm_kernel<<<dim3(512 / BN, NL / BM), 256, 0, stream>>>(hl_cur, Ws[2] + 128 * 512, zs3, NL, 512, 128);
        agg32_kernel<<<ND, 256, 0, stream>>>(zs3, ssb1, sdb1, offd, csrd, edge_dst,
                                             bb[2] + 512, pw, pb, hdp);
    }

    mlp_kernel<<<(NM + 255) / 256, 256, 0, stream>>>(hdp, hlp, label_src, label_dst,
                                                     fc1w, fc1b, fc2w, fc2b, (float*)d_out, NM);
}

// Round 12
// 983.897 us; speedup vs baseline: 1.4611x; 1.0635x over previous
//
#include <hip/hip_runtime.h>
#include <cstdint>
#include <cstddef>

#define ND 8000
#define NL 16000
#define NE 60000
#define NM 50000

#define BM 64
#define BN 64
#define BK 16

typedef __attribute__((ext_vector_type(8))) short bf16x8;
typedef __attribute__((ext_vector_type(4))) float f32x4;
typedef __attribute__((ext_vector_type(8))) unsigned int u32x8;

__device__ __forceinline__ unsigned short f2bf(float x) {
    unsigned int u = __float_as_uint(x);
    unsigned int r = (u + 0x7FFFu + ((u >> 16) & 1u)) >> 16;
    return (unsigned short)r;
}
__device__ __forceinline__ float bf2f(unsigned short b) {
    return __uint_as_float(((unsigned int)b) << 16);
}

// ---------------- GEMM: C = A[M,K] @ B[K,N] (layer-3 zs projections only) --------------
__global__ __launch_bounds__(256) void gemm_kernel(
    const float* __restrict__ A, const float* __restrict__ B,
    float* __restrict__ Cm, int M, int N, int K)
{
    __shared__ float As[BK][BM + 4];
    __shared__ float Bs[BK][BN + 4];
    const int tid = threadIdx.x;
    const int tx = tid & 15, ty = tid >> 4;
    const int bm = blockIdx.y * BM, bn = blockIdx.x * BN;
    float acc[4][4] = {};
    for (int k0 = 0; k0 < K; k0 += BK) {
#pragma unroll
        for (int i = 0; i < 4; ++i) {
            int idx = tid + i * 256;
            int ml = idx >> 4, kl = idx & 15;
            int gm = bm + ml, gk = k0 + kl;
            As[kl][ml] = (gm < M && gk < K) ? A[(size_t)gm * K + gk] : 0.f;
        }
#pragma unroll
        for (int i = 0; i < 4; ++i) {
            int idx = tid + i * 256;
            int kl = idx >> 6, nl = idx & 63;
            int gk = k0 + kl, gn = bn + nl;
            Bs[kl][nl] = (gk < K && gn < N) ? B[(size_t)gk * N + gn] : 0.f;
        }
        __syncthreads();
#pragma unroll
        for (int k = 0; k < BK; ++k) {
            float4 av = *(const float4*)&As[k][ty * 4];
            float4 bv = *(const float4*)&Bs[k][tx * 4];
            float a4[4] = {av.x, av.y, av.z, av.w};
            float b4[4] = {bv.x, bv.y, bv.z, bv.w};
#pragma unroll
            for (int i = 0; i < 4; ++i)
#pragma unroll
                for (int j = 0; j < 4; ++j)
                    acc[i][j] += a4[i] * b4[j];
        }
        __syncthreads();
    }
#pragma unroll
    for (int i = 0; i < 4; ++i) {
        int gm = bm + ty * 4 + i;
        if (gm >= M) continue;
        int gn0 = bn + tx * 4;
        float4 v;
        float* vp = &v.x;
#pragma unroll
        for (int j = 0; j < 4; ++j) vp[j] = acc[i][j];
        if (gn0 + 3 < N) *(float4*)&Cm[(size_t)gm * N + gn0] = v;
    }
}

// ---------------- fused input linears: hd AND hl in one dispatch (no split-K) ----------
// out[m,n] = x[m,:] @ W[:,n] + bias[n] + emb[nid[m], n]; direct stores, no atomics.
// grid (2, 125+250): blocks [0,125) -> x_d (K=412), [125,375) -> x_l (K=240).
__global__ __launch_bounds__(256) void inlin_kernel(
    const float* __restrict__ x_d, const float* __restrict__ x_l,
    const float* __restrict__ wd, const float* __restrict__ wl,
    const float* __restrict__ bd, const float* __restrict__ bl,
    const float* __restrict__ embd, const float* __restrict__ embl,
    const int* __restrict__ nidd, const int* __restrict__ nidl,
    float* __restrict__ hd, float* __restrict__ hl)
{
    __shared__ float As[BK][BM + 4];
    __shared__ float Bs[BK][BN + 4];
    int mt = blockIdx.y;
    const float* A; const float* B; const float* bias; const float* emb;
    const int* nid; float* out;
    int K;
    if (mt < 125) {
        A = x_d; B = wd; bias = bd; emb = embd; nid = nidd; out = hd; K = 412;
    } else {
        mt -= 125;
        A = x_l; B = wl; bias = bl; emb = embl; nid = nidl; out = hl; K = 240;
    }
    const int tid = threadIdx.x;
    const int tx = tid & 15, ty = tid >> 4;
    const int bm = mt * BM, bn = blockIdx.x * BN;
    float acc[4][4] = {};
    for (int k0 = 0; k0 < K; k0 += BK) {
#pragma unroll
        for (int i = 0; i < 4; ++i) {
            int idx = tid + i * 256;
            int ml = idx >> 4, kl = idx & 15;
            int gk = k0 + kl;
            As[kl][ml] = (gk < K) ? A[(size_t)(bm + ml) * K + gk] : 0.f;
        }
#pragma unroll
        for (int i = 0; i < 4; ++i) {
            int idx = tid + i * 256;
            int kl = idx >> 6, nl = idx & 63;
            int gk = k0 + kl;
            Bs[kl][nl] = (gk < K) ? B[(size_t)gk * 128 + bn + nl] : 0.f;
        }
        __syncthreads();
#pragma unroll
        for (int k = 0; k < BK; ++k) {
            float4 av = *(const float4*)&As[k][ty * 4];
            float4 bv = *(const float4*)&Bs[k][tx * 4];
            float a4[4] = {av.x, av.y, av.z, av.w};
            float b4[4] = {bv.x, bv.y, bv.z, bv.w};
#pragma unroll
            for (int i = 0; i < 4; ++i)
#pragma unroll
                for (int j = 0; j < 4; ++j)
                    acc[i][j] += a4[i] * b4[j];
        }
        __syncthreads();
    }
#pragma unroll
    for (int i = 0; i < 4; ++i) {
        int gm = bm + ty * 4 + i;
        int gn0 = bn + tx * 4;
        const float* ep = emb + (size_t)nid[gm] * 128 + gn0;
        float4 v;
        float* vp = &v.x;
#pragma unroll
        for (int j = 0; j < 4; ++j)
            vp[j] = acc[i][j] + bias[gn0 + j] + ep[j];
        *(float4*)&out[(size_t)gm * 128 + gn0] = v;
    }
}

// ---------------- W transpose + split-bf16 into MFMA-fragment tiling, BOTH layers ------
__global__ void wt2_kernel(const float* __restrict__ W0, const float* __restrict__ W1,
                           unsigned short* __restrict__ WtH, unsigned short* __restrict__ WtL)
{
    int gid = blockIdx.x * 256 + threadIdx.x;
    if (gid >= 2 * 2 * 128 * 2048) return;
    int l = gid >> 19;
    int rem0 = gid & 524287;
    int dir = rem0 >> 18;
    int rem = rem0 & 262143;
    int k = rem >> 11, n = rem & 2047;   // n fast -> coalesced read
    const float* W = l ? W1 : W0;
    float v = W[(size_t)dir * 262144 + (size_t)k * 2048 + n];
    unsigned short hb = f2bf(v);
    unsigned short lb = f2bf(v - bf2f(hb));
    int u = n >> 4;
    int lane = (n & 15) + 16 * ((k >> 3) & 3);
    size_t o = (size_t)l * 524288 + (size_t)dir * 262144 +
               ((size_t)u * 4 + (k >> 5)) * 512 + lane * 8 + (k & 7);
    WtH[o] = hb;
    WtL[o] = lb;
}

// ---------------- fused per-head projection + bias + relu + HEAD-MEAN (layers 1-2) ----
__global__ __launch_bounds__(256) void gemm2r_kernel(
    const unsigned int* __restrict__ haggP,
    const unsigned short* __restrict__ WtH, const unsigned short* __restrict__ WtL,
    const float* __restrict__ bias, float* __restrict__ out, int M)
{
    const int wave = threadIdx.x >> 6;
    const int lane = threadIdx.x & 63;
    const int cb = blockIdx.y;               // column half (0/1)
    const int m0 = blockIdx.x * 64 + wave * 16;
    const int t = m0 >> 4;                   // m-tile index
    const int row = lane & 15;               // D col within 16-col tile
    const int quad = lane >> 4;              // D row = quad*4 + r

    f32x4 mean[4] = {};

    for (int h = 0; h < 16; ++h) {
        f32x4 accH[4], accL[4];
#pragma unroll
        for (int ctl = 0; ctl < 4; ++ctl) {
            float bv = bias[h * 128 + cb * 64 + ctl * 16 + row];
            accH[ctl] = (f32x4){bv, bv, bv, bv};
            accL[ctl] = (f32x4){0.f, 0.f, 0.f, 0.f};
        }
#pragma unroll
        for (int kc = 0; kc < 4; ++kc) {
            const size_t aoff = (((size_t)t * 16 + h) * 4 + kc) * 512 + lane * 8;
            u32x8 p = *(const u32x8*)(haggP + aoff);
            bf16x8 aH, aL;
#pragma unroll
            for (int i = 0; i < 8; ++i) {
                aH[i] = (short)(p[i] & 0xffffu);
                aL[i] = (short)(p[i] >> 16);
            }
#pragma unroll
            for (int ctl = 0; ctl < 4; ++ctl) {
                const int u = h * 8 + cb * 4 + ctl;
                const size_t boff = ((size_t)u * 4 + kc) * 512 + lane * 8;
                bf16x8 bH = *(const bf16x8*)(WtH + boff);
                bf16x8 bL = *(const bf16x8*)(WtL + boff);
                accH[ctl] = __builtin_amdgcn_mfma_f32_16x16x32_bf16(aH, bH, accH[ctl], 0, 0, 0);
                accL[ctl] = __builtin_amdgcn_mfma_f32_16x16x32_bf16(aH, bL, accL[ctl], 0, 0, 0);
                accL[ctl] = __builtin_amdgcn_mfma_f32_16x16x32_bf16(aL, bH, accL[ctl], 0, 0, 0);
            }
        }
#pragma unroll
        for (int ctl = 0; ctl < 4; ++ctl)
#pragma unroll
            for (int r = 0; r < 4; ++r)
                mean[ctl][r] += fmaxf(accH[ctl][r] + accL[ctl][r], 0.f);
    }

#pragma unroll
    for (int ctl = 0; ctl < 4; ++ctl) {
        int c = cb * 64 + ctl * 16 + row;
#pragma unroll
        for (int r = 0; r < 4; ++r) {
            int gm = m0 + quad * 4 + r;
            out[(size_t)gm * 128 + c] = mean[ctl][r] * (1.f / 16.f);
        }
    }
}

// ---------------- fold for ALL 3 layers: fw3[l][f][k][h] = sum_c W[k,h*C+c]*a[h,c] ----
__global__ void fold3_kernel(
    const float* __restrict__ Ws1, const float* __restrict__ Wd1,
    const float* __restrict__ as1, const float* __restrict__ ad1,
    const float* __restrict__ Ws2, const float* __restrict__ Wd2,
    const float* __restrict__ as2, const float* __restrict__ ad2,
    const float* __restrict__ Ws3, const float* __restrict__ Wd3,
    const float* __restrict__ as3, const float* __restrict__ ad3,
    float* __restrict__ fw3)
{
    int gid = blockIdx.x * blockDim.x + threadIdx.x;
    if (gid >= 3 * 4 * 128 * 16) return;
    int l = gid / 8192, rem1 = gid % 8192;
    int f = rem1 / 2048, rem = rem1 % 2048;
    int k = rem >> 4, h = rem & 15;
    int Ntot = (l == 2) ? 512 : 2048;
    int C = Ntot >> 4;
    const float* W;
    const float* a;
    if (l == 0) { W = (f & 1) ? Wd1 : Ws1; a = (f & 1) ? ad1 : as1; }
    else if (l == 1) { W = (f & 1) ? Wd2 : Ws2; a = (f & 1) ? ad2 : as2; }
    else { W = (f & 1) ? Wd3 : Ws3; a = (f & 1) ? ad3 : as3; }
    if (f >= 2) { W += 128 * Ntot; a += 16 * C; }
    float s = 0.f;
    for (int c = 0; c < C; ++c) s += W[(size_t)k * Ntot + h * C + c] * a[h * C + c];
    fw3[gid] = s;
}

// ---------------- score2both: all four folded scores of a layer in one dispatch --------
__global__ __launch_bounds__(256) void score2both_kernel(
    const float* __restrict__ Hd, const float* __restrict__ Hl,
    const float* __restrict__ fw,   // layer base [4][128][16]
    float* __restrict__ ssb0, float* __restrict__ sdb1,
    float* __restrict__ sdb0, float* __restrict__ ssb1)
{
    __shared__ float hs[16 * 128];
    __shared__ float wa[128 * 16];
    __shared__ float wb[128 * 16];
    int b = blockIdx.x;
    const float* Hf; const float* WfA; const float* WfB;
    float* outA; float* outB; int n0;
    if (b < ND / 16) {
        Hf = Hd; WfA = fw; WfB = fw + 3 * 2048; outA = ssb0; outB = sdb1; n0 = b * 16;
    } else {
        Hf = Hl; WfA = fw + 1 * 2048; WfB = fw + 2 * 2048; outA = sdb0; outB = ssb1;
        n0 = (b - ND / 16) * 16;
    }
    int tid = threadIdx.x;
#pragma unroll
    for (int i = 0; i < 8; ++i) {
        int idx = tid + i * 256;
        int nl = idx >> 7, k = idx & 127;
        hs[idx] = Hf[(size_t)(n0 + nl) * 128 + k];
        wa[idx] = WfA[idx];
        wb[idx] = WfB[idx];
    }
    __syncthreads();
    int nl = tid >> 4, h = tid & 15;
    float sa = 0.f, sb = 0.f;
    for (int k = 0; k < 128; ++k) {
        float hv = hs[nl * 128 + k];
        sa += hv * wa[k * 16 + h];
        sb += hv * wb[k * 16 + h];
    }
    int gn = n0 + nl;
    outA[gn * 16 + h] = sa;
    outB[gn * 16 + h] = sb;
}

// ---------------- CSR build ----------------
__global__ void hist_kernel(const int* __restrict__ esrc, const int* __restrict__ edst,
                            int* __restrict__ degl, int* __restrict__ degd)
{
    int e = blockIdx.x * blockDim.x + threadIdx.x;
    if (e >= NE) return;
    atomicAdd(&degl[edst[e]], 1);
    atomicAdd(&degd[esrc[e]], 1);
}

__global__ __launch_bounds__(1024) void scan2_kernel(
    const int* __restrict__ degA, int* __restrict__ offA, int nA,
    const int* __restrict__ degB, int* __restrict__ offB, int nB)
{
    __shared__ int ps[1024];
    const int* deg = blockIdx.x ? degB : degA;
    int* off = blockIdx.x ? offB : offA;
    int n = blockIdx.x ? nB : nA;
    int tid = threadIdx.x;
    int chunk = (n + 1023) >> 10;
    int start = tid * chunk, end = min(start + chunk, n);
    int p = 0;
    for (int i = start; i < end; ++i) p += deg[i];
    ps[tid] = p;
    __syncthreads();
    for (int o = 1; o < 1024; o <<= 1) {
        int v = (tid >= o) ? ps[tid - o] : 0;
        __syncthreads();
        ps[tid] += v;
        __syncthreads();
    }
    int run = ps[tid] - p;
    for (int i = start; i < end; ++i) { off[i] = run; run += deg[i]; }
    if (tid == 1023) off[n] = ps[1023];
}

__global__ void scatter_kernel(const int* __restrict__ esrc, const int* __restrict__ edst,
                               const int* __restrict__ offl, const int* __restrict__ offd,
                               int* __restrict__ curl, int* __restrict__ curd,
                               int* __restrict__ csrl, int* __restrict__ csrd)
{
    int e = blockIdx.x * blockDim.x + threadIdx.x;
    if (e >= NE) return;
    int dl = edst[e]; int p = atomicAdd(&curl[dl], 1); csrl[offl[dl] + p] = e;
    int dd = esrc[e]; int q = atomicAdd(&curd[dd], 1); csrd[offd[dd] + q] = e;
}

// ---------------- fused softmax + per-head aggregation -> packed fragment-tiled hagg ---
__global__ __launch_bounds__(256) void hagg_kernel(
    const float* __restrict__ hsrc,  // [n_src, 128]
    const float* __restrict__ ss,    // [n_src, 16]
    const float* __restrict__ sd,    // [n_dst, 16]
    const int* __restrict__ off, const int* __restrict__ csr, const int* __restrict__ srcidx,
    unsigned int* __restrict__ haggP)
{
    __shared__ float m_s[2][16], s_s[2][16];
    __shared__ float alpha_s[2][8][17];
    __shared__ int src_s[2][8];
    const int d0 = blockIdx.x * 2;
    const int tid = threadIdx.x;

    if (tid < 32) {
        int nd = tid >> 4, h = tid & 15;
        int dd = d0 + nd;
        int e0 = off[dd], e1 = off[dd + 1];
        float sdv = sd[dd * 16 + h];
        float m = -1e30f;
        for (int e = e0; e < e1; ++e) {
            int sn = srcidx[csr[e]];
            float al = ss[sn * 16 + h] + sdv;
            al = al >= 0.f ? al : 0.2f * al;
            m = fmaxf(m, al);
        }
        float s = 0.f;
        for (int e = e0; e < e1; ++e) {
            int sn = srcidx[csr[e]];
            float al = ss[sn * 16 + h] + sdv;
            al = al >= 0.f ? al : 0.2f * al;
            s += expf(al - m);
        }
        m_s[nd][h] = m;
        s_s[nd][h] = s + 1e-16f;
    }
    __syncthreads();

    const int half = tid >> 7;       // node within block (wave-uniform)
    const int c = tid & 127;         // channel
    const int d = d0 + half;
    const int my_e0 = off[d];
    const int my_deg = off[d + 1] - my_e0;
    const int deg0 = off[d0 + 1] - off[d0];
    const int deg1 = off[d0 + 2] - off[d0 + 1];
    const int degmax = deg0 > deg1 ? deg0 : deg1;
    const int ntrip = (degmax + 7) >> 3;

    float acc[16];
#pragma unroll
    for (int h = 0; h < 16; ++h) acc[h] = 0.f;

    for (int trip = 0; trip < ntrip; ++trip) {
        int ce = trip * 8;
        {
            int ei = c >> 4, h = c & 15;
            if (ce + ei < my_deg) {
                int sn = srcidx[csr[my_e0 + ce + ei]];
                float al = ss[sn * 16 + h] + sd[d * 16 + h];
                al = al >= 0.f ? al : 0.2f * al;
                alpha_s[half][ei][h] = expf(al - m_s[half][h]) / s_s[half][h];
                if (h == 0) src_s[half][ei] = sn;
            }
        }
        __syncthreads();
        int nc = min(8, my_deg - ce);
        for (int ei = 0; ei < nc; ++ei) {
            float v = hsrc[(size_t)src_s[half][ei] * 128 + c];
#pragma unroll
            for (int h = 0; h < 16; ++h)
                acc[h] += alpha_s[half][ei][h] * v;
        }
        __syncthreads();
    }

    const int t = d >> 4;
    const int lane8 = ((d & 15) + 16 * ((c >> 3) & 3)) * 8 + (c & 7);
    const int kc = c >> 5;
#pragma unroll
    for (int h = 0; h < 16; ++h) {
        float v = acc[h];
        unsigned short hb = f2bf(v);
        unsigned short lb = f2bf(v - bf2f(hb));
        size_t idx = (((size_t)t * 16 + h) * 4 + kc) * 512 + lane8;
        haggP[idx] = (unsigned int)hb | ((unsigned int)lb << 16);
    }
}

// ---------------- layer 3: fused softmax + gather(zs) + bias + relu + mean + penalty --
__global__ __launch_bounds__(256) void agg32_kernel(
    const float* __restrict__ zs,    // [n_src, 512]
    const float* __restrict__ ss, const float* __restrict__ sd,
    const int* __restrict__ off, const int* __restrict__ csr, const int* __restrict__ srcidx,
    const float* __restrict__ bias,  // [512]
    const float* __restrict__ pwt, const float* __restrict__ pbt,  // [32], [1]
    float* __restrict__ out)         // [n_dst, 32]
{
    __shared__ float m_s[16], s_s[16];
    __shared__ float alpha_s[16][17];
    __shared__ int src_s[16];
    __shared__ float lds_out[512];
    __shared__ float hrow[32];
    const int d = blockIdx.x;
    const int tid = threadIdx.x;
    const int e0 = off[d], e1 = off[d + 1];

    if (tid < 16) {
        int h = tid;
        float sdv = sd[d * 16 + h];
        float m = -1e30f;
        for (int e = e0; e < e1; ++e) {
            int sn = srcidx[csr[e]];
            float al = ss[sn * 16 + h] + sdv;
            al = al >= 0.f ? al : 0.2f * al;
            m = fmaxf(m, al);
        }
        float s = 0.f;
        for (int e = e0; e < e1; ++e) {
            int sn = srcidx[csr[e]];
            float al = ss[sn * 16 + h] + sdv;
            al = al >= 0.f ? al : 0.2f * al;
            s += expf(al - m);
        }
        m_s[h] = m;
        s_s[h] = s + 1e-16f;
    }
    __syncthreads();

    float acc0 = 0.f, acc1 = 0.f;
    const int hsel = tid >> 4;

    for (int ce = e0; ce < e1; ce += 16) {
        int nc = min(16, e1 - ce);
        if (tid < nc * 16) {
            int ei = tid >> 4, h = tid & 15;
            int sn = srcidx[csr[ce + ei]];
            float al = ss[sn * 16 + h] + sd[d * 16 + h];
            al = al >= 0.f ? al : 0.2f * al;
            alpha_s[ei][h] = expf(al - m_s[h]) / s_s[h];
            if (h == 0) src_s[ei] = sn;
        }
        __syncthreads();
        for (int ei = 0; ei < nc; ++ei) {
            float a = alpha_s[ei][hsel];
            float2 v = *(const float2*)(zs + (size_t)src_s[ei] * 512 + tid * 2);
            acc0 += a * v.x;
            acc1 += a * v.y;
        }
        __syncthreads();
    }

    lds_out[tid * 2] = fmaxf(acc0 + bias[tid * 2], 0.f);
    lds_out[tid * 2 + 1] = fmaxf(acc1 + bias[tid * 2 + 1], 0.f);
    __syncthreads();
    if (tid < 32) {
        float s = 0.f;
#pragma unroll
        for (int hh = 0; hh < 16; ++hh) s += lds_out[hh * 32 + tid];
        hrow[tid] = s * (1.f / 16.f);
    }
    __syncthreads();
    if (tid < 32) {
        float t = pbt[0];
#pragma unroll
        for (int c = 0; c < 32; ++c) t += hrow[c] * pwt[c];
        out[(size_t)d * 32 + tid] = hrow[tid] * expf(t);
    }
}

// ---------------- final MLP on label edges ----------------
__global__ __launch_bounds__(256) void mlp_kernel(
    const float* __restrict__ hd, const float* __restrict__ hl,
    const int* __restrict__ ls, const int* __restrict__ ld,
    const float* __restrict__ w1, const float* __restrict__ b1,
    const float* __restrict__ w2, const float* __restrict__ b2,
    float* __restrict__ out, int M)
{
    __shared__ float w1s[64 * 64];
    __shared__ float b1s[64];
    __shared__ float w2s[64];
    int tid = threadIdx.x;
#pragma unroll
    for (int i = 0; i < 16; ++i) w1s[tid + i * 256] = w1[tid + i * 256];
    if (tid < 64) { b1s[tid] = b1[tid]; w2s[tid] = w2[tid]; }
    __syncthreads();
    int m = blockIdx.x * 256 + tid;
    if (m >= M) return;
    float f[64];
    const float* hp = hd + (size_t)ls[m] * 32;
    const float* lp = hl + (size_t)ld[m] * 32;
#pragma unroll
    for (int c = 0; c < 32; ++c) { f[c] = hp[c]; f[32 + c] = lp[c]; }
    float o = b2[0];
    for (int j = 0; j < 64; ++j) {
        float hj = b1s[j];
#pragma unroll
        for (int k = 0; k < 64; ++k) hj += f[k] * w1s[k * 64 + j];
        hj = fmaxf(hj, 0.f);
        o += hj * w2s[j];
    }
    out[m] = o;
}

extern "C" void kernel_launch(void* const* d_in, const int* in_sizes, int n_in,
                              void* d_out, int out_size, void* d_ws, size_t ws_size,
                              hipStream_t stream)
{
    const float* x_d = (const float*)d_in[0];
    const float* x_l = (const float*)d_in[1];
    const int* node_id_d = (const int*)d_in[2];
    const int* node_id_l = (const int*)d_in[3];
    const int* edge_src = (const int*)d_in[4];
    const int* edge_dst = (const int*)d_in[5];
    const int* label_src = (const int*)d_in[6];
    const int* label_dst = (const int*)d_in[7];
    const float* emb_d = (const float*)d_in[8];
    const float* emb_l = (const float*)d_in[9];
    const float* lin_dw = (const float*)d_in[10];
    const float* lin_db = (const float*)d_in[11];
    const float* lin_lw = (const float*)d_in[12];
    const float* lin_lb = (const float*)d_in[13];
    const float* Ws[3] = {(const float*)d_in[14], (const float*)d_in[19], (const float*)d_in[24]};
    const float* Wd[3] = {(const float*)d_in[15], (const float*)d_in[20], (const float*)d_in[25]};
    const float* as_[3] = {(const float*)d_in[16], (const float*)d_in[21], (const float*)d_in[26]};
    const float* ad_[3] = {(const float*)d_in[17], (const float*)d_in[22], (const float*)d_in[27]};
    const float* bb[3] = {(const float*)d_in[18], (const float*)d_in[23], (const float*)d_in[28]};
    const float* pw = (const float*)d_in[29];
    const float* pb = (const float*)d_in[30];
    const float* fc1w = (const float*)d_in[31];
    const float* fc1b = (const float*)d_in[32];
    const float* fc2w = (const float*)d_in[33];
    const float* fc2b = (const float*)d_in[34];

    char* wsb = (char*)d_ws;
    size_t woff = 0;
    auto carve = [&](size_t bytes) -> void* {
        woff = (woff + 255) & ~(size_t)255;
        void* p = wsb + woff;
        woff += bytes;
        return p;
    };
    float* hdA = (float*)carve((size_t)ND * 128 * 4);
    float* hlA = (float*)carve((size_t)NL * 128 * 4);
    float* hdB = (float*)carve((size_t)ND * 128 * 4);
    float* hlB = (float*)carve((size_t)NL * 128 * 4);
    unsigned int* haggP = (unsigned int*)carve((size_t)NL * 2048 * 4);  // L3 reuses as fp32 zs [*,512]
    unsigned short* WtH = (unsigned short*)carve((size_t)2 * 2 * 2048 * 128 * 2);  // [layer][dir]
    unsigned short* WtL = (unsigned short*)carve((size_t)2 * 2 * 2048 * 128 * 2);
    float* ssb0 = (float*)carve((size_t)ND * 16 * 4);
    float* sdb0 = (float*)carve((size_t)NL * 16 * 4);
    float* ssb1 = (float*)carve((size_t)NL * 16 * 4);
    float* sdb1 = (float*)carve((size_t)ND * 16 * 4);
    float* fw3 = (float*)carve((size_t)3 * 4 * 2048 * 4);
    int* degl = (int*)carve((size_t)(2 * (NL + ND)) * 4);
    int* degd = degl + NL;
    int* curl = degd + ND;
    int* curd = curl + NL;
    int* offl = (int*)carve((size_t)(NL + 1) * 4);
    int* offd = (int*)carve((size_t)(ND + 1) * 4);
    int* csrl = (int*)carve((size_t)NE * 4);
    int* csrd = (int*)carve((size_t)NE * 4);
    float* hdp = (float*)carve((size_t)ND * 32 * 4);
    float* hlp = (float*)carve((size_t)NL * 32 * 4);

    hipMemsetAsync(degl, 0, (size_t)2 * (NL + ND) * 4, stream);

    hist_kernel<<<(NE + 255) / 256, 256, 0, stream>>>(edge_src, edge_dst, degl, degd);
    scan2_kernel<<<2, 1024, 0, stream>>>(degl, offl, NL, degd, offd, ND);
    scatter_kernel<<<(NE + 255) / 256, 256, 0, stream>>>(edge_src, edge_dst, offl, offd, curl, curd, csrl, csrd);

    fold3_kernel<<<(3 * 8192 + 255) / 256, 256, 0, stream>>>(
        Ws[0], Wd[0], as_[0], ad_[0], Ws[1], Wd[1], as_[1], ad_[1],
        Ws[2], Wd[2], as_[2], ad_[2], fw3);
    wt2_kernel<<<(2 * 524288 + 255) / 256, 256, 0, stream>>>(Ws[0], Ws[1], WtH, WtL);

    // input linears + embedding add (both matrices, one dispatch, direct stores)
    inlin_kernel<<<dim3(2, 375), 256, 0, stream>>>(
        x_d, x_l, lin_dw, lin_lw, lin_db, lin_lb, emb_d, emb_l,
        node_id_d, node_id_l, hdA, hlA);

    float* hd_cur = hdA; float* hd_nxt = hdB;
    float* hl_cur = hlA; float* hl_nxt = hlB;

    // ---- layers 1-2: aggregate-then-project (split-bf16 MFMA, fused head-mean) ----
    for (int L = 0; L < 2; ++L) {
        const float* fw = fw3 + (size_t)L * 8192;
        const unsigned short* wtH = WtH + (size_t)L * 524288;
        const unsigned short* wtL = WtL + (size_t)L * 524288;

        score2both_kernel<<<ND / 16 + NL / 16, 256, 0, stream>>>(
            hd_cur, hl_cur, fw, ssb0, sdb1, sdb0, ssb1);

        // edge type 0: disease -> lncrna (dst = lncrna)
        hagg_kernel<<<NL / 2, 256, 0, stream>>>(hd_cur, ssb0, sdb0, offl, csrl, edge_src, haggP);
        gemm2r_kernel<<<dim3(NL / 64, 2), 256, 0, stream>>>(haggP, wtH, wtL, bb[L], hl_nxt, NL);

        // edge type 1: lncrna -> disease (dst = disease)
        hagg_kernel<<<ND / 2, 256, 0, stream>>>(hl_cur, ssb1, sdb1, offd, csrd, edge_dst, haggP);
        gemm2r_kernel<<<dim3(ND / 64, 2), 256, 0, stream>>>(haggP,
                                                            wtH + (size_t)2048 * 128, wtL + (size_t)2048 * 128,
                                                            bb[L] + 2048, hd_nxt, ND);

        float* t;
        t = hd_cur; hd_cur = hd_nxt; hd_nxt = t;
        t = hl_cur; hl_cur = hl_nxt; hl_nxt = t;
    }

    // ---- layer 3: project-then-aggregate (fp32), fused epilogue incl. penalty ----
    {
        const float* fw = fw3 + 2 * 8192;
        float* zs3 = (float*)haggP;  // 32.8 MB needed; hagg buffer free here
        score2both_kernel<<<ND / 16 + NL / 16, 256, 0, stream>>>(
            hd_cur, hl_cur, fw, ssb0, sdb1, sdb0, ssb1);

        // edge type 0: zs = hd @ Ws3[0] [ND,512]; dst = lncrna -> hlp (penalty pw[1],pb[1])
        gemm_kernel<<<dim3(512 / BN, ND / BM), 256, 0, stream>>>(hd_cur, Ws[2], zs3, ND, 512, 128);
        agg32_kernel<<<NL, 256, 0, stream>>>(zs3, ssb0, sdb0, offl, csrl, edge_src,
                                             bb[2], pw + 32, pb + 1, hlp);

        // edge type 1: zs = hl @ Ws3[1] [NL,512]; dst = disease -> hdp (penalty pw[0],pb[0])
        gemm_kernel<<<dim3(512 / BN, NL / BM), 256, 0, stream>>>(hl_cur, Ws[2] + 128 * 512, zs3, NL, 512, 128);
        agg32_kernel<<<ND, 256, 0, stream>>>(zs3, ssb1, sdb1, offd, csrd, edge_dst,
                                             bb[2] + 512, pw, pb, hdp);
    }

    mlp_kernel<<<(NM + 255) / 256, 256, 0, stream>>>(hdp, hlp, label_src, label_dst,
                                                     fc1w, fc1b, fc2w, fc2b, (float*)d_out, NM);
}

// Round 13
// 964.261 us; speedup vs baseline: 1.4908x; 1.0204x over previous
//
#include <hip/hip_runtime.h>
#include <cstdint>
#include <cstddef>

#define ND 8000
#define NL 16000
#define NE 60000
#define NM 50000

#define BM 64
#define BN 64
#define BK 16

typedef __attribute__((ext_vector_type(8))) short bf16x8;
typedef __attribute__((ext_vector_type(4))) float f32x4;
typedef __attribute__((ext_vector_type(8))) unsigned int u32x8;

__device__ __forceinline__ unsigned short f2bf(float x) {
    unsigned int u = __float_as_uint(x);
    unsigned int r = (u + 0x7FFFu + ((u >> 16) & 1u)) >> 16;
    return (unsigned short)r;
}
__device__ __forceinline__ float bf2f(unsigned short b) {
    return __uint_as_float(((unsigned int)b) << 16);
}

// ---------------- merged layer-3 GEMM: zs3d = hd @ W[0], zs3l = hl @ W[1], one dispatch
// grid (512/BN, 125 + 250)
__global__ __launch_bounds__(256) void gemm3_kernel(
    const float* __restrict__ hd, const float* __restrict__ hl,
    const float* __restrict__ W,   // [2,128,512]
    float* __restrict__ zs3d, float* __restrict__ zs3l)
{
    __shared__ float As[BK][BM + 4];
    __shared__ float Bs[BK][BN + 4];
    int mt = blockIdx.y;
    const float* A; const float* B; float* Cm; int M;
    if (mt < 125) { A = hd; B = W; Cm = zs3d; M = ND; }
    else { mt -= 125; A = hl; B = W + 128 * 512; Cm = zs3l; M = NL; }
    const int tid = threadIdx.x;
    const int tx = tid & 15, ty = tid >> 4;
    const int bm = mt * BM, bn = blockIdx.x * BN;
    float acc[4][4] = {};
    for (int k0 = 0; k0 < 128; k0 += BK) {
#pragma unroll
        for (int i = 0; i < 4; ++i) {
            int idx = tid + i * 256;
            int ml = idx >> 4, kl = idx & 15;
            As[kl][ml] = A[(size_t)(bm + ml) * 128 + k0 + kl];
        }
#pragma unroll
        for (int i = 0; i < 4; ++i) {
            int idx = tid + i * 256;
            int kl = idx >> 6, nl = idx & 63;
            Bs[kl][nl] = B[(size_t)(k0 + kl) * 512 + bn + nl];
        }
        __syncthreads();
#pragma unroll
        for (int k = 0; k < BK; ++k) {
            float4 av = *(const float4*)&As[k][ty * 4];
            float4 bv = *(const float4*)&Bs[k][tx * 4];
            float a4[4] = {av.x, av.y, av.z, av.w};
            float b4[4] = {bv.x, bv.y, bv.z, bv.w};
#pragma unroll
            for (int i = 0; i < 4; ++i)
#pragma unroll
                for (int j = 0; j < 4; ++j)
                    acc[i][j] += a4[i] * b4[j];
        }
        __syncthreads();
    }
#pragma unroll
    for (int i = 0; i < 4; ++i) {
        int gm = bm + ty * 4 + i;
        int gn0 = bn + tx * 4;
        float4 v;
        float* vp = &v.x;
#pragma unroll
        for (int j = 0; j < 4; ++j) vp[j] = acc[i][j];
        *(float4*)&Cm[(size_t)gm * 512 + gn0] = v;
    }
}

// ---------------- fused input linears, 32-row tiles for occupancy ----------------------
// grid (2, 250+500): blocks [0,250) -> x_d (K=412), [250,750) -> x_l (K=240).
__global__ __launch_bounds__(256) void inlin_kernel(
    const float* __restrict__ x_d, const float* __restrict__ x_l,
    const float* __restrict__ wd, const float* __restrict__ wl,
    const float* __restrict__ bd, const float* __restrict__ bl,
    const float* __restrict__ embd, const float* __restrict__ embl,
    const int* __restrict__ nidd, const int* __restrict__ nidl,
    float* __restrict__ hd, float* __restrict__ hl)
{
    __shared__ float As[BK][32 + 4];
    __shared__ float Bs[BK][BN + 4];
    int mt = blockIdx.y;
    const float* A; const float* B; const float* bias; const float* emb;
    const int* nid; float* out;
    int K;
    if (mt < 250) {
        A = x_d; B = wd; bias = bd; emb = embd; nid = nidd; out = hd; K = 412;
    } else {
        mt -= 250;
        A = x_l; B = wl; bias = bl; emb = embl; nid = nidl; out = hl; K = 240;
    }
    const int tid = threadIdx.x;
    const int tx = tid & 15, ty = tid >> 4;
    const int bm = mt * 32, bn = blockIdx.x * BN;
    float acc[2][4] = {};
    for (int k0 = 0; k0 < K; k0 += BK) {
#pragma unroll
        for (int i = 0; i < 2; ++i) {
            int idx = tid + i * 256;
            int ml = idx >> 4, kl = idx & 15;
            int gk = k0 + kl;
            As[kl][ml] = (gk < K) ? A[(size_t)(bm + ml) * K + gk] : 0.f;
        }
#pragma unroll
        for (int i = 0; i < 4; ++i) {
            int idx = tid + i * 256;
            int kl = idx >> 6, nl = idx & 63;
            int gk = k0 + kl;
            Bs[kl][nl] = (gk < K) ? B[(size_t)gk * 128 + bn + nl] : 0.f;
        }
        __syncthreads();
#pragma unroll
        for (int k = 0; k < BK; ++k) {
            float a0 = As[k][ty * 2];
            float a1 = As[k][ty * 2 + 1];
            float4 bv = *(const float4*)&Bs[k][tx * 4];
            float b4[4] = {bv.x, bv.y, bv.z, bv.w};
#pragma unroll
            for (int j = 0; j < 4; ++j) {
                acc[0][j] += a0 * b4[j];
                acc[1][j] += a1 * b4[j];
            }
        }
        __syncthreads();
    }
#pragma unroll
    for (int i = 0; i < 2; ++i) {
        int gm = bm + ty * 2 + i;
        int gn0 = bn + tx * 4;
        const float* ep = emb + (size_t)nid[gm] * 128 + gn0;
        float4 v;
        float* vp = &v.x;
#pragma unroll
        for (int j = 0; j < 4; ++j)
            vp[j] = acc[i][j] + bias[gn0 + j] + ep[j];
        *(float4*)&out[(size_t)gm * 128 + gn0] = v;
    }
}

// ---------------- W transpose + split-bf16 into MFMA-fragment tiling, BOTH layers ------
__global__ void wt2_kernel(const float* __restrict__ W0, const float* __restrict__ W1,
                           unsigned short* __restrict__ WtH, unsigned short* __restrict__ WtL)
{
    int gid = blockIdx.x * 256 + threadIdx.x;
    if (gid >= 2 * 2 * 128 * 2048) return;
    int l = gid >> 19;
    int rem0 = gid & 524287;
    int dir = rem0 >> 18;
    int rem = rem0 & 262143;
    int k = rem >> 11, n = rem & 2047;   // n fast -> coalesced read
    const float* W = l ? W1 : W0;
    float v = W[(size_t)dir * 262144 + (size_t)k * 2048 + n];
    unsigned short hb = f2bf(v);
    unsigned short lb = f2bf(v - bf2f(hb));
    int u = n >> 4;
    int lane = (n & 15) + 16 * ((k >> 3) & 3);
    size_t o = (size_t)l * 524288 + (size_t)dir * 262144 +
               ((size_t)u * 4 + (k >> 5)) * 512 + lane * 8 + (k & 7);
    WtH[o] = hb;
    WtL[o] = lb;
}

// ---------------- fused per-head projection + bias + relu + HEAD-MEAN (layers 1-2) ----
// grid (M/64, 4): 4 waves x 16 rows; each wave covers a 32-col quarter (2 ctl tiles).
__global__ __launch_bounds__(256) void gemm2r_kernel(
    const unsigned int* __restrict__ haggP,
    const unsigned short* __restrict__ WtH, const unsigned short* __restrict__ WtL,
    const float* __restrict__ bias, float* __restrict__ out, int M)
{
    const int wave = threadIdx.x >> 6;
    const int lane = threadIdx.x & 63;
    const int cb = blockIdx.y;               // column quarter (0..3)
    const int m0 = blockIdx.x * 64 + wave * 16;
    const int t = m0 >> 4;                   // m-tile index
    const int row = lane & 15;               // D col within 16-col tile
    const int quad = lane >> 4;              // D row = quad*4 + r

    f32x4 mean[2] = {};

    for (int h = 0; h < 16; ++h) {
        f32x4 accH[2], accL[2];
#pragma unroll
        for (int ctl = 0; ctl < 2; ++ctl) {
            float bv = bias[h * 128 + cb * 32 + ctl * 16 + row];
            accH[ctl] = (f32x4){bv, bv, bv, bv};
            accL[ctl] = (f32x4){0.f, 0.f, 0.f, 0.f};
        }
#pragma unroll
        for (int kc = 0; kc < 4; ++kc) {
            const size_t aoff = (((size_t)t * 16 + h) * 4 + kc) * 512 + lane * 8;
            u32x8 p = *(const u32x8*)(haggP + aoff);
            bf16x8 aH, aL;
#pragma unroll
            for (int i = 0; i < 8; ++i) {
                aH[i] = (short)(p[i] & 0xffffu);
                aL[i] = (short)(p[i] >> 16);
            }
#pragma unroll
            for (int ctl = 0; ctl < 2; ++ctl) {
                const int u = h * 8 + cb * 2 + ctl;
                const size_t boff = ((size_t)u * 4 + kc) * 512 + lane * 8;
                bf16x8 bH = *(const bf16x8*)(WtH + boff);
                bf16x8 bL = *(const bf16x8*)(WtL + boff);
                accH[ctl] = __builtin_amdgcn_mfma_f32_16x16x32_bf16(aH, bH, accH[ctl], 0, 0, 0);
                accL[ctl] = __builtin_amdgcn_mfma_f32_16x16x32_bf16(aH, bL, accL[ctl], 0, 0, 0);
                accL[ctl] = __builtin_amdgcn_mfma_f32_16x16x32_bf16(aL, bH, accL[ctl], 0, 0, 0);
            }
        }
#pragma unroll
        for (int ctl = 0; ctl < 2; ++ctl)
#pragma unroll
            for (int r = 0; r < 4; ++r)
                mean[ctl][r] += fmaxf(accH[ctl][r] + accL[ctl][r], 0.f);
    }

#pragma unroll
    for (int ctl = 0; ctl < 2; ++ctl) {
        int c = cb * 32 + ctl * 16 + row;
#pragma unroll
        for (int r = 0; r < 4; ++r) {
            int gm = m0 + quad * 4 + r;
            out[(size_t)gm * 128 + c] = mean[ctl][r] * (1.f / 16.f);
        }
    }
}

// ---------------- fold for ALL 3 layers: fw3[l][f][k][h] = sum_c W[k,h*C+c]*a[h,c] ----
__global__ void fold3_kernel(
    const float* __restrict__ Ws1, const float* __restrict__ Wd1,
    const float* __restrict__ as1, const float* __restrict__ ad1,
    const float* __restrict__ Ws2, const float* __restrict__ Wd2,
    const float* __restrict__ as2, const float* __restrict__ ad2,
    const float* __restrict__ Ws3, const float* __restrict__ Wd3,
    const float* __restrict__ as3, const float* __restrict__ ad3,
    float* __restrict__ fw3)
{
    int gid = blockIdx.x * blockDim.x + threadIdx.x;
    if (gid >= 3 * 4 * 128 * 16) return;
    int l = gid / 8192, rem1 = gid % 8192;
    int f = rem1 / 2048, rem = rem1 % 2048;
    int k = rem >> 4, h = rem & 15;
    int Ntot = (l == 2) ? 512 : 2048;
    int C = Ntot >> 4;
    const float* W;
    const float* a;
    if (l == 0) { W = (f & 1) ? Wd1 : Ws1; a = (f & 1) ? ad1 : as1; }
    else if (l == 1) { W = (f & 1) ? Wd2 : Ws2; a = (f & 1) ? ad2 : as2; }
    else { W = (f & 1) ? Wd3 : Ws3; a = (f & 1) ? ad3 : as3; }
    if (f >= 2) { W += 128 * Ntot; a += 16 * C; }
    float s = 0.f;
    for (int c = 0; c < C; ++c) s += W[(size_t)k * Ntot + h * C + c] * a[h * C + c];
    fw3[gid] = s;
}

// ---------------- score2both: all four folded scores of a layer in one dispatch --------
__global__ __launch_bounds__(256) void score2both_kernel(
    const float* __restrict__ Hd, const float* __restrict__ Hl,
    const float* __restrict__ fw,   // layer base [4][128][16]
    float* __restrict__ ssb0, float* __restrict__ sdb1,
    float* __restrict__ sdb0, float* __restrict__ ssb1)
{
    __shared__ float hs[16 * 128];
    __shared__ float wa[128 * 16];
    __shared__ float wb[128 * 16];
    int b = blockIdx.x;
    const float* Hf; const float* WfA; const float* WfB;
    float* outA; float* outB; int n0;
    if (b < ND / 16) {
        Hf = Hd; WfA = fw; WfB = fw + 3 * 2048; outA = ssb0; outB = sdb1; n0 = b * 16;
    } else {
        Hf = Hl; WfA = fw + 1 * 2048; WfB = fw + 2 * 2048; outA = sdb0; outB = ssb1;
        n0 = (b - ND / 16) * 16;
    }
    int tid = threadIdx.x;
#pragma unroll
    for (int i = 0; i < 8; ++i) {
        int idx = tid + i * 256;
        int nl = idx >> 7, k = idx & 127;
        hs[idx] = Hf[(size_t)(n0 + nl) * 128 + k];
        wa[idx] = WfA[idx];
        wb[idx] = WfB[idx];
    }
    __syncthreads();
    int nl = tid >> 4, h = tid & 15;
    float sa = 0.f, sb = 0.f;
    for (int k = 0; k < 128; ++k) {
        float hv = hs[nl * 128 + k];
        sa += hv * wa[k * 16 + h];
        sb += hv * wb[k * 16 + h];
    }
    int gn = n0 + nl;
    outA[gn * 16 + h] = sa;
    outB[gn * 16 + h] = sb;
}

// ---------------- CSR build ----------------
__global__ void hist_kernel(const int* __restrict__ esrc, const int* __restrict__ edst,
                            int* __restrict__ degl, int* __restrict__ degd)
{
    int e = blockIdx.x * blockDim.x + threadIdx.x;
    if (e >= NE) return;
    atomicAdd(&degl[edst[e]], 1);
    atomicAdd(&degd[esrc[e]], 1);
}

__global__ __launch_bounds__(1024) void scan2_kernel(
    const int* __restrict__ degA, int* __restrict__ offA, int nA,
    const int* __restrict__ degB, int* __restrict__ offB, int nB)
{
    __shared__ int ps[1024];
    const int* deg = blockIdx.x ? degB : degA;
    int* off = blockIdx.x ? offB : offA;
    int n = blockIdx.x ? nB : nA;
    int tid = threadIdx.x;
    int chunk = (n + 1023) >> 10;
    int start = tid * chunk, end = min(start + chunk, n);
    int p = 0;
    for (int i = start; i < end; ++i) p += deg[i];
    ps[tid] = p;
    __syncthreads();
    for (int o = 1; o < 1024; o <<= 1) {
        int v = (tid >= o) ? ps[tid - o] : 0;
        __syncthreads();
        ps[tid] += v;
        __syncthreads();
    }
    int run = ps[tid] - p;
    for (int i = start; i < end; ++i) { off[i] = run; run += deg[i]; }
    if (tid == 1023) off[n] = ps[1023];
}

__global__ void scatter_kernel(const int* __restrict__ esrc, const int* __restrict__ edst,
                               const int* __restrict__ offl, const int* __restrict__ offd,
                               int* __restrict__ curl, int* __restrict__ curd,
                               int* __restrict__ csrl, int* __restrict__ csrd)
{
    int e = blockIdx.x * blockDim.x + threadIdx.x;
    if (e >= NE) return;
    int dl = edst[e]; int p = atomicAdd(&curl[dl], 1); csrl[offl[dl] + p] = e;
    int dd = esrc[e]; int q = atomicAdd(&curd[dd], 1); csrd[offd[dd] + q] = e;
}

// ---------------- fused softmax + per-head aggregation -> packed fragment-tiled hagg ---
__global__ __launch_bounds__(256) void hagg_kernel(
    const float* __restrict__ hsrc,  // [n_src, 128]
    const float* __restrict__ ss,    // [n_src, 16]
    const float* __restrict__ sd,    // [n_dst, 16]
    const int* __restrict__ off, const int* __restrict__ csr, const int* __restrict__ srcidx,
    unsigned int* __restrict__ haggP)
{
    __shared__ float m_s[2][16], s_s[2][16];
    __shared__ float alpha_s[2][8][17];
    __shared__ int src_s[2][8];
    const int d0 = blockIdx.x * 2;
    const int tid = threadIdx.x;

    if (tid < 32) {
        int nd = tid >> 4, h = tid & 15;
        int dd = d0 + nd;
        int e0 = off[dd], e1 = off[dd + 1];
        float sdv = sd[dd * 16 + h];
        float m = -1e30f;
        for (int e = e0; e < e1; ++e) {
            int sn = srcidx[csr[e]];
            float al = ss[sn * 16 + h] + sdv;
            al = al >= 0.f ? al : 0.2f * al;
            m = fmaxf(m, al);
        }
        float s = 0.f;
        for (int e = e0; e < e1; ++e) {
            int sn = srcidx[csr[e]];
            float al = ss[sn * 16 + h] + sdv;
            al = al >= 0.f ? al : 0.2f * al;
            s += expf(al - m);
        }
        m_s[nd][h] = m;
        s_s[nd][h] = s + 1e-16f;
    }
    __syncthreads();

    const int half = tid >> 7;       // node within block (wave-uniform)
    const int c = tid & 127;         // channel
    const int d = d0 + half;
    const int my_e0 = off[d];
    const int my_deg = off[d + 1] - my_e0;
    const int deg0 = off[d0 + 1] - off[d0];
    const int deg1 = off[d0 + 2] - off[d0 + 1];
    const int degmax = deg0 > deg1 ? deg0 : deg1;
    const int ntrip = (degmax + 7) >> 3;

    float acc[16];
#pragma unroll
    for (int h = 0; h < 16; ++h) acc[h] = 0.f;

    for (int trip = 0; trip < ntrip; ++trip) {
        int ce = trip * 8;
        {
            int ei = c >> 4, h = c & 15;
            if (ce + ei < my_deg) {
                int sn = srcidx[csr[my_e0 + ce + ei]];
                float al = ss[sn * 16 + h] + sd[d * 16 + h];
                al = al >= 0.f ? al : 0.2f * al;
                alpha_s[half][ei][h] = expf(al - m_s[half][h]) / s_s[half][h];
                if (h == 0) src_s[half][ei] = sn;
            }
        }
        __syncthreads();
        int nc = min(8, my_deg - ce);
        for (int ei = 0; ei < nc; ++ei) {
            float v = hsrc[(size_t)src_s[half][ei] * 128 + c];
#pragma unroll
            for (int h = 0; h < 16; ++h)
                acc[h] += alpha_s[half][ei][h] * v;
        }
        __syncthreads();
    }

    const int t = d >> 4;
    const int lane8 = ((d & 15) + 16 * ((c >> 3) & 3)) * 8 + (c & 7);
    const int kc = c >> 5;
#pragma unroll
    for (int h = 0; h < 16; ++h) {
        float v = acc[h];
        unsigned short hb = f2bf(v);
        unsigned short lb = f2bf(v - bf2f(hb));
        size_t idx = (((size_t)t * 16 + h) * 4 + kc) * 512 + lane8;
        haggP[idx] = (unsigned int)hb | ((unsigned int)lb << 16);
    }
}

// ---------------- layer 3 merged: softmax + gather + bias + relu + mean + penalty ------
// blocks [0, NL): dst lncrna from zs3d; blocks [NL, NL+ND): dst disease from zs3l.
__global__ __launch_bounds__(256) void agg32both_kernel(
    const float* __restrict__ zs3d, const float* __restrict__ zs3l,
    const float* __restrict__ ssb0, const float* __restrict__ sdb0,
    const float* __restrict__ ssb1, const float* __restrict__ sdb1,
    const int* __restrict__ offl, const int* __restrict__ csrl,
    const int* __restrict__ offd, const int* __restrict__ csrd,
    const int* __restrict__ esrc, const int* __restrict__ edst,
    const float* __restrict__ bias512,  // [2][512]
    const float* __restrict__ pw, const float* __restrict__ pb,  // [2,32],[2]
    float* __restrict__ hlp, float* __restrict__ hdp)
{
    __shared__ float m_s[16], s_s[16];
    __shared__ float alpha_s[16][17];
    __shared__ int src_s[16];
    __shared__ float lds_out[512];
    __shared__ float hrow[32];
    int d = blockIdx.x;
    const float* zs; const float* ss; const float* sd;
    const int* off; const int* csr; const int* srcidx;
    const float* bias; const float* pwt; const float* pbt; float* out;
    if (d < NL) {
        zs = zs3d; ss = ssb0; sd = sdb0; off = offl; csr = csrl; srcidx = esrc;
        bias = bias512; pwt = pw + 32; pbt = pb + 1; out = hlp;
    } else {
        d -= NL;
        zs = zs3l; ss = ssb1; sd = sdb1; off = offd; csr = csrd; srcidx = edst;
        bias = bias512 + 512; pwt = pw; pbt = pb; out = hdp;
    }
    const int tid = threadIdx.x;
    const int e0 = off[d], e1 = off[d + 1];

    if (tid < 16) {
        int h = tid;
        float sdv = sd[d * 16 + h];
        float m = -1e30f;
        for (int e = e0; e < e1; ++e) {
            int sn = srcidx[csr[e]];
            float al = ss[sn * 16 + h] + sdv;
            al = al >= 0.f ? al : 0.2f * al;
            m = fmaxf(m, al);
        }
        float s = 0.f;
        for (int e = e0; e < e1; ++e) {
            int sn = srcidx[csr[e]];
            float al = ss[sn * 16 + h] + sdv;
            al = al >= 0.f ? al : 0.2f * al;
            s += expf(al - m);
        }
        m_s[h] = m;
        s_s[h] = s + 1e-16f;
    }
    __syncthreads();

    float acc0 = 0.f, acc1 = 0.f;
    const int hsel = tid >> 4;

    for (int ce = e0; ce < e1; ce += 16) {
        int nc = min(16, e1 - ce);
        if (tid < nc * 16) {
            int ei = tid >> 4, h = tid & 15;
            int sn = srcidx[csr[ce + ei]];
            float al = ss[sn * 16 + h] + sd[d * 16 + h];
            al = al >= 0.f ? al : 0.2f * al;
            alpha_s[ei][h] = expf(al - m_s[h]) / s_s[h];
            if (h == 0) src_s[ei] = sn;
        }
        __syncthreads();
        for (int ei = 0; ei < nc; ++ei) {
            float a = alpha_s[ei][hsel];
            float2 v = *(const float2*)(zs + (size_t)src_s[ei] * 512 + tid * 2);
            acc0 += a * v.x;
            acc1 += a * v.y;
        }
        __syncthreads();
    }

    lds_out[tid * 2] = fmaxf(acc0 + bias[tid * 2], 0.f);
    lds_out[tid * 2 + 1] = fmaxf(acc1 + bias[tid * 2 + 1], 0.f);
    __syncthreads();
    if (tid < 32) {
        float s = 0.f;
#pragma unroll
        for (int hh = 0; hh < 16; ++hh) s += lds_out[hh * 32 + tid];
        hrow[tid] = s * (1.f / 16.f);
    }
    __syncthreads();
    if (tid < 32) {
        float t = pbt[0];
#pragma unroll
        for (int c = 0; c < 32; ++c) t += hrow[c] * pwt[c];
        out[(size_t)d * 32 + tid] = hrow[tid] * expf(t);
    }
}

// ---------------- final MLP on label edges ----------------
__global__ __launch_bounds__(256) void mlp_kernel(
    const float* __restrict__ hd, const float* __restrict__ hl,
    const int* __restrict__ ls, const int* __restrict__ ld,
    const float* __restrict__ w1, const float* __restrict__ b1,
    const float* __restrict__ w2, const float* __restrict__ b2,
    float* __restrict__ out, int M)
{
    __shared__ float w1s[64 * 64];
    __shared__ float b1s[64];
    __shared__ float w2s[64];
    int tid = threadIdx.x;
#pragma unroll
    for (int i = 0; i < 16; ++i) w1s[tid + i * 256] = w1[tid + i * 256];
    if (tid < 64) { b1s[tid] = b1[tid]; w2s[tid] = w2[tid]; }
    __syncthreads();
    int m = blockIdx.x * 256 + tid;
    if (m >= M) return;
    float f[64];
    const float* hp = hd + (size_t)ls[m] * 32;
    const float* lp = hl + (size_t)ld[m] * 32;
#pragma unroll
    for (int c = 0; c < 32; ++c) { f[c] = hp[c]; f[32 + c] = lp[c]; }
    float o = b2[0];
    for (int j = 0; j < 64; ++j) {
        float hj = b1s[j];
#pragma unroll
        for (int k = 0; k < 64; ++k) hj += f[k] * w1s[k * 64 + j];
        hj = fmaxf(hj, 0.f);
        o += hj * w2s[j];
    }
    out[m] = o;
}

extern "C" void kernel_launch(void* const* d_in, const int* in_sizes, int n_in,
                              void* d_out, int out_size, void* d_ws, size_t ws_size,
                              hipStream_t stream)
{
    const float* x_d = (const float*)d_in[0];
    const float* x_l = (const float*)d_in[1];
    const int* node_id_d = (const int*)d_in[2];
    const int* node_id_l = (const int*)d_in[3];
    const int* edge_src = (const int*)d_in[4];
    const int* edge_dst = (const int*)d_in[5];
    const int* label_src = (const int*)d_in[6];
    const int* label_dst = (const int*)d_in[7];
    const float* emb_d = (const float*)d_in[8];
    const float* emb_l = (const float*)d_in[9];
    const float* lin_dw = (const float*)d_in[10];
    const float* lin_db = (const float*)d_in[11];
    const float* lin_lw = (const float*)d_in[12];
    const float* lin_lb = (const float*)d_in[13];
    const float* Ws[3] = {(const float*)d_in[14], (const float*)d_in[19], (const float*)d_in[24]};
    const float* Wd[3] = {(const float*)d_in[15], (const float*)d_in[20], (const float*)d_in[25]};
    const float* as_[3] = {(const float*)d_in[16], (const float*)d_in[21], (const float*)d_in[26]};
    const float* ad_[3] = {(const float*)d_in[17], (const float*)d_in[22], (const float*)d_in[27]};
    const float* bb[3] = {(const float*)d_in[18], (const float*)d_in[23], (const float*)d_in[28]};
    const float* pw = (const float*)d_in[29];
    const float* pb = (const float*)d_in[30];
    const float* fc1w = (const float*)d_in[31];
    const float* fc1b = (const float*)d_in[32];
    const float* fc2w = (const float*)d_in[33];
    const float* fc2b = (const float*)d_in[34];

    char* wsb = (char*)d_ws;
    size_t woff = 0;
    auto carve = [&](size_t bytes) -> void* {
        woff = (woff + 255) & ~(size_t)255;
        void* p = wsb + woff;
        woff += bytes;
        return p;
    };
    float* hdA = (float*)carve((size_t)ND * 128 * 4);
    float* hlA = (float*)carve((size_t)NL * 128 * 4);
    float* hdB = (float*)carve((size_t)ND * 128 * 4);
    float* hlB = (float*)carve((size_t)NL * 128 * 4);
    unsigned int* haggP = (unsigned int*)carve((size_t)NL * 2048 * 4);  // L3 reuses as zs3d/zs3l
    unsigned short* WtH = (unsigned short*)carve((size_t)2 * 2 * 2048 * 128 * 2);  // [layer][dir]
    unsigned short* WtL = (unsigned short*)carve((size_t)2 * 2 * 2048 * 128 * 2);
    float* ssb0 = (float*)carve((size_t)ND * 16 * 4);
    float* sdb0 = (float*)carve((size_t)NL * 16 * 4);
    float* ssb1 = (float*)carve((size_t)NL * 16 * 4);
    float* sdb1 = (float*)carve((size_t)ND * 16 * 4);
    float* fw3 = (float*)carve((size_t)3 * 4 * 2048 * 4);
    int* degl = (int*)carve((size_t)(2 * (NL + ND)) * 4);
    int* degd = degl + NL;
    int* curl = degd + ND;
    int* curd = curl + NL;
    int* offl = (int*)carve((size_t)(NL + 1) * 4);
    int* offd = (int*)carve((size_t)(ND + 1) * 4);
    int* csrl = (int*)carve((size_t)NE * 4);
    int* csrd = (int*)carve((size_t)NE * 4);
    float* hdp = (float*)carve((size_t)ND * 32 * 4);
    float* hlp = (float*)carve((size_t)NL * 32 * 4);

    hipMemsetAsync(degl, 0, (size_t)2 * (NL + ND) * 4, stream);

    hist_kernel<<<(NE + 255) / 256, 256, 0, stream>>>(edge_src, edge_dst, degl, degd);
    scan2_kernel<<<2, 1024, 0, stream>>>(degl, offl, NL, degd, offd, ND);
    scatter_kernel<<<(NE + 255) / 256, 256, 0, stream>>>(edge_src, edge_dst, offl, offd, curl, curd, csrl, csrd);

    fold3_kernel<<<(3 * 8192 + 255) / 256, 256, 0, stream>>>(
        Ws[0], Wd[0], as_[0], ad_[0], Ws[1], Wd[1], as_[1], ad_[1],
        Ws[2], Wd[2], as_[2], ad_[2], fw3);
    wt2_kernel<<<(2 * 524288 + 255) / 256, 256, 0, stream>>>(Ws[0], Ws[1], WtH, WtL);

    // input linears + embedding add (both matrices, one dispatch, 32-row tiles)
    inlin_kernel<<<dim3(2, 750), 256, 0, stream>>>(
        x_d, x_l, lin_dw, lin_lw, lin_db, lin_lb, emb_d, emb_l,
        node_id_d, node_id_l, hdA, hlA);

    float* hd_cur = hdA; float* hd_nxt = hdB;
    float* hl_cur = hlA; float* hl_nxt = hlB;

    // ---- layers 1-2: aggregate-then-project (split-bf16 MFMA, fused head-mean) ----
    for (int L = 0; L < 2; ++L) {
        const float* fw = fw3 + (size_t)L * 8192;
        const unsigned short* wtH = WtH + (size_t)L * 524288;
        const unsigned short* wtL = WtL + (size_t)L * 524288;

        score2both_kernel<<<ND / 16 + NL / 16, 256, 0, stream>>>(
            hd_cur, hl_cur, fw, ssb0, sdb1, sdb0, ssb1);

        // edge type 0: disease -> lncrna (dst = lncrna)
        hagg_kernel<<<NL / 2, 256, 0, stream>>>(hd_cur, ssb0, sdb0, offl, csrl, edge_src, haggP);
        gemm2r_kernel<<<dim3(NL / 64, 4), 256, 0, stream>>>(haggP, wtH, wtL, bb[L], hl_nxt, NL);

        // edge type 1: lncrna -> disease (dst = disease)
        hagg_kernel<<<ND / 2, 256, 0, stream>>>(hl_cur, ssb1, sdb1, offd, csrd, edge_dst, haggP);
        gemm2r_kernel<<<dim3(ND / 64, 4), 256, 0, stream>>>(haggP,
                                                            wtH + (size_t)2048 * 128, wtL + (size_t)2048 * 128,
                                                            bb[L] + 2048, hd_nxt, ND);

        float* t;
        t = hd_cur; hd_cur = hd_nxt; hd_nxt = t;
        t = hl_cur; hl_cur = hl_nxt; hl_nxt = t;
    }

    // ---- layer 3: project-then-aggregate (fp32), merged dispatches ----
    {
        const float* fw = fw3 + 2 * 8192;
        float* zs3d = (float*)haggP;                       // [ND, 512] 16.4 MB
        float* zs3l = (float*)haggP + (size_t)ND * 512;    // [NL, 512] 32.8 MB (fits in 131 MB)
        score2both_kernel<<<ND / 16 + NL / 16, 256, 0, stream>>>(
            hd_cur, hl_cur, fw, ssb0, sdb1, sdb0, ssb1);

        gemm3_kernel<<<dim3(512 / BN, 125 + 250), 256, 0, stream>>>(
            hd_cur, hl_cur, Ws[2], zs3d, zs3l);

        agg32both_kernel<<<NL + ND, 256, 0, stream>>>(
            zs3d, zs3l, ssb0, sdb0, ssb1, sdb1,
            offl, csrl, offd, csrd, edge_src, edge_dst,
            bb[2], pw, pb, hlp, hdp);
    }

    mlp_kernel<<<(NM + 255) / 256, 256, 0, stream>>>(hdp, hlp, label_src, label_dst,
                                                     fc1w, fc1b, fc2w, fc2b, (float*)d_out, NM);
}

// Round 14
// 902.504 us; speedup vs baseline: 1.5928x; 1.0684x over previous
//
#include <hip/hip_runtime.h>
#include <cstdint>
#include <cstddef>

#define ND 8000
#define NL 16000
#define NE 60000
#define NM 50000

#define BM 64
#define BN 64
#define BK 16

typedef __attribute__((ext_vector_type(8))) short bf16x8;
typedef __attribute__((ext_vector_type(4))) float f32x4;
typedef __attribute__((ext_vector_type(8))) unsigned int u32x8;

__device__ __forceinline__ unsigned short f2bf(float x) {
    unsigned int u = __float_as_uint(x);
    unsigned int r = (u + 0x7FFFu + ((u >> 16) & 1u)) >> 16;
    return (unsigned short)r;
}
__device__ __forceinline__ float bf2f(unsigned short b) {
    return __uint_as_float(((unsigned int)b) << 16);
}

// ---------------- merged layer-3 GEMM: zs3d = hd @ W[0], zs3l = hl @ W[1] --------------
__global__ __launch_bounds__(256) void gemm3_kernel(
    const float* __restrict__ hd, const float* __restrict__ hl,
    const float* __restrict__ W,   // [2,128,512]
    float* __restrict__ zs3d, float* __restrict__ zs3l)
{
    __shared__ float As[BK][BM + 4];
    __shared__ float Bs[BK][BN + 4];
    int mt = blockIdx.y;
    const float* A; const float* B; float* Cm;
    if (mt < 125) { A = hd; B = W; Cm = zs3d; }
    else { mt -= 125; A = hl; B = W + 128 * 512; Cm = zs3l; }
    const int tid = threadIdx.x;
    const int tx = tid & 15, ty = tid >> 4;
    const int bm = mt * BM, bn = blockIdx.x * BN;
    float acc[4][4] = {};
    for (int k0 = 0; k0 < 128; k0 += BK) {
#pragma unroll
        for (int i = 0; i < 4; ++i) {
            int idx = tid + i * 256;
            int ml = idx >> 4, kl = idx & 15;
            As[kl][ml] = A[(size_t)(bm + ml) * 128 + k0 + kl];
        }
#pragma unroll
        for (int i = 0; i < 4; ++i) {
            int idx = tid + i * 256;
            int kl = idx >> 6, nl = idx & 63;
            Bs[kl][nl] = B[(size_t)(k0 + kl) * 512 + bn + nl];
        }
        __syncthreads();
#pragma unroll
        for (int k = 0; k < BK; ++k) {
            float4 av = *(const float4*)&As[k][ty * 4];
            float4 bv = *(const float4*)&Bs[k][tx * 4];
            float a4[4] = {av.x, av.y, av.z, av.w};
            float b4[4] = {bv.x, bv.y, bv.z, bv.w};
#pragma unroll
            for (int i = 0; i < 4; ++i)
#pragma unroll
                for (int j = 0; j < 4; ++j)
                    acc[i][j] += a4[i] * b4[j];
        }
        __syncthreads();
    }
#pragma unroll
    for (int i = 0; i < 4; ++i) {
        int gm = bm + ty * 4 + i;
        int gn0 = bn + tx * 4;
        float4 v;
        float* vp = &v.x;
#pragma unroll
        for (int j = 0; j < 4; ++j) vp[j] = acc[i][j];
        *(float4*)&Cm[(size_t)gm * 512 + gn0] = v;
    }
}

// ---------------- fused input linears, 32-row tiles ------------------------------------
__global__ __launch_bounds__(256) void inlin_kernel(
    const float* __restrict__ x_d, const float* __restrict__ x_l,
    const float* __restrict__ wd, const float* __restrict__ wl,
    const float* __restrict__ bd, const float* __restrict__ bl,
    const float* __restrict__ embd, const float* __restrict__ embl,
    const int* __restrict__ nidd, const int* __restrict__ nidl,
    float* __restrict__ hd, float* __restrict__ hl)
{
    __shared__ float As[BK][32 + 4];
    __shared__ float Bs[BK][BN + 4];
    int mt = blockIdx.y;
    const float* A; const float* B; const float* bias; const float* emb;
    const int* nid; float* out;
    int K;
    if (mt < 250) {
        A = x_d; B = wd; bias = bd; emb = embd; nid = nidd; out = hd; K = 412;
    } else {
        mt -= 250;
        A = x_l; B = wl; bias = bl; emb = embl; nid = nidl; out = hl; K = 240;
    }
    const int tid = threadIdx.x;
    const int tx = tid & 15, ty = tid >> 4;
    const int bm = mt * 32, bn = blockIdx.x * BN;
    float acc[2][4] = {};
    for (int k0 = 0; k0 < K; k0 += BK) {
#pragma unroll
        for (int i = 0; i < 2; ++i) {
            int idx = tid + i * 256;
            int ml = idx >> 4, kl = idx & 15;
            int gk = k0 + kl;
            As[kl][ml] = (gk < K) ? A[(size_t)(bm + ml) * K + gk] : 0.f;
        }
#pragma unroll
        for (int i = 0; i < 4; ++i) {
            int idx = tid + i * 256;
            int kl = idx >> 6, nl = idx & 63;
            int gk = k0 + kl;
            Bs[kl][nl] = (gk < K) ? B[(size_t)gk * 128 + bn + nl] : 0.f;
        }
        __syncthreads();
#pragma unroll
        for (int k = 0; k < BK; ++k) {
            float a0 = As[k][ty * 2];
            float a1 = As[k][ty * 2 + 1];
            float4 bv = *(const float4*)&Bs[k][tx * 4];
            float b4[4] = {bv.x, bv.y, bv.z, bv.w};
#pragma unroll
            for (int j = 0; j < 4; ++j) {
                acc[0][j] += a0 * b4[j];
                acc[1][j] += a1 * b4[j];
            }
        }
        __syncthreads();
    }
#pragma unroll
    for (int i = 0; i < 2; ++i) {
        int gm = bm + ty * 2 + i;
        int gn0 = bn + tx * 4;
        const float* ep = emb + (size_t)nid[gm] * 128 + gn0;
        float4 v;
        float* vp = &v.x;
#pragma unroll
        for (int j = 0; j < 4; ++j)
            vp[j] = acc[i][j] + bias[gn0 + j] + ep[j];
        *(float4*)&out[(size_t)gm * 128 + gn0] = v;
    }
}

// ---------------- W transpose + split-bf16 into MFMA-fragment tiling, BOTH layers ------
__global__ void wt2_kernel(const float* __restrict__ W0, const float* __restrict__ W1,
                           unsigned short* __restrict__ WtH, unsigned short* __restrict__ WtL)
{
    int gid = blockIdx.x * 256 + threadIdx.x;
    if (gid >= 2 * 2 * 128 * 2048) return;
    int l = gid >> 19;
    int rem0 = gid & 524287;
    int dir = rem0 >> 18;
    int rem = rem0 & 262143;
    int k = rem >> 11, n = rem & 2047;
    const float* W = l ? W1 : W0;
    float v = W[(size_t)dir * 262144 + (size_t)k * 2048 + n];
    unsigned short hb = f2bf(v);
    unsigned short lb = f2bf(v - bf2f(hb));
    int u = n >> 4;
    int lane = (n & 15) + 16 * ((k >> 3) & 3);
    size_t o = (size_t)l * 524288 + (size_t)dir * 262144 +
               ((size_t)u * 4 + (k >> 5)) * 512 + lane * 8 + (k & 7);
    WtH[o] = hb;
    WtL[o] = lb;
}

// ---------------- fused per-head projection + bias + relu + HEAD-MEAN (layers 1-2) ----
__global__ __launch_bounds__(256) void gemm2r_kernel(
    const unsigned int* __restrict__ haggP,
    const unsigned short* __restrict__ WtH, const unsigned short* __restrict__ WtL,
    const float* __restrict__ bias, float* __restrict__ out, int M)
{
    const int wave = threadIdx.x >> 6;
    const int lane = threadIdx.x & 63;
    const int cb = blockIdx.y;               // column quarter (0..3)
    const int m0 = blockIdx.x * 64 + wave * 16;
    const int t = m0 >> 4;
    const int row = lane & 15;
    const int quad = lane >> 4;

    f32x4 mean[2] = {};

    for (int h = 0; h < 16; ++h) {
        f32x4 accH[2], accL[2];
#pragma unroll
        for (int ctl = 0; ctl < 2; ++ctl) {
            float bv = bias[h * 128 + cb * 32 + ctl * 16 + row];
            accH[ctl] = (f32x4){bv, bv, bv, bv};
            accL[ctl] = (f32x4){0.f, 0.f, 0.f, 0.f};
        }
#pragma unroll
        for (int kc = 0; kc < 4; ++kc) {
            const size_t aoff = (((size_t)t * 16 + h) * 4 + kc) * 512 + lane * 8;
            u32x8 p = *(const u32x8*)(haggP + aoff);
            bf16x8 aH, aL;
#pragma unroll
            for (int i = 0; i < 8; ++i) {
                aH[i] = (short)(p[i] & 0xffffu);
                aL[i] = (short)(p[i] >> 16);
            }
#pragma unroll
            for (int ctl = 0; ctl < 2; ++ctl) {
                const int u = h * 8 + cb * 2 + ctl;
                const size_t boff = ((size_t)u * 4 + kc) * 512 + lane * 8;
                bf16x8 bH = *(const bf16x8*)(WtH + boff);
                bf16x8 bL = *(const bf16x8*)(WtL + boff);
                accH[ctl] = __builtin_amdgcn_mfma_f32_16x16x32_bf16(aH, bH, accH[ctl], 0, 0, 0);
                accL[ctl] = __builtin_amdgcn_mfma_f32_16x16x32_bf16(aH, bL, accL[ctl], 0, 0, 0);
                accL[ctl] = __builtin_amdgcn_mfma_f32_16x16x32_bf16(aL, bH, accL[ctl], 0, 0, 0);
            }
        }
#pragma unroll
        for (int ctl = 0; ctl < 2; ++ctl)
#pragma unroll
            for (int r = 0; r < 4; ++r)
                mean[ctl][r] += fmaxf(accH[ctl][r] + accL[ctl][r], 0.f);
    }

#pragma unroll
    for (int ctl = 0; ctl < 2; ++ctl) {
        int c = cb * 32 + ctl * 16 + row;
#pragma unroll
        for (int r = 0; r < 4; ++r) {
            int gm = m0 + quad * 4 + r;
            out[(size_t)gm * 128 + c] = mean[ctl][r] * (1.f / 16.f);
        }
    }
}

// ---------------- fold for ALL 3 layers ------------------------------------------------
__global__ void fold3_kernel(
    const float* __restrict__ Ws1, const float* __restrict__ Wd1,
    const float* __restrict__ as1, const float* __restrict__ ad1,
    const float* __restrict__ Ws2, const float* __restrict__ Wd2,
    const float* __restrict__ as2, const float* __restrict__ ad2,
    const float* __restrict__ Ws3, const float* __restrict__ Wd3,
    const float* __restrict__ as3, const float* __restrict__ ad3,
    float* __restrict__ fw3)
{
    int gid = blockIdx.x * blockDim.x + threadIdx.x;
    if (gid >= 3 * 4 * 128 * 16) return;
    int l = gid / 8192, rem1 = gid % 8192;
    int f = rem1 / 2048, rem = rem1 % 2048;
    int k = rem >> 4, h = rem & 15;
    int Ntot = (l == 2) ? 512 : 2048;
    int C = Ntot >> 4;
    const float* W;
    const float* a;
    if (l == 0) { W = (f & 1) ? Wd1 : Ws1; a = (f & 1) ? ad1 : as1; }
    else if (l == 1) { W = (f & 1) ? Wd2 : Ws2; a = (f & 1) ? ad2 : as2; }
    else { W = (f & 1) ? Wd3 : Ws3; a = (f & 1) ? ad3 : as3; }
    if (f >= 2) { W += 128 * Ntot; a += 16 * C; }
    float s = 0.f;
    for (int c = 0; c < C; ++c) s += W[(size_t)k * Ntot + h * C + c] * a[h * C + c];
    fw3[gid] = s;
}

// ---------------- score2both: all four folded scores of a layer ------------------------
__global__ __launch_bounds__(256) void score2both_kernel(
    const float* __restrict__ Hd, const float* __restrict__ Hl,
    const float* __restrict__ fw,
    float* __restrict__ ssb0, float* __restrict__ sdb1,
    float* __restrict__ sdb0, float* __restrict__ ssb1)
{
    __shared__ float hs[16 * 128];
    __shared__ float wa[128 * 16];
    __shared__ float wb[128 * 16];
    int b = blockIdx.x;
    const float* Hf; const float* WfA; const float* WfB;
    float* outA; float* outB; int n0;
    if (b < ND / 16) {
        Hf = Hd; WfA = fw; WfB = fw + 3 * 2048; outA = ssb0; outB = sdb1; n0 = b * 16;
    } else {
        Hf = Hl; WfA = fw + 1 * 2048; WfB = fw + 2 * 2048; outA = sdb0; outB = ssb1;
        n0 = (b - ND / 16) * 16;
    }
    int tid = threadIdx.x;
#pragma unroll
    for (int i = 0; i < 8; ++i) {
        int idx = tid + i * 256;
        int nl = idx >> 7, k = idx & 127;
        hs[idx] = Hf[(size_t)(n0 + nl) * 128 + k];
        wa[idx] = WfA[idx];
        wb[idx] = WfB[idx];
    }
    __syncthreads();
    int nl = tid >> 4, h = tid & 15;
    float sa = 0.f, sb = 0.f;
    for (int k = 0; k < 128; ++k) {
        float hv = hs[nl * 128 + k];
        sa += hv * wa[k * 16 + h];
        sb += hv * wb[k * 16 + h];
    }
    int gn = n0 + nl;
    outA[gn * 16 + h] = sa;
    outB[gn * 16 + h] = sb;
}

// ---------------- edge logits, both directions: al = leaky_relu(ss[src]+sd[dst]) -------
__global__ void ale_kernel(
    const int* __restrict__ esrc, const int* __restrict__ edst,
    const float* __restrict__ ssb0, const float* __restrict__ sdb0,
    const float* __restrict__ ssb1, const float* __restrict__ sdb1,
    float* __restrict__ al0, float* __restrict__ al1)
{
    int t = blockIdx.x * 256 + threadIdx.x;
    if (t >= NE * 16) return;
    int e = t >> 4, h = t & 15;
    int s = esrc[e], d = edst[e];
    float a0 = ssb0[s * 16 + h] + sdb0[d * 16 + h];
    al0[t] = a0 >= 0.f ? a0 : 0.2f * a0;
    float a1 = ssb1[d * 16 + h] + sdb1[s * 16 + h];
    al1[t] = a1 >= 0.f ? a1 : 0.2f * a1;
}

// ---------------- per-(dst,head) online softmax max/sum over CSR segment ---------------
// ms layout: [d*32 + h] = m, [d*32 + 16 + h] = s
__global__ void ms_kernel(
    const int* __restrict__ offl, const int* __restrict__ csrl, const float* __restrict__ al0,
    float* __restrict__ msl,
    const int* __restrict__ offd, const int* __restrict__ csrd, const float* __restrict__ al1,
    float* __restrict__ msd)
{
    int t = blockIdx.x * 256 + threadIdx.x;
    const int* off; const int* csr; const float* al; float* ms; int d;
    if (t < NL * 16) { off = offl; csr = csrl; al = al0; ms = msl; d = t >> 4; }
    else {
        t -= NL * 16;
        if (t >= ND * 16) return;
        off = offd; csr = csrd; al = al1; ms = msd; d = t >> 4;
    }
    int h = t & 15;
    int e0 = off[d], e1 = off[d + 1];
    float m = -1e30f, s = 0.f;
    for (int e = e0; e < e1; ++e) {
        float a = al[csr[e] * 16 + h];
        if (a > m) { s = s * __expf(m - a) + 1.f; m = a; }
        else s += __expf(a - m);
    }
    ms[d * 32 + h] = m;
    ms[d * 32 + 16 + h] = s + 1e-16f;
}

// ---------------- edge-parallel alpha = exp(al - m[dst]) / s[dst], in place ------------
__global__ void alphaw_kernel(
    const int* __restrict__ esrc, const int* __restrict__ edst,
    const float* __restrict__ msl, const float* __restrict__ msd,
    float* __restrict__ al0, float* __restrict__ al1)
{
    int t = blockIdx.x * 256 + threadIdx.x;
    if (t >= NE * 16) return;
    int e = t >> 4, h = t & 15;
    int d0 = edst[e];
    al0[t] = __expf(al0[t] - msl[d0 * 32 + h]) / msl[d0 * 32 + 16 + h];
    int d1 = esrc[e];
    al1[t] = __expf(al1[t] - msd[d1 * 32 + h]) / msd[d1 * 32 + 16 + h];
}

// ---------------- CSR build ----------------
__global__ void hist_kernel(const int* __restrict__ esrc, const int* __restrict__ edst,
                            int* __restrict__ degl, int* __restrict__ degd)
{
    int e = blockIdx.x * blockDim.x + threadIdx.x;
    if (e >= NE) return;
    atomicAdd(&degl[edst[e]], 1);
    atomicAdd(&degd[esrc[e]], 1);
}

__global__ __launch_bounds__(1024) void scan2_kernel(
    const int* __restrict__ degA, int* __restrict__ offA, int nA,
    const int* __restrict__ degB, int* __restrict__ offB, int nB)
{
    __shared__ int ps[1024];
    const int* deg = blockIdx.x ? degB : degA;
    int* off = blockIdx.x ? offB : offA;
    int n = blockIdx.x ? nB : nA;
    int tid = threadIdx.x;
    int chunk = (n + 1023) >> 10;
    int start = tid * chunk, end = min(start + chunk, n);
    int p = 0;
    for (int i = start; i < end; ++i) p += deg[i];
    ps[tid] = p;
    __syncthreads();
    for (int o = 1; o < 1024; o <<= 1) {
        int v = (tid >= o) ? ps[tid - o] : 0;
        __syncthreads();
        ps[tid] += v;
        __syncthreads();
    }
    int run = ps[tid] - p;
    for (int i = start; i < end; ++i) { off[i] = run; run += deg[i]; }
    if (tid == 1023) off[n] = ps[1023];
}

__global__ void scatter_kernel(const int* __restrict__ esrc, const int* __restrict__ edst,
                               const int* __restrict__ offl, const int* __restrict__ offd,
                               int* __restrict__ curl, int* __restrict__ curd,
                               int* __restrict__ csrl, int* __restrict__ csrd)
{
    int e = blockIdx.x * blockDim.x + threadIdx.x;
    if (e >= NE) return;
    int dl = edst[e]; int p = atomicAdd(&curl[dl], 1); csrl[offl[dl] + p] = e;
    int dd = esrc[e]; int q = atomicAdd(&curd[dd], 1); csrd[offd[dd] + q] = e;
}

// ---------------- fused per-head aggregation -> packed fragment-tiled hagg -------------
// alpha precomputed; two consecutive dst nodes per block.
__global__ __launch_bounds__(256) void hagg_kernel(
    const float* __restrict__ hsrc,   // [n_src, 128]
    const float* __restrict__ alpha,  // [NE, 16]
    const int* __restrict__ off, const int* __restrict__ csr, const int* __restrict__ srcidx,
    unsigned int* __restrict__ haggP)
{
    __shared__ float alpha_s[2][8][17];
    __shared__ int src_s[2][8];
    const int d0 = blockIdx.x * 2;
    const int tid = threadIdx.x;

    const int half = tid >> 7;       // node within block (wave-uniform)
    const int c = tid & 127;         // channel
    const int d = d0 + half;
    const int my_e0 = off[d];
    const int my_deg = off[d + 1] - my_e0;
    const int deg0 = off[d0 + 1] - off[d0];
    const int deg1 = off[d0 + 2] - off[d0 + 1];
    const int degmax = deg0 > deg1 ? deg0 : deg1;
    const int ntrip = (degmax + 7) >> 3;

    float acc[16];
#pragma unroll
    for (int h = 0; h < 16; ++h) acc[h] = 0.f;

    for (int trip = 0; trip < ntrip; ++trip) {
        int ce = trip * 8;
        {
            int ei = c >> 4, h = c & 15;
            if (ce + ei < my_deg) {
                int eid = csr[my_e0 + ce + ei];
                alpha_s[half][ei][h] = alpha[(size_t)eid * 16 + h];
                if (h == 0) src_s[half][ei] = srcidx[eid];
            }
        }
        __syncthreads();
        int nc = min(8, my_deg - ce);
        for (int ei = 0; ei < nc; ++ei) {
            float v = hsrc[(size_t)src_s[half][ei] * 128 + c];
#pragma unroll
            for (int h = 0; h < 16; ++h)
                acc[h] += alpha_s[half][ei][h] * v;
        }
        __syncthreads();
    }

    const int t = d >> 4;
    const int lane8 = ((d & 15) + 16 * ((c >> 3) & 3)) * 8 + (c & 7);
    const int kc = c >> 5;
#pragma unroll
    for (int h = 0; h < 16; ++h) {
        float v = acc[h];
        unsigned short hb = f2bf(v);
        unsigned short lb = f2bf(v - bf2f(hb));
        size_t idx = (((size_t)t * 16 + h) * 4 + kc) * 512 + lane8;
        haggP[idx] = (unsigned int)hb | ((unsigned int)lb << 16);
    }
}

// ---------------- layer 3 merged: gather + bias + relu + mean + penalty ----------------
// alpha precomputed. blocks [0, NL): dst lncrna; [NL, NL+ND): dst disease.
__global__ __launch_bounds__(256) void agg32both_kernel(
    const float* __restrict__ zs3d, const float* __restrict__ zs3l,
    const float* __restrict__ alpha0, const float* __restrict__ alpha1,
    const int* __restrict__ offl, const int* __restrict__ csrl,
    const int* __restrict__ offd, const int* __restrict__ csrd,
    const int* __restrict__ esrc, const int* __restrict__ edst,
    const float* __restrict__ bias512,  // [2][512]
    const float* __restrict__ pw, const float* __restrict__ pb,  // [2,32],[2]
    float* __restrict__ hlp, float* __restrict__ hdp)
{
    __shared__ float alpha_s[16][17];
    __shared__ int src_s[16];
    __shared__ float lds_out[512];
    __shared__ float hrow[32];
    int d = blockIdx.x;
    const float* zs; const float* alpha;
    const int* off; const int* csr; const int* srcidx;
    const float* bias; const float* pwt; const float* pbt; float* out;
    if (d < NL) {
        zs = zs3d; alpha = alpha0; off = offl; csr = csrl; srcidx = esrc;
        bias = bias512; pwt = pw + 32; pbt = pb + 1; out = hlp;
    } else {
        d -= NL;
        zs = zs3l; alpha = alpha1; off = offd; csr = csrd; srcidx = edst;
        bias = bias512 + 512; pwt = pw; pbt = pb; out = hdp;
    }
    const int tid = threadIdx.x;
    const int e0 = off[d], e1 = off[d + 1];

    float acc0 = 0.f, acc1 = 0.f;
    const int hsel = tid >> 4;

    for (int ce = e0; ce < e1; ce += 16) {
        int nc = min(16, e1 - ce);
        if (tid < nc * 16) {
            int ei = tid >> 4, h = tid & 15;
            int eid = csr[ce + ei];
            alpha_s[ei][h] = alpha[(size_t)eid * 16 + h];
            if (h == 0) src_s[ei] = srcidx[eid];
        }
        __syncthreads();
        for (int ei = 0; ei < nc; ++ei) {
            float a = alpha_s[ei][hsel];
            float2 v = *(const float2*)(zs + (size_t)src_s[ei] * 512 + tid * 2);
            acc0 += a * v.x;
            acc1 += a * v.y;
        }
        __syncthreads();
    }

    lds_out[tid * 2] = fmaxf(acc0 + bias[tid * 2], 0.f);
    lds_out[tid * 2 + 1] = fmaxf(acc1 + bias[tid * 2 + 1], 0.f);
    __syncthreads();
    if (tid < 32) {
        float s = 0.f;
#pragma unroll
        for (int hh = 0; hh < 16; ++hh) s += lds_out[hh * 32 + tid];
        hrow[tid] = s * (1.f / 16.f);
    }
    __syncthreads();
    if (tid < 32) {
        float t = pbt[0];
#pragma unroll
        for (int c = 0; c < 32; ++c) t += hrow[c] * pwt[c];
        out[(size_t)d * 32 + tid] = hrow[tid] * expf(t);
    }
}

// ---------------- final MLP on label edges ----------------
__global__ __launch_bounds__(256) void mlp_kernel(
    const float* __restrict__ hd, const float* __restrict__ hl,
    const int* __restrict__ ls, const int* __restrict__ ld,
    const float* __restrict__ w1, const float* __restrict__ b1,
    const float* __restrict__ w2, const float* __restrict__ b2,
    float* __restrict__ out, int M)
{
    __shared__ float w1s[64 * 64];
    __shared__ float b1s[64];
    __shared__ float w2s[64];
    int tid = threadIdx.x;
#pragma unroll
    for (int i = 0; i < 16; ++i) w1s[tid + i * 256] = w1[tid + i * 256];
    if (tid < 64) { b1s[tid] = b1[tid]; w2s[tid] = w2[tid]; }
    __syncthreads();
    int m = blockIdx.x * 256 + tid;
    if (m >= M) return;
    float f[64];
    const float* hp = hd + (size_t)ls[m] * 32;
    const float* lp = hl + (size_t)ld[m] * 32;
#pragma unroll
    for (int c = 0; c < 32; ++c) { f[c] = hp[c]; f[32 + c] = lp[c]; }
    float o = b2[0];
    for (int j = 0; j < 64; ++j) {
        float hj = b1s[j];
#pragma unroll
        for (int k = 0; k < 64; ++k) hj += f[k] * w1s[k * 64 + j];
        hj = fmaxf(hj, 0.f);
        o += hj * w2s[j];
    }
    out[m] = o;
}

extern "C" void kernel_launch(void* const* d_in, const int* in_sizes, int n_in,
                              void* d_out, int out_size, void* d_ws, size_t ws_size,
                              hipStream_t stream)
{
    const float* x_d = (const float*)d_in[0];
    const float* x_l = (const float*)d_in[1];
    const int* node_id_d = (const int*)d_in[2];
    const int* node_id_l = (const int*)d_in[3];
    const int* edge_src = (const int*)d_in[4];
    const int* edge_dst = (const int*)d_in[5];
    const int* label_src = (const int*)d_in[6];
    const int* label_dst = (const int*)d_in[7];
    const float* emb_d = (const float*)d_in[8];
    const float* emb_l = (const float*)d_in[9];
    const float* lin_dw = (const float*)d_in[10];
    const float* lin_db = (const float*)d_in[11];
    const float* lin_lw = (const float*)d_in[12];
    const float* lin_lb = (const float*)d_in[13];
    const float* Ws[3] = {(const float*)d_in[14], (const float*)d_in[19], (const float*)d_in[24]};
    const float* Wd[3] = {(const float*)d_in[15], (const float*)d_in[20], (const float*)d_in[25]};
    const float* as_[3] = {(const float*)d_in[16], (const float*)d_in[21], (const float*)d_in[26]};
    const float* ad_[3] = {(const float*)d_in[17], (const float*)d_in[22], (const float*)d_in[27]};
    const float* bb[3] = {(const float*)d_in[18], (const float*)d_in[23], (const float*)d_in[28]};
    const float* pw = (const float*)d_in[29];
    const float* pb = (const float*)d_in[30];
    const float* fc1w = (const float*)d_in[31];
    const float* fc1b = (const float*)d_in[32];
    const float* fc2w = (const float*)d_in[33];
    const float* fc2b = (const float*)d_in[34];

    char* wsb = (char*)d_ws;
    size_t woff = 0;
    auto carve = [&](size_t bytes) -> void* {
        woff = (woff + 255) & ~(size_t)255;
        void* p = wsb + woff;
        woff += bytes;
        return p;
    };
    float* hdA = (float*)carve((size_t)ND * 128 * 4);
    float* hlA = (float*)carve((size_t)NL * 128 * 4);
    float* hdB = (float*)carve((size_t)ND * 128 * 4);
    float* hlB = (float*)carve((size_t)NL * 128 * 4);
    unsigned int* haggP = (unsigned int*)carve((size_t)NL * 2048 * 4);  // L3 reuses as zs3d/zs3l
    unsigned short* WtH = (unsigned short*)carve((size_t)2 * 2 * 2048 * 128 * 2);
    unsigned short* WtL = (unsigned short*)carve((size_t)2 * 2 * 2048 * 128 * 2);
    float* ssb0 = (float*)carve((size_t)ND * 16 * 4);
    float* sdb0 = (float*)carve((size_t)NL * 16 * 4);
    float* ssb1 = (float*)carve((size_t)NL * 16 * 4);
    float* sdb1 = (float*)carve((size_t)ND * 16 * 4);
    float* al0 = (float*)carve((size_t)NE * 16 * 4);
    float* al1 = (float*)carve((size_t)NE * 16 * 4);
    float* msl = (float*)carve((size_t)NL * 32 * 4);
    float* msd = (float*)carve((size_t)ND * 32 * 4);
    float* fw3 = (float*)carve((size_t)3 * 4 * 2048 * 4);
    int* degl = (int*)carve((size_t)(2 * (NL + ND)) * 4);
    int* degd = degl + NL;
    int* curl = degd + ND;
    int* curd = curl + NL;
    int* offl = (int*)carve((size_t)(NL + 1) * 4);
    int* offd = (int*)carve((size_t)(ND + 1) * 4);
    int* csrl = (int*)carve((size_t)NE * 4);
    int* csrd = (int*)carve((size_t)NE * 4);
    float* hdp = (float*)carve((size_t)ND * 32 * 4);
    float* hlp = (float*)carve((size_t)NL * 32 * 4);

    hipMemsetAsync(degl, 0, (size_t)2 * (NL + ND) * 4, stream);

    hist_kernel<<<(NE + 255) / 256, 256, 0, stream>>>(edge_src, edge_dst, degl, degd);
    scan2_kernel<<<2, 1024, 0, stream>>>(degl, offl, NL, degd, offd, ND);
    scatter_kernel<<<(NE + 255) / 256, 256, 0, stream>>>(edge_src, edge_dst, offl, offd, curl, curd, csrl, csrd);

    fold3_kernel<<<(3 * 8192 + 255) / 256, 256, 0, stream>>>(
        Ws[0], Wd[0], as_[0], ad_[0], Ws[1], Wd[1], as_[1], ad_[1],
        Ws[2], Wd[2], as_[2], ad_[2], fw3);
    wt2_kernel<<<(2 * 524288 + 255) / 256, 256, 0, stream>>>(Ws[0], Ws[1], WtH, WtL);

    inlin_kernel<<<dim3(2, 750), 256, 0, stream>>>(
        x_d, x_l, lin_dw, lin_lw, lin_db, lin_lb, emb_d, emb_l,
        node_id_d, node_id_l, hdA, hlA);

    float* hd_cur = hdA; float* hd_nxt = hdB;
    float* hl_cur = hlA; float* hl_nxt = hlB;

    const int grid_e16 = (NE * 16 + 255) / 256;
    const int grid_ms = ((NL + ND) * 16 + 255) / 256;

    // ---- layers 1-2: aggregate-then-project (split-bf16 MFMA, fused head-mean) ----
    for (int L = 0; L < 2; ++L) {
        const float* fw = fw3 + (size_t)L * 8192;
        const unsigned short* wtH = WtH + (size_t)L * 524288;
        const unsigned short* wtL = WtL + (size_t)L * 524288;

        score2both_kernel<<<ND / 16 + NL / 16, 256, 0, stream>>>(
            hd_cur, hl_cur, fw, ssb0, sdb1, sdb0, ssb1);
        ale_kernel<<<grid_e16, 256, 0, stream>>>(edge_src, edge_dst, ssb0, sdb0, ssb1, sdb1, al0, al1);
        ms_kernel<<<grid_ms, 256, 0, stream>>>(offl, csrl, al0, msl, offd, csrd, al1, msd);
        alphaw_kernel<<<grid_e16, 256, 0, stream>>>(edge_src, edge_dst, msl, msd, al0, al1);

        // edge type 0: disease -> lncrna (dst = lncrna)
        hagg_kernel<<<NL / 2, 256, 0, stream>>>(hd_cur, al0, offl, csrl, edge_src, haggP);
        gemm2r_kernel<<<dim3(NL / 64, 4), 256, 0, stream>>>(haggP, wtH, wtL, bb[L], hl_nxt, NL);

        // edge type 1: lncrna -> disease (dst = disease)
        hagg_kernel<<<ND / 2, 256, 0, stream>>>(hl_cur, al1, offd, csrd, edge_dst, haggP);
        gemm2r_kernel<<<dim3(ND / 64, 4), 256, 0, stream>>>(haggP,
                                                            wtH + (size_t)2048 * 128, wtL + (size_t)2048 * 128,
                                                            bb[L] + 2048, hd_nxt, ND);

        float* t;
        t = hd_cur; hd_cur = hd_nxt; hd_nxt = t;
        t = hl_cur; hl_cur = hl_nxt; hl_nxt = t;
    }

    // ---- layer 3: project-then-aggregate (fp32), merged dispatches ----
    {
        const float* fw = fw3 + 2 * 8192;
        float* zs3d = (float*)haggP;                       // [ND, 512]
        float* zs3l = (float*)haggP + (size_t)ND * 512;    // [NL, 512]
        score2both_kernel<<<ND / 16 + NL / 16, 256, 0, stream>>>(
            hd_cur, hl_cur, fw, ssb0, sdb1, sdb0, ssb1);
        ale_kernel<<<grid_e16, 256, 0, stream>>>(edge_src, edge_dst, ssb0, sdb0, ssb1, sdb1, al0, al1);
        ms_kernel<<<grid_ms, 256, 0, stream>>>(offl, csrl, al0, msl, offd, csrd, al1, msd);
        alphaw_kernel<<<grid_e16, 256, 0, stream>>>(edge_src, edge_dst, msl, msd, al0, al1);

        gemm3_kernel<<<dim3(512 / BN, 125 + 250), 256, 0, stream>>>(
            hd_cur, hl_cur, Ws[2], zs3d, zs3l);

        agg32both_kernel<<<NL + ND, 256, 0, stream>>>(
            zs3d, zs3l, al0, al1,
            offl, csrl, offd, csrd, edge_src, edge_dst,
            bb[2], pw, pb, hlp, hdp);
    }

    mlp_kernel<<<(NM + 255) / 256, 256, 0, stream>>>(hdp, hlp, label_src, label_dst,
                                                     fc1w, fc1b, fc2w, fc2b, (float*)d_out, NM);
}

// Round 15
// 873.680 us; speedup vs baseline: 1.6454x; 1.0330x over previous
//
#include <hip/hip_runtime.h>
#include <cstdint>
#include <cstddef>

#define ND 8000
#define NL 16000
#define NE 60000
#define NM 50000

#define BM 64
#define BN 64
#define BK 16

typedef __attribute__((ext_vector_type(8))) short bf16x8;
typedef __attribute__((ext_vector_type(4))) float f32x4;
typedef __attribute__((ext_vector_type(8))) unsigned int u32x8;

__device__ __forceinline__ unsigned short f2bf(float x) {
    unsigned int u = __float_as_uint(x);
    unsigned int r = (u + 0x7FFFu + ((u >> 16) & 1u)) >> 16;
    return (unsigned short)r;
}
__device__ __forceinline__ float bf2f(unsigned short b) {
    return __uint_as_float(((unsigned int)b) << 16);
}

// ---------------- merged layer-3 GEMM: zs3d = hd @ W[0], zs3l = hl @ W[1] --------------
__global__ __launch_bounds__(256) void gemm3_kernel(
    const float* __restrict__ hd, const float* __restrict__ hl,
    const float* __restrict__ W,   // [2,128,512]
    float* __restrict__ zs3d, float* __restrict__ zs3l)
{
    __shared__ float As[BK][BM + 4];
    __shared__ float Bs[BK][BN + 4];
    int mt = blockIdx.y;
    const float* A; const float* B; float* Cm;
    if (mt < 125) { A = hd; B = W; Cm = zs3d; }
    else { mt -= 125; A = hl; B = W + 128 * 512; Cm = zs3l; }
    const int tid = threadIdx.x;
    const int tx = tid & 15, ty = tid >> 4;
    const int bm = mt * BM, bn = blockIdx.x * BN;
    float acc[4][4] = {};
    for (int k0 = 0; k0 < 128; k0 += BK) {
#pragma unroll
        for (int i = 0; i < 4; ++i) {
            int idx = tid + i * 256;
            int ml = idx >> 4, kl = idx & 15;
            As[kl][ml] = A[(size_t)(bm + ml) * 128 + k0 + kl];
        }
#pragma unroll
        for (int i = 0; i < 4; ++i) {
            int idx = tid + i * 256;
            int kl = idx >> 6, nl = idx & 63;
            Bs[kl][nl] = B[(size_t)(k0 + kl) * 512 + bn + nl];
        }
        __syncthreads();
#pragma unroll
        for (int k = 0; k < BK; ++k) {
            float4 av = *(const float4*)&As[k][ty * 4];
            float4 bv = *(const float4*)&Bs[k][tx * 4];
            float a4[4] = {av.x, av.y, av.z, av.w};
            float b4[4] = {bv.x, bv.y, bv.z, bv.w};
#pragma unroll
            for (int i = 0; i < 4; ++i)
#pragma unroll
                for (int j = 0; j < 4; ++j)
                    acc[i][j] += a4[i] * b4[j];
        }
        __syncthreads();
    }
#pragma unroll
    for (int i = 0; i < 4; ++i) {
        int gm = bm + ty * 4 + i;
        int gn0 = bn + tx * 4;
        float4 v;
        float* vp = &v.x;
#pragma unroll
        for (int j = 0; j < 4; ++j) vp[j] = acc[i][j];
        *(float4*)&Cm[(size_t)gm * 512 + gn0] = v;
    }
}

// ---------------- fused input linears, 32-row tiles ------------------------------------
__global__ __launch_bounds__(256) void inlin_kernel(
    const float* __restrict__ x_d, const float* __restrict__ x_l,
    const float* __restrict__ wd, const float* __restrict__ wl,
    const float* __restrict__ bd, const float* __restrict__ bl,
    const float* __restrict__ embd, const float* __restrict__ embl,
    const int* __restrict__ nidd, const int* __restrict__ nidl,
    float* __restrict__ hd, float* __restrict__ hl)
{
    __shared__ float As[BK][32 + 4];
    __shared__ float Bs[BK][BN + 4];
    int mt = blockIdx.y;
    const float* A; const float* B; const float* bias; const float* emb;
    const int* nid; float* out;
    int K;
    if (mt < 250) {
        A = x_d; B = wd; bias = bd; emb = embd; nid = nidd; out = hd; K = 412;
    } else {
        mt -= 250;
        A = x_l; B = wl; bias = bl; emb = embl; nid = nidl; out = hl; K = 240;
    }
    const int tid = threadIdx.x;
    const int tx = tid & 15, ty = tid >> 4;
    const int bm = mt * 32, bn = blockIdx.x * BN;
    float acc[2][4] = {};
    for (int k0 = 0; k0 < K; k0 += BK) {
#pragma unroll
        for (int i = 0; i < 2; ++i) {
            int idx = tid + i * 256;
            int ml = idx >> 4, kl = idx & 15;
            int gk = k0 + kl;
            As[kl][ml] = (gk < K) ? A[(size_t)(bm + ml) * K + gk] : 0.f;
        }
#pragma unroll
        for (int i = 0; i < 4; ++i) {
            int idx = tid + i * 256;
            int kl = idx >> 6, nl = idx & 63;
            int gk = k0 + kl;
            Bs[kl][nl] = (gk < K) ? B[(size_t)gk * 128 + bn + nl] : 0.f;
        }
        __syncthreads();
#pragma unroll
        for (int k = 0; k < BK; ++k) {
            float a0 = As[k][ty * 2];
            float a1 = As[k][ty * 2 + 1];
            float4 bv = *(const float4*)&Bs[k][tx * 4];
            float b4[4] = {bv.x, bv.y, bv.z, bv.w};
#pragma unroll
            for (int j = 0; j < 4; ++j) {
                acc[0][j] += a0 * b4[j];
                acc[1][j] += a1 * b4[j];
            }
        }
        __syncthreads();
    }
#pragma unroll
    for (int i = 0; i < 2; ++i) {
        int gm = bm + ty * 2 + i;
        int gn0 = bn + tx * 4;
        const float* ep = emb + (size_t)nid[gm] * 128 + gn0;
        float4 v;
        float* vp = &v.x;
#pragma unroll
        for (int j = 0; j < 4; ++j)
            vp[j] = acc[i][j] + bias[gn0 + j] + ep[j];
        *(float4*)&out[(size_t)gm * 128 + gn0] = v;
    }
}

// ---------------- W transpose + split-bf16 into MFMA-fragment tiling, BOTH layers ------
__global__ void wt2_kernel(const float* __restrict__ W0, const float* __restrict__ W1,
                           unsigned short* __restrict__ WtH, unsigned short* __restrict__ WtL)
{
    int gid = blockIdx.x * 256 + threadIdx.x;
    if (gid >= 2 * 2 * 128 * 2048) return;
    int l = gid >> 19;
    int rem0 = gid & 524287;
    int dir = rem0 >> 18;
    int rem = rem0 & 262143;
    int k = rem >> 11, n = rem & 2047;
    const float* W = l ? W1 : W0;
    float v = W[(size_t)dir * 262144 + (size_t)k * 2048 + n];
    unsigned short hb = f2bf(v);
    unsigned short lb = f2bf(v - bf2f(hb));
    int u = n >> 4;
    int lane = (n & 15) + 16 * ((k >> 3) & 3);
    size_t o = (size_t)l * 524288 + (size_t)dir * 262144 +
               ((size_t)u * 4 + (k >> 5)) * 512 + lane * 8 + (k & 7);
    WtH[o] = hb;
    WtL[o] = lb;
}

// ---------------- fused per-head projection + bias + relu + HEAD-MEAN (layers 1-2) ----
// grid ((M/64)*4): column-quarter cb = blockIdx.x & 3 varies FASTEST so the 4 blocks
// sharing an A m-tile are co-resident -> A fetched from HBM once, rest hit L2/L3.
__global__ __launch_bounds__(256) void gemm2r_kernel(
    const unsigned int* __restrict__ haggP,
    const unsigned short* __restrict__ WtH, const unsigned short* __restrict__ WtL,
    const float* __restrict__ bias, float* __restrict__ out, int M)
{
    const int wave = threadIdx.x >> 6;
    const int lane = threadIdx.x & 63;
    const int cb = blockIdx.x & 3;           // column quarter (0..3), fastest
    const int mt = blockIdx.x >> 2;
    const int m0 = mt * 64 + wave * 16;
    const int t = m0 >> 4;
    const int row = lane & 15;
    const int quad = lane >> 4;

    f32x4 mean[2] = {};

    for (int h = 0; h < 16; ++h) {
        f32x4 accH[2], accL[2];
#pragma unroll
        for (int ctl = 0; ctl < 2; ++ctl) {
            float bv = bias[h * 128 + cb * 32 + ctl * 16 + row];
            accH[ctl] = (f32x4){bv, bv, bv, bv};
            accL[ctl] = (f32x4){0.f, 0.f, 0.f, 0.f};
        }
#pragma unroll
        for (int kc = 0; kc < 4; ++kc) {
            const size_t aoff = (((size_t)t * 16 + h) * 4 + kc) * 512 + lane * 8;
            u32x8 p = *(const u32x8*)(haggP + aoff);
            bf16x8 aH, aL;
#pragma unroll
            for (int i = 0; i < 8; ++i) {
                aH[i] = (short)(p[i] & 0xffffu);
                aL[i] = (short)(p[i] >> 16);
            }
#pragma unroll
            for (int ctl = 0; ctl < 2; ++ctl) {
                const int u = h * 8 + cb * 2 + ctl;
                const size_t boff = ((size_t)u * 4 + kc) * 512 + lane * 8;
                bf16x8 bH = *(const bf16x8*)(WtH + boff);
                bf16x8 bL = *(const bf16x8*)(WtL + boff);
                accH[ctl] = __builtin_amdgcn_mfma_f32_16x16x32_bf16(aH, bH, accH[ctl], 0, 0, 0);
                accL[ctl] = __builtin_amdgcn_mfma_f32_16x16x32_bf16(aH, bL, accL[ctl], 0, 0, 0);
                accL[ctl] = __builtin_amdgcn_mfma_f32_16x16x32_bf16(aL, bH, accL[ctl], 0, 0, 0);
            }
        }
#pragma unroll
        for (int ctl = 0; ctl < 2; ++ctl)
#pragma unroll
            for (int r = 0; r < 4; ++r)
                mean[ctl][r] += fmaxf(accH[ctl][r] + accL[ctl][r], 0.f);
    }

#pragma unroll
    for (int ctl = 0; ctl < 2; ++ctl) {
        int c = cb * 32 + ctl * 16 + row;
#pragma unroll
        for (int r = 0; r < 4; ++r) {
            int gm = m0 + quad * 4 + r;
            out[(size_t)gm * 128 + c] = mean[ctl][r] * (1.f / 16.f);
        }
    }
}

// ---------------- fold for ALL 3 layers ------------------------------------------------
__global__ void fold3_kernel(
    const float* __restrict__ Ws1, const float* __restrict__ Wd1,
    const float* __restrict__ as1, const float* __restrict__ ad1,
    const float* __restrict__ Ws2, const float* __restrict__ Wd2,
    const float* __restrict__ as2, const float* __restrict__ ad2,
    const float* __restrict__ Ws3, const float* __restrict__ Wd3,
    const float* __restrict__ as3, const float* __restrict__ ad3,
    float* __restrict__ fw3)
{
    int gid = blockIdx.x * blockDim.x + threadIdx.x;
    if (gid >= 3 * 4 * 128 * 16) return;
    int l = gid / 8192, rem1 = gid % 8192;
    int f = rem1 / 2048, rem = rem1 % 2048;
    int k = rem >> 4, h = rem & 15;
    int Ntot = (l == 2) ? 512 : 2048;
    int C = Ntot >> 4;
    const float* W;
    const float* a;
    if (l == 0) { W = (f & 1) ? Wd1 : Ws1; a = (f & 1) ? ad1 : as1; }
    else if (l == 1) { W = (f & 1) ? Wd2 : Ws2; a = (f & 1) ? ad2 : as2; }
    else { W = (f & 1) ? Wd3 : Ws3; a = (f & 1) ? ad3 : as3; }
    if (f >= 2) { W += 128 * Ntot; a += 16 * C; }
    float s = 0.f;
    for (int c = 0; c < C; ++c) s += W[(size_t)k * Ntot + h * C + c] * a[h * C + c];
    fw3[gid] = s;
}

// ---------------- score2both: all four folded scores of a layer ------------------------
__global__ __launch_bounds__(256) void score2both_kernel(
    const float* __restrict__ Hd, const float* __restrict__ Hl,
    const float* __restrict__ fw,
    float* __restrict__ ssb0, float* __restrict__ sdb1,
    float* __restrict__ sdb0, float* __restrict__ ssb1)
{
    __shared__ float hs[16 * 128];
    __shared__ float wa[128 * 16];
    __shared__ float wb[128 * 16];
    int b = blockIdx.x;
    const float* Hf; const float* WfA; const float* WfB;
    float* outA; float* outB; int n0;
    if (b < ND / 16) {
        Hf = Hd; WfA = fw; WfB = fw + 3 * 2048; outA = ssb0; outB = sdb1; n0 = b * 16;
    } else {
        Hf = Hl; WfA = fw + 1 * 2048; WfB = fw + 2 * 2048; outA = sdb0; outB = ssb1;
        n0 = (b - ND / 16) * 16;
    }
    int tid = threadIdx.x;
#pragma unroll
    for (int i = 0; i < 8; ++i) {
        int idx = tid + i * 256;
        int nl = idx >> 7, k = idx & 127;
        hs[idx] = Hf[(size_t)(n0 + nl) * 128 + k];
        wa[idx] = WfA[idx];
        wb[idx] = WfB[idx];
    }
    __syncthreads();
    int nl = tid >> 4, h = tid & 15;
    float sa = 0.f, sb = 0.f;
    for (int k = 0; k < 128; ++k) {
        float hv = hs[nl * 128 + k];
        sa += hv * wa[k * 16 + h];
        sb += hv * wb[k * 16 + h];
    }
    int gn = n0 + nl;
    outA[gn * 16 + h] = sa;
    outB[gn * 16 + h] = sb;
}

// ---------------- edge logits, both directions -----------------------------------------
__global__ void ale_kernel(
    const int* __restrict__ esrc, const int* __restrict__ edst,
    const float* __restrict__ ssb0, const float* __restrict__ sdb0,
    const float* __restrict__ ssb1, const float* __restrict__ sdb1,
    float* __restrict__ al0, float* __restrict__ al1)
{
    int t = blockIdx.x * 256 + threadIdx.x;
    if (t >= NE * 16) return;
    int e = t >> 4, h = t & 15;
    int s = esrc[e], d = edst[e];
    float a0 = ssb0[s * 16 + h] + sdb0[d * 16 + h];
    al0[t] = a0 >= 0.f ? a0 : 0.2f * a0;
    float a1 = ssb1[d * 16 + h] + sdb1[s * 16 + h];
    al1[t] = a1 >= 0.f ? a1 : 0.2f * a1;
}

// ---------------- per-(dst,head) online softmax max/sum --------------------------------
__global__ void ms_kernel(
    const int* __restrict__ offl, const int* __restrict__ csrl, const float* __restrict__ al0,
    float* __restrict__ msl,
    const int* __restrict__ offd, const int* __restrict__ csrd, const float* __restrict__ al1,
    float* __restrict__ msd)
{
    int t = blockIdx.x * 256 + threadIdx.x;
    const int* off; const int* csr; const float* al; float* ms; int d;
    if (t < NL * 16) { off = offl; csr = csrl; al = al0; ms = msl; d = t >> 4; }
    else {
        t -= NL * 16;
        if (t >= ND * 16) return;
        off = offd; csr = csrd; al = al1; ms = msd; d = t >> 4;
    }
    int h = t & 15;
    int e0 = off[d], e1 = off[d + 1];
    float m = -1e30f, s = 0.f;
    for (int e = e0; e < e1; ++e) {
        float a = al[csr[e] * 16 + h];
        if (a > m) { s = s * __expf(m - a) + 1.f; m = a; }
        else s += __expf(a - m);
    }
    ms[d * 32 + h] = m;
    ms[d * 32 + 16 + h] = s + 1e-16f;
}

// ---------------- edge-parallel alpha, in place ----------------------------------------
__global__ void alphaw_kernel(
    const int* __restrict__ esrc, const int* __restrict__ edst,
    const float* __restrict__ msl, const float* __restrict__ msd,
    float* __restrict__ al0, float* __restrict__ al1)
{
    int t = blockIdx.x * 256 + threadIdx.x;
    if (t >= NE * 16) return;
    int e = t >> 4, h = t & 15;
    int d0 = edst[e];
    al0[t] = __expf(al0[t] - msl[d0 * 32 + h]) / msl[d0 * 32 + 16 + h];
    int d1 = esrc[e];
    al1[t] = __expf(al1[t] - msd[d1 * 32 + h]) / msd[d1 * 32 + 16 + h];
}

// ---------------- CSR build ----------------
__global__ void hist_kernel(const int* __restrict__ esrc, const int* __restrict__ edst,
                            int* __restrict__ degl, int* __restrict__ degd)
{
    int e = blockIdx.x * blockDim.x + threadIdx.x;
    if (e >= NE) return;
    atomicAdd(&degl[edst[e]], 1);
    atomicAdd(&degd[esrc[e]], 1);
}

__global__ __launch_bounds__(1024) void scan2_kernel(
    const int* __restrict__ degA, int* __restrict__ offA, int nA,
    const int* __restrict__ degB, int* __restrict__ offB, int nB)
{
    __shared__ int ps[1024];
    const int* deg = blockIdx.x ? degB : degA;
    int* off = blockIdx.x ? offB : offA;
    int n = blockIdx.x ? nB : nA;
    int tid = threadIdx.x;
    int chunk = (n + 1023) >> 10;
    int start = tid * chunk, end = min(start + chunk, n);
    int p = 0;
    for (int i = start; i < end; ++i) p += deg[i];
    ps[tid] = p;
    __syncthreads();
    for (int o = 1; o < 1024; o <<= 1) {
        int v = (tid >= o) ? ps[tid - o] : 0;
        __syncthreads();
        ps[tid] += v;
        __syncthreads();
    }
    int run = ps[tid] - p;
    for (int i = start; i < end; ++i) { off[i] = run; run += deg[i]; }
    if (tid == 1023) off[n] = ps[1023];
}

__global__ void scatter_kernel(const int* __restrict__ esrc, const int* __restrict__ edst,
                               const int* __restrict__ offl, const int* __restrict__ offd,
                               int* __restrict__ curl, int* __restrict__ curd,
                               int* __restrict__ csrl, int* __restrict__ csrd)
{
    int e = blockIdx.x * blockDim.x + threadIdx.x;
    if (e >= NE) return;
    int dl = edst[e]; int p = atomicAdd(&curl[dl], 1); csrl[offl[dl] + p] = e;
    int dd = esrc[e]; int q = atomicAdd(&curd[dd], 1); csrd[offd[dd] + q] = e;
}

// ---------------- fused per-head aggregation -> packed fragment-tiled hagg -------------
__global__ __launch_bounds__(256) void hagg_kernel(
    const float* __restrict__ hsrc,   // [n_src, 128]
    const float* __restrict__ alpha,  // [NE, 16]
    const int* __restrict__ off, const int* __restrict__ csr, const int* __restrict__ srcidx,
    unsigned int* __restrict__ haggP)
{
    __shared__ float alpha_s[2][8][17];
    __shared__ int src_s[2][8];
    const int d0 = blockIdx.x * 2;
    const int tid = threadIdx.x;

    const int half = tid >> 7;
    const int c = tid & 127;
    const int d = d0 + half;
    const int my_e0 = off[d];
    const int my_deg = off[d + 1] - my_e0;
    const int deg0 = off[d0 + 1] - off[d0];
    const int deg1 = off[d0 + 2] - off[d0 + 1];
    const int degmax = deg0 > deg1 ? deg0 : deg1;
    const int ntrip = (degmax + 7) >> 3;

    float acc[16];
#pragma unroll
    for (int h = 0; h < 16; ++h) acc[h] = 0.f;

    for (int trip = 0; trip < ntrip; ++trip) {
        int ce = trip * 8;
        {
            int ei = c >> 4, h = c & 15;
            if (ce + ei < my_deg) {
                int eid = csr[my_e0 + ce + ei];
                alpha_s[half][ei][h] = alpha[(size_t)eid * 16 + h];
                if (h == 0) src_s[half][ei] = srcidx[eid];
            }
        }
        __syncthreads();
        int nc = min(8, my_deg - ce);
        for (int ei = 0; ei < nc; ++ei) {
            float v = hsrc[(size_t)src_s[half][ei] * 128 + c];
#pragma unroll
            for (int h = 0; h < 16; ++h)
                acc[h] += alpha_s[half][ei][h] * v;
        }
        __syncthreads();
    }

    const int t = d >> 4;
    const int lane8 = ((d & 15) + 16 * ((c >> 3) & 3)) * 8 + (c & 7);
    const int kc = c >> 5;
#pragma unroll
    for (int h = 0; h < 16; ++h) {
        float v = acc[h];
        unsigned short hb = f2bf(v);
        unsigned short lb = f2bf(v - bf2f(hb));
        size_t idx = (((size_t)t * 16 + h) * 4 + kc) * 512 + lane8;
        haggP[idx] = (unsigned int)hb | ((unsigned int)lb << 16);
    }
}

// ---------------- layer 3 merged: gather + bias + relu + mean + penalty ----------------
__global__ __launch_bounds__(256) void agg32both_kernel(
    const float* __restrict__ zs3d, const float* __restrict__ zs3l,
    const float* __restrict__ alpha0, const float* __restrict__ alpha1,
    const int* __restrict__ offl, const int* __restrict__ csrl,
    const int* __restrict__ offd, const int* __restrict__ csrd,
    const int* __restrict__ esrc, const int* __restrict__ edst,
    const float* __restrict__ bias512,
    const float* __restrict__ pw, const float* __restrict__ pb,
    float* __restrict__ hlp, float* __restrict__ hdp)
{
    __shared__ float alpha_s[16][17];
    __shared__ int src_s[16];
    __shared__ float lds_out[512];
    __shared__ float hrow[32];
    int d = blockIdx.x;
    const float* zs; const float* alpha;
    const int* off; const int* csr; const int* srcidx;
    const float* bias; const float* pwt; const float* pbt; float* out;
    if (d < NL) {
        zs = zs3d; alpha = alpha0; off = offl; csr = csrl; srcidx = esrc;
        bias = bias512; pwt = pw + 32; pbt = pb + 1; out = hlp;
    } else {
        d -= NL;
        zs = zs3l; alpha = alpha1; off = offd; csr = csrd; srcidx = edst;
        bias = bias512 + 512; pwt = pw; pbt = pb; out = hdp;
    }
    const int tid = threadIdx.x;
    const int e0 = off[d], e1 = off[d + 1];

    float acc0 = 0.f, acc1 = 0.f;
    const int hsel = tid >> 4;

    for (int ce = e0; ce < e1; ce += 16) {
        int nc = min(16, e1 - ce);
        if (tid < nc * 16) {
            int ei = tid >> 4, h = tid & 15;
            int eid = csr[ce + ei];
            alpha_s[ei][h] = alpha[(size_t)eid * 16 + h];
            if (h == 0) src_s[ei] = srcidx[eid];
        }
        __syncthreads();
        for (int ei = 0; ei < nc; ++ei) {
            float a = alpha_s[ei][hsel];
            float2 v = *(const float2*)(zs + (size_t)src_s[ei] * 512 + tid * 2);
            acc0 += a * v.x;
            acc1 += a * v.y;
        }
        __syncthreads();
    }

    lds_out[tid * 2] = fmaxf(acc0 + bias[tid * 2], 0.f);
    lds_out[tid * 2 + 1] = fmaxf(acc1 + bias[tid * 2 + 1], 0.f);
    __syncthreads();
    if (tid < 32) {
        float s = 0.f;
#pragma unroll
        for (int hh = 0; hh < 16; ++hh) s += lds_out[hh * 32 + tid];
        hrow[tid] = s * (1.f / 16.f);
    }
    __syncthreads();
    if (tid < 32) {
        float t = pbt[0];
#pragma unroll
        for (int c = 0; c < 32; ++c) t += hrow[c] * pwt[c];
        out[(size_t)d * 32 + tid] = hrow[tid] * expf(t);
    }
}

// ---------------- final MLP on label edges ----------------
__global__ __launch_bounds__(256) void mlp_kernel(
    const float* __restrict__ hd, const float* __restrict__ hl,
    const int* __restrict__ ls, const int* __restrict__ ld,
    const float* __restrict__ w1, const float* __restrict__ b1,
    const float* __restrict__ w2, const float* __restrict__ b2,
    float* __restrict__ out, int M)
{
    __shared__ float w1s[64 * 64];
    __shared__ float b1s[64];
    __shared__ float w2s[64];
    int tid = threadIdx.x;
#pragma unroll
    for (int i = 0; i < 16; ++i) w1s[tid + i * 256] = w1[tid + i * 256];
    if (tid < 64) { b1s[tid] = b1[tid]; w2s[tid] = w2[tid]; }
    __syncthreads();
    int m = blockIdx.x * 256 + tid;
    if (m >= M) return;
    float f[64];
    const float* hp = hd + (size_t)ls[m] * 32;
    const float* lp = hl + (size_t)ld[m] * 32;
#pragma unroll
    for (int c = 0; c < 32; ++c) { f[c] = hp[c]; f[32 + c] = lp[c]; }
    float o = b2[0];
    for (int j = 0; j < 64; ++j) {
        float hj = b1s[j];
#pragma unroll
        for (int k = 0; k < 64; ++k) hj += f[k] * w1s[k * 64 + j];
        hj = fmaxf(hj, 0.f);
        o += hj * w2s[j];
    }
    out[m] = o;
}

extern "C" void kernel_launch(void* const* d_in, const int* in_sizes, int n_in,
                              void* d_out, int out_size, void* d_ws, size_t ws_size,
                              hipStream_t stream)
{
    const float* x_d = (const float*)d_in[0];
    const float* x_l = (const float*)d_in[1];
    const int* node_id_d = (const int*)d_in[2];
    const int* node_id_l = (const int*)d_in[3];
    const int* edge_src = (const int*)d_in[4];
    const int* edge_dst = (const int*)d_in[5];
    const int* label_src = (const int*)d_in[6];
    const int* label_dst = (const int*)d_in[7];
    const float* emb_d = (const float*)d_in[8];
    const float* emb_l = (const float*)d_in[9];
    const float* lin_dw = (const float*)d_in[10];
    const float* lin_db = (const float*)d_in[11];
    const float* lin_lw = (const float*)d_in[12];
    const float* lin_lb = (const float*)d_in[13];
    const float* Ws[3] = {(const float*)d_in[14], (const float*)d_in[19], (const float*)d_in[24]};
    const float* Wd[3] = {(const float*)d_in[15], (const float*)d_in[20], (const float*)d_in[25]};
    const float* as_[3] = {(const float*)d_in[16], (const float*)d_in[21], (const float*)d_in[26]};
    const float* ad_[3] = {(const float*)d_in[17], (const float*)d_in[22], (const float*)d_in[27]};
    const float* bb[3] = {(const float*)d_in[18], (const float*)d_in[23], (const float*)d_in[28]};
    const float* pw = (const float*)d_in[29];
    const float* pb = (const float*)d_in[30];
    const float* fc1w = (const float*)d_in[31];
    const float* fc1b = (const float*)d_in[32];
    const float* fc2w = (const float*)d_in[33];
    const float* fc2b = (const float*)d_in[34];

    char* wsb = (char*)d_ws;
    size_t woff = 0;
    auto carve = [&](size_t bytes) -> void* {
        woff = (woff + 255) & ~(size_t)255;
        void* p = wsb + woff;
        woff += bytes;
        return p;
    };
    float* hdA = (float*)carve((size_t)ND * 128 * 4);
    float* hlA = (float*)carve((size_t)NL * 128 * 4);
    float* hdB = (float*)carve((size_t)ND * 128 * 4);
    float* hlB = (float*)carve((size_t)NL * 128 * 4);
    unsigned int* haggP = (unsigned int*)carve((size_t)NL * 2048 * 4);  // L3 reuses as zs3d/zs3l
    unsigned short* WtH = (unsigned short*)carve((size_t)2 * 2 * 2048 * 128 * 2);
    unsigned short* WtL = (unsigned short*)carve((size_t)2 * 2 * 2048 * 128 * 2);
    float* ssb0 = (float*)carve((size_t)ND * 16 * 4);
    float* sdb0 = (float*)carve((size_t)NL * 16 * 4);
    float* ssb1 = (float*)carve((size_t)NL * 16 * 4);
    float* sdb1 = (float*)carve((size_t)ND * 16 * 4);
    float* al0 = (float*)carve((size_t)NE * 16 * 4);
    float* al1 = (float*)carve((size_t)NE * 16 * 4);
    float* msl = (float*)carve((size_t)NL * 32 * 4);
    float* msd = (float*)carve((size_t)ND * 32 * 4);
    float* fw3 = (float*)carve((size_t)3 * 4 * 2048 * 4);
    int* degl = (int*)carve((size_t)(2 * (NL + ND)) * 4);
    int* degd = degl + NL;
    int* curl = degd + ND;
    int* curd = curl + NL;
    int* offl = (int*)carve((size_t)(NL + 1) * 4);
    int* offd = (int*)carve((size_t)(ND + 1) * 4);
    int* csrl = (int*)carve((size_t)NE * 4);
    int* csrd = (int*)carve((size_t)NE * 4);
    float* hdp = (float*)carve((size_t)ND * 32 * 4);
    float* hlp = (float*)carve((size_t)NL * 32 * 4);

    hipMemsetAsync(degl, 0, (size_t)2 * (NL + ND) * 4, stream);

    hist_kernel<<<(NE + 255) / 256, 256, 0, stream>>>(edge_src, edge_dst, degl, degd);
    scan2_kernel<<<2, 1024, 0, stream>>>(degl, offl, NL, degd, offd, ND);
    scatter_kernel<<<(NE + 255) / 256, 256, 0, stream>>>(edge_src, edge_dst, offl, offd, curl, curd, csrl, csrd);

    fold3_kernel<<<(3 * 8192 + 255) / 256, 256, 0, stream>>>(
        Ws[0], Wd[0], as_[0], ad_[0], Ws[1], Wd[1], as_[1], ad_[1],
        Ws[2], Wd[2], as_[2], ad_[2], fw3);
    wt2_kernel<<<(2 * 524288 + 255) / 256, 256, 0, stream>>>(Ws[0], Ws[1], WtH, WtL);

    inlin_kernel<<<dim3(2, 750), 256, 0, stream>>>(
        x_d, x_l, lin_dw, lin_lw, lin_db, lin_lb, emb_d, emb_l,
        node_id_d, node_id_l, hdA, hlA);

    float* hd_cur = hdA; float* hd_nxt = hdB;
    float* hl_cur = hlA; float* hl_nxt = hlB;

    const int grid_e16 = (NE * 16 + 255) / 256;
    const int grid_ms = ((NL + ND) * 16 + 255) / 256;

    // ---- layers 1-2: aggregate-then-project (split-bf16 MFMA, fused head-mean) ----
    for (int L = 0; L < 2; ++L) {
        const float* fw = fw3 + (size_t)L * 8192;
        const unsigned short* wtH = WtH + (size_t)L * 524288;
        const unsigned short* wtL = WtL + (size_t)L * 524288;

        score2both_kernel<<<ND / 16 + NL / 16, 256, 0, stream>>>(
            hd_cur, hl_cur, fw, ssb0, sdb1, sdb0, ssb1);
        ale_kernel<<<grid_e16, 256, 0, stream>>>(edge_src, edge_dst, ssb0, sdb0, ssb1, sdb1, al0, al1);
        ms_kernel<<<grid_ms, 256, 0, stream>>>(offl, csrl, al0, msl, offd, csrd, al1, msd);
        alphaw_kernel<<<grid_e16, 256, 0, stream>>>(edge_src, edge_dst, msl, msd, al0, al1);

        // edge type 0: disease -> lncrna (dst = lncrna)
        hagg_kernel<<<NL / 2, 256, 0, stream>>>(hd_cur, al0, offl, csrl, edge_src, haggP);
        gemm2r_kernel<<<(NL / 64) * 4, 256, 0, stream>>>(haggP, wtH, wtL, bb[L], hl_nxt, NL);

        // edge type 1: lncrna -> disease (dst = disease)
        hagg_kernel<<<ND / 2, 256, 0, stream>>>(hl_cur, al1, offd, csrd, edge_dst, haggP);
        gemm2r_kernel<<<(ND / 64) * 4, 256, 0, stream>>>(haggP,
                                                         wtH + (size_t)2048 * 128, wtL + (size_t)2048 * 128,
                                                         bb[L] + 2048, hd_nxt, ND);

        float* t;
        t = hd_cur; hd_cur = hd_nxt; hd_nxt = t;
        t = hl_cur; hl_cur = hl_nxt; hl_nxt = t;
    }

    // ---- layer 3: project-then-aggregate (fp32), merged dispatches ----
    {
        const float* fw = fw3 + 2 * 8192;
        float* zs3d = (float*)haggP;
        float* zs3l = (float*)haggP + (size_t)ND * 512;
        score2both_kernel<<<ND / 16 + NL / 16, 256, 0, stream>>>(
            hd_cur, hl_cur, fw, ssb0, sdb1, sdb0, ssb1);
        ale_kernel<<<grid_e16, 256, 0, stream>>>(edge_src, edge_dst, ssb0, sdb0, ssb1, sdb1, al0, al1);
        ms_kernel<<<grid_ms, 256, 0, stream>>>(offl, csrl, al0, msl, offd, csrd, al1, msd);
        alphaw_kernel<<<grid_e16, 256, 0, stream>>>(edge_src, edge_dst, msl, msd, al0, al1);

        gemm3_kernel<<<dim3(512 / BN, 125 + 250), 256, 0, stream>>>(
            hd_cur, hl_cur, Ws[2], zs3d, zs3l);

        agg32both_kernel<<<NL + ND, 256, 0, stream>>>(
            zs3d, zs3l, al0, al1,
            offl, csrl, offd, csrd, edge_src, edge_dst,
            bb[2], pw, pb, hlp, hdp);
    }

    mlp_kernel<<<(NM + 255) / 256, 256, 0, stream>>>(hdp, hlp, label_src, label_dst,
                                                     fc1w, fc1b, fc2w, fc2b, (float*)d_out, NM);
}

// Round 16
// 824.383 us; speedup vs baseline: 1.7438x; 1.0598x over previous
//
#include <hip/hip_runtime.h>
#include <cstdint>
#include <cstddef>

#define ND 8000
#define NL 16000
#define NE 60000
#define NM 50000

#define BM 64
#define BN 64
#define BK 16

typedef __attribute__((ext_vector_type(8))) short bf16x8;
typedef __attribute__((ext_vector_type(4))) float f32x4;
typedef __attribute__((ext_vector_type(8))) unsigned int u32x8;

__device__ __forceinline__ unsigned short f2bf(float x) {
    unsigned int u = __float_as_uint(x);
    unsigned int r = (u + 0x7FFFu + ((u >> 16) & 1u)) >> 16;
    return (unsigned short)r;
}
__device__ __forceinline__ float bf2f(unsigned short b) {
    return __uint_as_float(((unsigned int)b) << 16);
}

// ---------------- merged layer-3 GEMM: zs3d = hd @ W[0], zs3l = hl @ W[1] --------------
__global__ __launch_bounds__(256) void gemm3_kernel(
    const float* __restrict__ hd, const float* __restrict__ hl,
    const float* __restrict__ W,   // [2,128,512]
    float* __restrict__ zs3d, float* __restrict__ zs3l)
{
    __shared__ float As[BK][BM + 4];
    __shared__ float Bs[BK][BN + 4];
    int mt = blockIdx.y;
    const float* A; const float* B; float* Cm;
    if (mt < 125) { A = hd; B = W; Cm = zs3d; }
    else { mt -= 125; A = hl; B = W + 128 * 512; Cm = zs3l; }
    const int tid = threadIdx.x;
    const int tx = tid & 15, ty = tid >> 4;
    const int bm = mt * BM, bn = blockIdx.x * BN;
    float acc[4][4] = {};
    for (int k0 = 0; k0 < 128; k0 += BK) {
#pragma unroll
        for (int i = 0; i < 4; ++i) {
            int idx = tid + i * 256;
            int ml = idx >> 4, kl = idx & 15;
            As[kl][ml] = A[(size_t)(bm + ml) * 128 + k0 + kl];
        }
#pragma unroll
        for (int i = 0; i < 4; ++i) {
            int idx = tid + i * 256;
            int kl = idx >> 6, nl = idx & 63;
            Bs[kl][nl] = B[(size_t)(k0 + kl) * 512 + bn + nl];
        }
        __syncthreads();
#pragma unroll
        for (int k = 0; k < BK; ++k) {
            float4 av = *(const float4*)&As[k][ty * 4];
            float4 bv = *(const float4*)&Bs[k][tx * 4];
            float a4[4] = {av.x, av.y, av.z, av.w};
            float b4[4] = {bv.x, bv.y, bv.z, bv.w};
#pragma unroll
            for (int i = 0; i < 4; ++i)
#pragma unroll
                for (int j = 0; j < 4; ++j)
                    acc[i][j] += a4[i] * b4[j];
        }
        __syncthreads();
    }
#pragma unroll
    for (int i = 0; i < 4; ++i) {
        int gm = bm + ty * 4 + i;
        int gn0 = bn + tx * 4;
        float4 v;
        float* vp = &v.x;
#pragma unroll
        for (int j = 0; j < 4; ++j) vp[j] = acc[i][j];
        *(float4*)&Cm[(size_t)gm * 512 + gn0] = v;
    }
}

// ---------------- fused input linears, 32-row tiles ------------------------------------
__global__ __launch_bounds__(256) void inlin_kernel(
    const float* __restrict__ x_d, const float* __restrict__ x_l,
    const float* __restrict__ wd, const float* __restrict__ wl,
    const float* __restrict__ bd, const float* __restrict__ bl,
    const float* __restrict__ embd, const float* __restrict__ embl,
    const int* __restrict__ nidd, const int* __restrict__ nidl,
    float* __restrict__ hd, float* __restrict__ hl)
{
    __shared__ float As[BK][32 + 4];
    __shared__ float Bs[BK][BN + 4];
    int mt = blockIdx.y;
    const float* A; const float* B; const float* bias; const float* emb;
    const int* nid; float* out;
    int K;
    if (mt < 250) {
        A = x_d; B = wd; bias = bd; emb = embd; nid = nidd; out = hd; K = 412;
    } else {
        mt -= 250;
        A = x_l; B = wl; bias = bl; emb = embl; nid = nidl; out = hl; K = 240;
    }
    const int tid = threadIdx.x;
    const int tx = tid & 15, ty = tid >> 4;
    const int bm = mt * 32, bn = blockIdx.x * BN;
    float acc[2][4] = {};
    for (int k0 = 0; k0 < K; k0 += BK) {
#pragma unroll
        for (int i = 0; i < 2; ++i) {
            int idx = tid + i * 256;
            int ml = idx >> 4, kl = idx & 15;
            int gk = k0 + kl;
            As[kl][ml] = (gk < K) ? A[(size_t)(bm + ml) * K + gk] : 0.f;
        }
#pragma unroll
        for (int i = 0; i < 4; ++i) {
            int idx = tid + i * 256;
            int kl = idx >> 6, nl = idx & 63;
            int gk = k0 + kl;
            Bs[kl][nl] = (gk < K) ? B[(size_t)gk * 128 + bn + nl] : 0.f;
        }
        __syncthreads();
#pragma unroll
        for (int k = 0; k < BK; ++k) {
            float a0 = As[k][ty * 2];
            float a1 = As[k][ty * 2 + 1];
            float4 bv = *(const float4*)&Bs[k][tx * 4];
            float b4[4] = {bv.x, bv.y, bv.z, bv.w};
#pragma unroll
            for (int j = 0; j < 4; ++j) {
                acc[0][j] += a0 * b4[j];
                acc[1][j] += a1 * b4[j];
            }
        }
        __syncthreads();
    }
#pragma unroll
    for (int i = 0; i < 2; ++i) {
        int gm = bm + ty * 2 + i;
        int gn0 = bn + tx * 4;
        const float* ep = emb + (size_t)nid[gm] * 128 + gn0;
        float4 v;
        float* vp = &v.x;
#pragma unroll
        for (int j = 0; j < 4; ++j)
            vp[j] = acc[i][j] + bias[gn0 + j] + ep[j];
        *(float4*)&out[(size_t)gm * 128 + gn0] = v;
    }
}

// ---------------- W transpose + split-bf16 into MFMA-fragment tiling, BOTH layers ------
__global__ void wt2_kernel(const float* __restrict__ W0, const float* __restrict__ W1,
                           unsigned short* __restrict__ WtH, unsigned short* __restrict__ WtL)
{
    int gid = blockIdx.x * 256 + threadIdx.x;
    if (gid >= 2 * 2 * 128 * 2048) return;
    int l = gid >> 19;
    int rem0 = gid & 524287;
    int dir = rem0 >> 18;
    int rem = rem0 & 262143;
    int k = rem >> 11, n = rem & 2047;
    const float* W = l ? W1 : W0;
    float v = W[(size_t)dir * 262144 + (size_t)k * 2048 + n];
    unsigned short hb = f2bf(v);
    unsigned short lb = f2bf(v - bf2f(hb));
    int u = n >> 4;
    int lane = (n & 15) + 16 * ((k >> 3) & 3);
    size_t o = (size_t)l * 524288 + (size_t)dir * 262144 +
               ((size_t)u * 4 + (k >> 5)) * 512 + lane * 8 + (k & 7);
    WtH[o] = hb;
    WtL[o] = lb;
}

// ---------------- fused per-head projection + bias + relu + HEAD-MEAN (layers 1-2) ----
// XCD-aware swizzle: i = b32*32 + cb*8 + r -> mt = b32*8 + r, cb = (i>>3)&3.
// The 4 blocks sharing m-tile mt have identical i%8 -> same XCD -> A slice served
// from that XCD's L2 after the first miss (per-XCD L2s are NOT cross-coherent/shared).
__global__ __launch_bounds__(256) void gemm2r_kernel(
    const unsigned int* __restrict__ haggP,
    const unsigned short* __restrict__ WtH, const unsigned short* __restrict__ WtL,
    const float* __restrict__ bias, float* __restrict__ out, int M)
{
    const int wave = threadIdx.x >> 6;
    const int lane = threadIdx.x & 63;
    const int i = blockIdx.x;
    const int cb = (i >> 3) & 3;             // column quarter
    const int mt = (i >> 5) * 8 + (i & 7);   // m-tile
    if (mt >= (M >> 6)) return;
    const int m0 = mt * 64 + wave * 16;
    const int t = m0 >> 4;
    const int row = lane & 15;
    const int quad = lane >> 4;

    f32x4 mean[2] = {};

    for (int h = 0; h < 16; ++h) {
        f32x4 accH[2], accL[2];
#pragma unroll
        for (int ctl = 0; ctl < 2; ++ctl) {
            float bv = bias[h * 128 + cb * 32 + ctl * 16 + row];
            accH[ctl] = (f32x4){bv, bv, bv, bv};
            accL[ctl] = (f32x4){0.f, 0.f, 0.f, 0.f};
        }
#pragma unroll
        for (int kc = 0; kc < 4; ++kc) {
            const size_t aoff = (((size_t)t * 16 + h) * 4 + kc) * 512 + lane * 8;
            u32x8 p = *(const u32x8*)(haggP + aoff);
            bf16x8 aH, aL;
#pragma unroll
            for (int ii = 0; ii < 8; ++ii) {
                aH[ii] = (short)(p[ii] & 0xffffu);
                aL[ii] = (short)(p[ii] >> 16);
            }
#pragma unroll
            for (int ctl = 0; ctl < 2; ++ctl) {
                const int u = h * 8 + cb * 2 + ctl;
                const size_t boff = ((size_t)u * 4 + kc) * 512 + lane * 8;
                bf16x8 bH = *(const bf16x8*)(WtH + boff);
                bf16x8 bL = *(const bf16x8*)(WtL + boff);
                accH[ctl] = __builtin_amdgcn_mfma_f32_16x16x32_bf16(aH, bH, accH[ctl], 0, 0, 0);
                accL[ctl] = __builtin_amdgcn_mfma_f32_16x16x32_bf16(aH, bL, accL[ctl], 0, 0, 0);
                accL[ctl] = __builtin_amdgcn_mfma_f32_16x16x32_bf16(aL, bH, accL[ctl], 0, 0, 0);
            }
        }
#pragma unroll
        for (int ctl = 0; ctl < 2; ++ctl)
#pragma unroll
            for (int r = 0; r < 4; ++r)
                mean[ctl][r] += fmaxf(accH[ctl][r] + accL[ctl][r], 0.f);
    }

#pragma unroll
    for (int ctl = 0; ctl < 2; ++ctl) {
        int c = cb * 32 + ctl * 16 + row;
#pragma unroll
        for (int r = 0; r < 4; ++r) {
            int gm = m0 + quad * 4 + r;
            out[(size_t)gm * 128 + c] = mean[ctl][r] * (1.f / 16.f);
        }
    }
}

// ---------------- fold for ALL 3 layers ------------------------------------------------
__global__ void fold3_kernel(
    const float* __restrict__ Ws1, const float* __restrict__ Wd1,
    const float* __restrict__ as1, const float* __restrict__ ad1,
    const float* __restrict__ Ws2, const float* __restrict__ Wd2,
    const float* __restrict__ as2, const float* __restrict__ ad2,
    const float* __restrict__ Ws3, const float* __restrict__ Wd3,
    const float* __restrict__ as3, const float* __restrict__ ad3,
    float* __restrict__ fw3)
{
    int gid = blockIdx.x * blockDim.x + threadIdx.x;
    if (gid >= 3 * 4 * 128 * 16) return;
    int l = gid / 8192, rem1 = gid % 8192;
    int f = rem1 / 2048, rem = rem1 % 2048;
    int k = rem >> 4, h = rem & 15;
    int Ntot = (l == 2) ? 512 : 2048;
    int C = Ntot >> 4;
    const float* W;
    const float* a;
    if (l == 0) { W = (f & 1) ? Wd1 : Ws1; a = (f & 1) ? ad1 : as1; }
    else if (l == 1) { W = (f & 1) ? Wd2 : Ws2; a = (f & 1) ? ad2 : as2; }
    else { W = (f & 1) ? Wd3 : Ws3; a = (f & 1) ? ad3 : as3; }
    if (f >= 2) { W += 128 * Ntot; a += 16 * C; }
    float s = 0.f;
    for (int c = 0; c < C; ++c) s += W[(size_t)k * Ntot + h * C + c] * a[h * C + c];
    fw3[gid] = s;
}

// ---------------- score2both: all four folded scores of a layer ------------------------
__global__ __launch_bounds__(256) void score2both_kernel(
    const float* __restrict__ Hd, const float* __restrict__ Hl,
    const float* __restrict__ fw,
    float* __restrict__ ssb0, float* __restrict__ sdb1,
    float* __restrict__ sdb0, float* __restrict__ ssb1)
{
    __shared__ float hs[16 * 128];
    __shared__ float wa[128 * 16];
    __shared__ float wb[128 * 16];
    int b = blockIdx.x;
    const float* Hf; const float* WfA; const float* WfB;
    float* outA; float* outB; int n0;
    if (b < ND / 16) {
        Hf = Hd; WfA = fw; WfB = fw + 3 * 2048; outA = ssb0; outB = sdb1; n0 = b * 16;
    } else {
        Hf = Hl; WfA = fw + 1 * 2048; WfB = fw + 2 * 2048; outA = sdb0; outB = ssb1;
        n0 = (b - ND / 16) * 16;
    }
    int tid = threadIdx.x;
#pragma unroll
    for (int i = 0; i < 8; ++i) {
        int idx = tid + i * 256;
        int nl = idx >> 7, k = idx & 127;
        hs[idx] = Hf[(size_t)(n0 + nl) * 128 + k];
        wa[idx] = WfA[idx];
        wb[idx] = WfB[idx];
    }
    __syncthreads();
    int nl = tid >> 4, h = tid & 15;
    float sa = 0.f, sb = 0.f;
    for (int k = 0; k < 128; ++k) {
        float hv = hs[nl * 128 + k];
        sa += hv * wa[k * 16 + h];
        sb += hv * wb[k * 16 + h];
    }
    int gn = n0 + nl;
    outA[gn * 16 + h] = sa;
    outB[gn * 16 + h] = sb;
}

// ---------------- edge logits, both directions -----------------------------------------
__global__ void ale_kernel(
    const int* __restrict__ esrc, const int* __restrict__ edst,
    const float* __restrict__ ssb0, const float* __restrict__ sdb0,
    const float* __restrict__ ssb1, const float* __restrict__ sdb1,
    float* __restrict__ al0, float* __restrict__ al1)
{
    int t = blockIdx.x * 256 + threadIdx.x;
    if (t >= NE * 16) return;
    int e = t >> 4, h = t & 15;
    int s = esrc[e], d = edst[e];
    float a0 = ssb0[s * 16 + h] + sdb0[d * 16 + h];
    al0[t] = a0 >= 0.f ? a0 : 0.2f * a0;
    float a1 = ssb1[d * 16 + h] + sdb1[s * 16 + h];
    al1[t] = a1 >= 0.f ? a1 : 0.2f * a1;
}

// ---------------- per-(dst,head) online softmax max/sum --------------------------------
__global__ void ms_kernel(
    const int* __restrict__ offl, const int* __restrict__ csrl, const float* __restrict__ al0,
    float* __restrict__ msl,
    const int* __restrict__ offd, const int* __restrict__ csrd, const float* __restrict__ al1,
    float* __restrict__ msd)
{
    int t = blockIdx.x * 256 + threadIdx.x;
    const int* off; const int* csr; const float* al; float* ms; int d;
    if (t < NL * 16) { off = offl; csr = csrl; al = al0; ms = msl; d = t >> 4; }
    else {
        t -= NL * 16;
        if (t >= ND * 16) return;
        off = offd; csr = csrd; al = al1; ms = msd; d = t >> 4;
    }
    int h = t & 15;
    int e0 = off[d], e1 = off[d + 1];
    float m = -1e30f, s = 0.f;
    for (int e = e0; e < e1; ++e) {
        float a = al[csr[e] * 16 + h];
        if (a > m) { s = s * __expf(m - a) + 1.f; m = a; }
        else s += __expf(a - m);
    }
    ms[d * 32 + h] = m;
    ms[d * 32 + 16 + h] = s + 1e-16f;
}

// ---------------- edge-parallel alpha, in place ----------------------------------------
__global__ void alphaw_kernel(
    const int* __restrict__ esrc, const int* __restrict__ edst,
    const float* __restrict__ msl, const float* __restrict__ msd,
    float* __restrict__ al0, float* __restrict__ al1)
{
    int t = blockIdx.x * 256 + threadIdx.x;
    if (t >= NE * 16) return;
    int e = t >> 4, h = t & 15;
    int d0 = edst[e];
    al0[t] = __expf(al0[t] - msl[d0 * 32 + h]) / msl[d0 * 32 + 16 + h];
    int d1 = esrc[e];
    al1[t] = __expf(al1[t] - msd[d1 * 32 + h]) / msd[d1 * 32 + 16 + h];
}

// ---------------- CSR build ----------------
__global__ void hist_kernel(const int* __restrict__ esrc, const int* __restrict__ edst,
                            int* __restrict__ degl, int* __restrict__ degd)
{
    int e = blockIdx.x * blockDim.x + threadIdx.x;
    if (e >= NE) return;
    atomicAdd(&degl[edst[e]], 1);
    atomicAdd(&degd[esrc[e]], 1);
}

__global__ __launch_bounds__(1024) void scan2_kernel(
    const int* __restrict__ degA, int* __restrict__ offA, int nA,
    const int* __restrict__ degB, int* __restrict__ offB, int nB)
{
    __shared__ int ps[1024];
    const int* deg = blockIdx.x ? degB : degA;
    int* off = blockIdx.x ? offB : offA;
    int n = blockIdx.x ? nB : nA;
    int tid = threadIdx.x;
    int chunk = (n + 1023) >> 10;
    int start = tid * chunk, end = min(start + chunk, n);
    int p = 0;
    for (int i = start; i < end; ++i) p += deg[i];
    ps[tid] = p;
    __syncthreads();
    for (int o = 1; o < 1024; o <<= 1) {
        int v = (tid >= o) ? ps[tid - o] : 0;
        __syncthreads();
        ps[tid] += v;
        __syncthreads();
    }
    int run = ps[tid] - p;
    for (int i = start; i < end; ++i) { off[i] = run; run += deg[i]; }
    if (tid == 1023) off[n] = ps[1023];
}

__global__ void scatter_kernel(const int* __restrict__ esrc, const int* __restrict__ edst,
                               const int* __restrict__ offl, const int* __restrict__ offd,
                               int* __restrict__ curl, int* __restrict__ curd,
                               int* __restrict__ csrl, int* __restrict__ csrd)
{
    int e = blockIdx.x * blockDim.x + threadIdx.x;
    if (e >= NE) return;
    int dl = edst[e]; int p = atomicAdd(&curl[dl], 1); csrl[offl[dl] + p] = e;
    int dd = esrc[e]; int q = atomicAdd(&curd[dd], 1); csrd[offd[dd] + q] = e;
}

// ---------------- fused per-head aggregation -> packed fragment-tiled hagg -------------
__global__ __launch_bounds__(256) void hagg_kernel(
    const float* __restrict__ hsrc,   // [n_src, 128]
    const float* __restrict__ alpha,  // [NE, 16]
    const int* __restrict__ off, const int* __restrict__ csr, const int* __restrict__ srcidx,
    unsigned int* __restrict__ haggP)
{
    __shared__ float alpha_s[2][8][17];
    __shared__ int src_s[2][8];
    const int d0 = blockIdx.x * 2;
    const int tid = threadIdx.x;

    const int half = tid >> 7;
    const int c = tid & 127;
    const int d = d0 + half;
    const int my_e0 = off[d];
    const int my_deg = off[d + 1] - my_e0;
    const int deg0 = off[d0 + 1] - off[d0];
    const int deg1 = off[d0 + 2] - off[d0 + 1];
    const int degmax = deg0 > deg1 ? deg0 : deg1;
    const int ntrip = (degmax + 7) >> 3;

    float acc[16];
#pragma unroll
    for (int h = 0; h < 16; ++h) acc[h] = 0.f;

    for (int trip = 0; trip < ntrip; ++trip) {
        int ce = trip * 8;
        {
            int ei = c >> 4, h = c & 15;
            if (ce + ei < my_deg) {
                int eid = csr[my_e0 + ce + ei];
                alpha_s[half][ei][h] = alpha[(size_t)eid * 16 + h];
                if (h == 0) src_s[half][ei] = srcidx[eid];
            }
        }
        __syncthreads();
        int nc = min(8, my_deg - ce);
        for (int ei = 0; ei < nc; ++ei) {
            float v = hsrc[(size_t)src_s[half][ei] * 128 + c];
#pragma unroll
            for (int h = 0; h < 16; ++h)
                acc[h] += alpha_s[half][ei][h] * v;
        }
        __syncthreads();
    }

    const int t = d >> 4;
    const int lane8 = ((d & 15) + 16 * ((c >> 3) & 3)) * 8 + (c & 7);
    const int kc = c >> 5;
#pragma unroll
    for (int h = 0; h < 16; ++h) {
        float v = acc[h];
        unsigned short hb = f2bf(v);
        unsigned short lb = f2bf(v - bf2f(hb));
        size_t idx = (((size_t)t * 16 + h) * 4 + kc) * 512 + lane8;
        haggP[idx] = (unsigned int)hb | ((unsigned int)lb << 16);
    }
}

// ---------------- layer 3 merged: gather + bias + relu + mean + penalty ----------------
__global__ __launch_bounds__(256) void agg32both_kernel(
    const float* __restrict__ zs3d, const float* __restrict__ zs3l,
    const float* __restrict__ alpha0, const float* __restrict__ alpha1,
    const int* __restrict__ offl, const int* __restrict__ csrl,
    const int* __restrict__ offd, const int* __restrict__ csrd,
    const int* __restrict__ esrc, const int* __restrict__ edst,
    const float* __restrict__ bias512,
    const float* __restrict__ pw, const float* __restrict__ pb,
    float* __restrict__ hlp, float* __restrict__ hdp)
{
    __shared__ float alpha_s[16][17];
    __shared__ int src_s[16];
    __shared__ float lds_out[512];
    __shared__ float hrow[32];
    int d = blockIdx.x;
    const float* zs; const float* alpha;
    const int* off; const int* csr; const int* srcidx;
    const float* bias; const float* pwt; const float* pbt; float* out;
    if (d < NL) {
        zs = zs3d; alpha = alpha0; off = offl; csr = csrl; srcidx = esrc;
        bias = bias512; pwt = pw + 32; pbt = pb + 1; out = hlp;
    } else {
        d -= NL;
        zs = zs3l; alpha = alpha1; off = offd; csr = csrd; srcidx = edst;
        bias = bias512 + 512; pwt = pw; pbt = pb; out = hdp;
    }
    const int tid = threadIdx.x;
    const int e0 = off[d], e1 = off[d + 1];

    float acc0 = 0.f, acc1 = 0.f;
    const int hsel = tid >> 4;

    for (int ce = e0; ce < e1; ce += 16) {
        int nc = min(16, e1 - ce);
        if (tid < nc * 16) {
            int ei = tid >> 4, h = tid & 15;
            int eid = csr[ce + ei];
            alpha_s[ei][h] = alpha[(size_t)eid * 16 + h];
            if (h == 0) src_s[ei] = srcidx[eid];
        }
        __syncthreads();
        for (int ei = 0; ei < nc; ++ei) {
            float a = alpha_s[ei][hsel];
            float2 v = *(const float2*)(zs + (size_t)src_s[ei] * 512 + tid * 2);
            acc0 += a * v.x;
            acc1 += a * v.y;
        }
        __syncthreads();
    }

    lds_out[tid * 2] = fmaxf(acc0 + bias[tid * 2], 0.f);
    lds_out[tid * 2 + 1] = fmaxf(acc1 + bias[tid * 2 + 1], 0.f);
    __syncthreads();
    if (tid < 32) {
        float s = 0.f;
#pragma unroll
        for (int hh = 0; hh < 16; ++hh) s += lds_out[hh * 32 + tid];
        hrow[tid] = s * (1.f / 16.f);
    }
    __syncthreads();
    if (tid < 32) {
        float t = pbt[0];
#pragma unroll
        for (int c = 0; c < 32; ++c) t += hrow[c] * pwt[c];
        out[(size_t)d * 32 + tid] = hrow[tid] * expf(t);
    }
}

// ---------------- final MLP on label edges ----------------
__global__ __launch_bounds__(256) void mlp_kernel(
    const float* __restrict__ hd, const float* __restrict__ hl,
    const int* __restrict__ ls, const int* __restrict__ ld,
    const float* __restrict__ w1, const float* __restrict__ b1,
    const float* __restrict__ w2, const float* __restrict__ b2,
    float* __restrict__ out, int M)
{
    __shared__ float w1s[64 * 64];
    __shared__ float b1s[64];
    __shared__ float w2s[64];
    int tid = threadIdx.x;
#pragma unroll
    for (int i = 0; i < 16; ++i) w1s[tid + i * 256] = w1[tid + i * 256];
    if (tid < 64) { b1s[tid] = b1[tid]; w2s[tid] = w2[tid]; }
    __syncthreads();
    int m = blockIdx.x * 256 + tid;
    if (m >= M) return;
    float f[64];
    const float* hp = hd + (size_t)ls[m] * 32;
    const float* lp = hl + (size_t)ld[m] * 32;
#pragma unroll
    for (int c = 0; c < 32; ++c) { f[c] = hp[c]; f[32 + c] = lp[c]; }
    float o = b2[0];
    for (int j = 0; j < 64; ++j) {
        float hj = b1s[j];
#pragma unroll
        for (int k = 0; k < 64; ++k) hj += f[k] * w1s[k * 64 + j];
        hj = fmaxf(hj, 0.f);
        o += hj * w2s[j];
    }
    out[m] = o;
}

extern "C" void kernel_launch(void* const* d_in, const int* in_sizes, int n_in,
                              void* d_out, int out_size, void* d_ws, size_t ws_size,
                              hipStream_t stream)
{
    const float* x_d = (const float*)d_in[0];
    const float* x_l = (const float*)d_in[1];
    const int* node_id_d = (const int*)d_in[2];
    const int* node_id_l = (const int*)d_in[3];
    const int* edge_src = (const int*)d_in[4];
    const int* edge_dst = (const int*)d_in[5];
    const int* label_src = (const int*)d_in[6];
    const int* label_dst = (const int*)d_in[7];
    const float* emb_d = (const float*)d_in[8];
    const float* emb_l = (const float*)d_in[9];
    const float* lin_dw = (const float*)d_in[10];
    const float* lin_db = (const float*)d_in[11];
    const float* lin_lw = (const float*)d_in[12];
    const float* lin_lb = (const float*)d_in[13];
    const float* Ws[3] = {(const float*)d_in[14], (const float*)d_in[19], (const float*)d_in[24]};
    const float* Wd[3] = {(const float*)d_in[15], (const float*)d_in[20], (const float*)d_in[25]};
    const float* as_[3] = {(const float*)d_in[16], (const float*)d_in[21], (const float*)d_in[26]};
    const float* ad_[3] = {(const float*)d_in[17], (const float*)d_in[22], (const float*)d_in[27]};
    const float* bb[3] = {(const float*)d_in[18], (const float*)d_in[23], (const float*)d_in[28]};
    const float* pw = (const float*)d_in[29];
    const float* pb = (const float*)d_in[30];
    const float* fc1w = (const float*)d_in[31];
    const float* fc1b = (const float*)d_in[32];
    const float* fc2w = (const float*)d_in[33];
    const float* fc2b = (const float*)d_in[34];

    char* wsb = (char*)d_ws;
    size_t woff = 0;
    auto carve = [&](size_t bytes) -> void* {
        woff = (woff + 255) & ~(size_t)255;
        void* p = wsb + woff;
        woff += bytes;
        return p;
    };
    float* hdA = (float*)carve((size_t)ND * 128 * 4);
    float* hlA = (float*)carve((size_t)NL * 128 * 4);
    float* hdB = (float*)carve((size_t)ND * 128 * 4);
    float* hlB = (float*)carve((size_t)NL * 128 * 4);
    unsigned int* haggP = (unsigned int*)carve((size_t)NL * 2048 * 4);  // L3 reuses as zs3d/zs3l
    unsigned short* WtH = (unsigned short*)carve((size_t)2 * 2 * 2048 * 128 * 2);
    unsigned short* WtL = (unsigned short*)carve((size_t)2 * 2 * 2048 * 128 * 2);
    float* ssb0 = (float*)carve((size_t)ND * 16 * 4);
    float* sdb0 = (float*)carve((size_t)NL * 16 * 4);
    float* ssb1 = (float*)carve((size_t)NL * 16 * 4);
    float* sdb1 = (float*)carve((size_t)ND * 16 * 4);
    float* al0 = (float*)carve((size_t)NE * 16 * 4);
    float* al1 = (float*)carve((size_t)NE * 16 * 4);
    float* msl = (float*)carve((size_t)NL * 32 * 4);
    float* msd = (float*)carve((size_t)ND * 32 * 4);
    float* fw3 = (float*)carve((size_t)3 * 4 * 2048 * 4);
    int* degl = (int*)carve((size_t)(2 * (NL + ND)) * 4);
    int* degd = degl + NL;
    int* curl = degd + ND;
    int* curd = curl + NL;
    int* offl = (int*)carve((size_t)(NL + 1) * 4);
    int* offd = (int*)carve((size_t)(ND + 1) * 4);
    int* csrl = (int*)carve((size_t)NE * 4);
    int* csrd = (int*)carve((size_t)NE * 4);
    float* hdp = (float*)carve((size_t)ND * 32 * 4);
    float* hlp = (float*)carve((size_t)NL * 32 * 4);

    hipMemsetAsync(degl, 0, (size_t)2 * (NL + ND) * 4, stream);

    hist_kernel<<<(NE + 255) / 256, 256, 0, stream>>>(edge_src, edge_dst, degl, degd);
    scan2_kernel<<<2, 1024, 0, stream>>>(degl, offl, NL, degd, offd, ND);
    scatter_kernel<<<(NE + 255) / 256, 256, 0, stream>>>(edge_src, edge_dst, offl, offd, curl, curd, csrl, csrd);

    fold3_kernel<<<(3 * 8192 + 255) / 256, 256, 0, stream>>>(
        Ws[0], Wd[0], as_[0], ad_[0], Ws[1], Wd[1], as_[1], ad_[1],
        Ws[2], Wd[2], as_[2], ad_[2], fw3);
    wt2_kernel<<<(2 * 524288 + 255) / 256, 256, 0, stream>>>(Ws[0], Ws[1], WtH, WtL);

    inlin_kernel<<<dim3(2, 750), 256, 0, stream>>>(
        x_d, x_l, lin_dw, lin_lw, lin_db, lin_lb, emb_d, emb_l,
        node_id_d, node_id_l, hdA, hlA);

    float* hd_cur = hdA; float* hd_nxt = hdB;
    float* hl_cur = hlA; float* hl_nxt = hlB;

    const int grid_e16 = (NE * 16 + 255) / 256;
    const int grid_ms = ((NL + ND) * 16 + 255) / 256;
    // XCD-swizzled gemm2r grids: 32 blocks per group of 8 m-tiles
    const int gridNL = ((NL / 64 + 7) / 8) * 32;   // 250 tiles -> 1024 blocks
    const int gridND = ((ND / 64 + 7) / 8) * 32;   // 125 tiles -> 512 blocks

    // ---- layers 1-2: aggregate-then-project (split-bf16 MFMA, fused head-mean) ----
    for (int L = 0; L < 2; ++L) {
        const float* fw = fw3 + (size_t)L * 8192;
        const unsigned short* wtH = WtH + (size_t)L * 524288;
        const unsigned short* wtL = WtL + (size_t)L * 524288;

        score2both_kernel<<<ND / 16 + NL / 16, 256, 0, stream>>>(
            hd_cur, hl_cur, fw, ssb0, sdb1, sdb0, ssb1);
        ale_kernel<<<grid_e16, 256, 0, stream>>>(edge_src, edge_dst, ssb0, sdb0, ssb1, sdb1, al0, al1);
        ms_kernel<<<grid_ms, 256, 0, stream>>>(offl, csrl, al0, msl, offd, csrd, al1, msd);
        alphaw_kernel<<<grid_e16, 256, 0, stream>>>(edge_src, edge_dst, msl, msd, al0, al1);

        // edge type 0: disease -> lncrna (dst = lncrna)
        hagg_kernel<<<NL / 2, 256, 0, stream>>>(hd_cur, al0, offl, csrl, edge_src, haggP);
        gemm2r_kernel<<<gridNL, 256, 0, stream>>>(haggP, wtH, wtL, bb[L], hl_nxt, NL);

        // edge type 1: lncrna -> disease (dst = disease)
        hagg_kernel<<<ND / 2, 256, 0, stream>>>(hl_cur, al1, offd, csrd, edge_dst, haggP);
        gemm2r_kernel<<<gridND, 256, 0, stream>>>(haggP,
                                                  wtH + (size_t)2048 * 128, wtL + (size_t)2048 * 128,
                                                  bb[L] + 2048, hd_nxt, ND);

        float* t;
        t = hd_cur; hd_cur = hd_nxt; hd_nxt = t;
        t = hl_cur; hl_cur = hl_nxt; hl_nxt = t;
    }

    // ---- layer 3: project-then-aggregate (fp32), merged dispatches ----
    {
        const float* fw = fw3 + 2 * 8192;
        float* zs3d = (float*)haggP;
        float* zs3l = (float*)haggP + (size_t)ND * 512;
        score2both_kernel<<<ND / 16 + NL / 16, 256, 0, stream>>>(
            hd_cur, hl_cur, fw, ssb0, sdb1, sdb0, ssb1);
        ale_kernel<<<grid_e16, 256, 0, stream>>>(edge_src, edge_dst, ssb0, sdb0, ssb1, sdb1, al0, al1);
        ms_kernel<<<grid_ms, 256, 0, stream>>>(offl, csrl, al0, msl, offd, csrd, al1, msd);
        alphaw_kernel<<<grid_e16, 256, 0, stream>>>(edge_src, edge_dst, msl, msd, al0, al1);

        gemm3_kernel<<<dim3(512 / BN, 125 + 250), 256, 0, stream>>>(
            hd_cur, hl_cur, Ws[2], zs3d, zs3l);

        agg32both_kernel<<<NL + ND, 256, 0, stream>>>(
            zs3d, zs3l, al0, al1,
            offl, csrl, offd, csrd, edge_src, edge_dst,
            bb[2], pw, pb, hlp, hdp);
    }

    mlp_kernel<<<(NM + 255) / 256, 256, 0, stream>>>(hdp, hlp, label_src, label_dst,
                                                     fc1w, fc1b, fc2w, fc2b, (float*)d_out, NM);
}

// Round 17
// 774.598 us; speedup vs baseline: 1.8559x; 1.0643x over previous
//
#include <hip/hip_runtime.h>
#include <cstdint>
#include <cstddef>

#define ND 8000
#define NL 16000
#define NE 60000
#define NM 50000

#define BM 64
#define BN 64
#define BK 16

typedef __attribute__((ext_vector_type(8))) short bf16x8;
typedef __attribute__((ext_vector_type(4))) float f32x4;
typedef __attribute__((ext_vector_type(8))) unsigned int u32x8;

__device__ __forceinline__ unsigned short f2bf(float x) {
    unsigned int u = __float_as_uint(x);
    unsigned int r = (u + 0x7FFFu + ((u >> 16) & 1u)) >> 16;
    return (unsigned short)r;
}
__device__ __forceinline__ float bf2f(unsigned short b) {
    return __uint_as_float(((unsigned int)b) << 16);
}
__device__ __forceinline__ float lrelu(float x) {
    return x >= 0.f ? x : 0.2f * x;
}

// ---------------- merged layer-3 GEMM: zs3d = hd @ W[0], zs3l = hl @ W[1] --------------
__global__ __launch_bounds__(256) void gemm3_kernel(
    const float* __restrict__ hd, const float* __restrict__ hl,
    const float* __restrict__ W,   // [2,128,512]
    float* __restrict__ zs3d, float* __restrict__ zs3l)
{
    __shared__ float As[BK][BM + 4];
    __shared__ float Bs[BK][BN + 4];
    int mt = blockIdx.y;
    const float* A; const float* B; float* Cm;
    if (mt < 125) { A = hd; B = W; Cm = zs3d; }
    else { mt -= 125; A = hl; B = W + 128 * 512; Cm = zs3l; }
    const int tid = threadIdx.x;
    const int tx = tid & 15, ty = tid >> 4;
    const int bm = mt * BM, bn = blockIdx.x * BN;
    float acc[4][4] = {};
    for (int k0 = 0; k0 < 128; k0 += BK) {
#pragma unroll
        for (int i = 0; i < 4; ++i) {
            int idx = tid + i * 256;
            int ml = idx >> 4, kl = idx & 15;
            As[kl][ml] = A[(size_t)(bm + ml) * 128 + k0 + kl];
        }
#pragma unroll
        for (int i = 0; i < 4; ++i) {
            int idx = tid + i * 256;
            int kl = idx >> 6, nl = idx & 63;
            Bs[kl][nl] = B[(size_t)(k0 + kl) * 512 + bn + nl];
        }
        __syncthreads();
#pragma unroll
        for (int k = 0; k < BK; ++k) {
            float4 av = *(const float4*)&As[k][ty * 4];
            float4 bv = *(const float4*)&Bs[k][tx * 4];
            float a4[4] = {av.x, av.y, av.z, av.w};
            float b4[4] = {bv.x, bv.y, bv.z, bv.w};
#pragma unroll
            for (int i = 0; i < 4; ++i)
#pragma unroll
                for (int j = 0; j < 4; ++j)
                    acc[i][j] += a4[i] * b4[j];
        }
        __syncthreads();
    }
#pragma unroll
    for (int i = 0; i < 4; ++i) {
        int gm = bm + ty * 4 + i;
        int gn0 = bn + tx * 4;
        float4 v;
        float* vp = &v.x;
#pragma unroll
        for (int j = 0; j < 4; ++j) vp[j] = acc[i][j];
        *(float4*)&Cm[(size_t)gm * 512 + gn0] = v;
    }
}

// ---------------- fused input linears, 32-row tiles, register double-buffer ------------
__global__ __launch_bounds__(256) void inlin_kernel(
    const float* __restrict__ x_d, const float* __restrict__ x_l,
    const float* __restrict__ wd, const float* __restrict__ wl,
    const float* __restrict__ bd, const float* __restrict__ bl,
    const float* __restrict__ embd, const float* __restrict__ embl,
    const int* __restrict__ nidd, const int* __restrict__ nidl,
    float* __restrict__ hd, float* __restrict__ hl)
{
    __shared__ float As[BK][32 + 4];
    __shared__ float Bs[BK][BN + 4];
    int mt = blockIdx.y;
    const float* A; const float* B; const float* bias; const float* emb;
    const int* nid; float* out;
    int K;
    if (mt < 250) {
        A = x_d; B = wd; bias = bd; emb = embd; nid = nidd; out = hd; K = 412;
    } else {
        mt -= 250;
        A = x_l; B = wl; bias = bl; emb = embl; nid = nidl; out = hl; K = 240;
    }
    const int tid = threadIdx.x;
    const int tx = tid & 15, ty = tid >> 4;
    const int bm = mt * 32, bn = blockIdx.x * BN;

    // per-thread staging coords
    const int aml0 = tid >> 4, akl0 = tid & 15;           // i=0
    const int aml1 = (tid + 256) >> 4, akl1 = tid & 15;   // i=1
    const int bkl = tid >> 6, bnl = tid & 63;             // i-th adds 4 to kl

    float pa[2], pb[4];
    // prefetch k0 = 0
    {
        int gk0 = akl0, gk1 = akl1;
        pa[0] = (gk0 < K) ? A[(size_t)(bm + aml0) * K + gk0] : 0.f;
        pa[1] = (gk1 < K) ? A[(size_t)(bm + aml1) * K + gk1] : 0.f;
#pragma unroll
        for (int i = 0; i < 4; ++i) {
            int gk = bkl + i * 4;
            pb[i] = (gk < K) ? B[(size_t)gk * 128 + bn + bnl] : 0.f;
        }
    }

    float acc[2][4] = {};
    for (int k0 = 0; k0 < K; k0 += BK) {
        // commit staged regs to LDS
        As[akl0][aml0] = pa[0];
        As[akl1][aml1] = pa[1];
#pragma unroll
        for (int i = 0; i < 4; ++i)
            Bs[bkl + i * 4][bnl] = pb[i];
        __syncthreads();
        // prefetch next tile while computing this one
        int kn = k0 + BK;
        if (kn < K) {
            int gk0 = kn + akl0, gk1 = kn + akl1;
            pa[0] = (gk0 < K) ? A[(size_t)(bm + aml0) * K + gk0] : 0.f;
            pa[1] = (gk1 < K) ? A[(size_t)(bm + aml1) * K + gk1] : 0.f;
#pragma unroll
            for (int i = 0; i < 4; ++i) {
                int gk = kn + bkl + i * 4;
                pb[i] = (gk < K) ? B[(size_t)gk * 128 + bn + bnl] : 0.f;
            }
        }
#pragma unroll
        for (int k = 0; k < BK; ++k) {
            float a0 = As[k][ty * 2];
            float a1 = As[k][ty * 2 + 1];
            float4 bv = *(const float4*)&Bs[k][tx * 4];
            float b4[4] = {bv.x, bv.y, bv.z, bv.w};
#pragma unroll
            for (int j = 0; j < 4; ++j) {
                acc[0][j] += a0 * b4[j];
                acc[1][j] += a1 * b4[j];
            }
        }
        __syncthreads();
    }
#pragma unroll
    for (int i = 0; i < 2; ++i) {
        int gm = bm + ty * 2 + i;
        int gn0 = bn + tx * 4;
        const float* ep = emb + (size_t)nid[gm] * 128 + gn0;
        float4 v;
        float* vp = &v.x;
#pragma unroll
        for (int j = 0; j < 4; ++j)
            vp[j] = acc[i][j] + bias[gn0 + j] + ep[j];
        *(float4*)&out[(size_t)gm * 128 + gn0] = v;
    }
}

// ---------------- W transpose + split-bf16 into MFMA-fragment tiling, BOTH layers ------
__global__ void wt2_kernel(const float* __restrict__ W0, const float* __restrict__ W1,
                           unsigned short* __restrict__ WtH, unsigned short* __restrict__ WtL)
{
    int gid = blockIdx.x * 256 + threadIdx.x;
    if (gid >= 2 * 2 * 128 * 2048) return;
    int l = gid >> 19;
    int rem0 = gid & 524287;
    int dir = rem0 >> 18;
    int rem = rem0 & 262143;
    int k = rem >> 11, n = rem & 2047;
    const float* W = l ? W1 : W0;
    float v = W[(size_t)dir * 262144 + (size_t)k * 2048 + n];
    unsigned short hb = f2bf(v);
    unsigned short lb = f2bf(v - bf2f(hb));
    int u = n >> 4;
    int lane = (n & 15) + 16 * ((k >> 3) & 3);
    size_t o = (size_t)l * 524288 + (size_t)dir * 262144 +
               ((size_t)u * 4 + (k >> 5)) * 512 + lane * 8 + (k & 7);
    WtH[o] = hb;
    WtL[o] = lb;
}

// ---------------- fused per-head projection + bias + relu + HEAD-MEAN (layers 1-2) ----
// XCD-aware swizzle: blocks sharing an m-tile land on the same XCD (i%8 equal).
__global__ __launch_bounds__(256) void gemm2r_kernel(
    const unsigned int* __restrict__ haggP,
    const unsigned short* __restrict__ WtH, const unsigned short* __restrict__ WtL,
    const float* __restrict__ bias, float* __restrict__ out, int M)
{
    const int wave = threadIdx.x >> 6;
    const int lane = threadIdx.x & 63;
    const int i = blockIdx.x;
    const int cb = (i >> 3) & 3;             // column quarter
    const int mt = (i >> 5) * 8 + (i & 7);   // m-tile
    if (mt >= (M >> 6)) return;
    const int m0 = mt * 64 + wave * 16;
    const int t = m0 >> 4;
    const int row = lane & 15;
    const int quad = lane >> 4;

    f32x4 mean[2] = {};

    for (int h = 0; h < 16; ++h) {
        f32x4 accH[2], accL[2];
#pragma unroll
        for (int ctl = 0; ctl < 2; ++ctl) {
            float bv = bias[h * 128 + cb * 32 + ctl * 16 + row];
            accH[ctl] = (f32x4){bv, bv, bv, bv};
            accL[ctl] = (f32x4){0.f, 0.f, 0.f, 0.f};
        }
#pragma unroll
        for (int kc = 0; kc < 4; ++kc) {
            const size_t aoff = (((size_t)t * 16 + h) * 4 + kc) * 512 + lane * 8;
            u32x8 p = *(const u32x8*)(haggP + aoff);
            bf16x8 aH, aL;
#pragma unroll
            for (int ii = 0; ii < 8; ++ii) {
                aH[ii] = (short)(p[ii] & 0xffffu);
                aL[ii] = (short)(p[ii] >> 16);
            }
#pragma unroll
            for (int ctl = 0; ctl < 2; ++ctl) {
                const int u = h * 8 + cb * 2 + ctl;
                const size_t boff = ((size_t)u * 4 + kc) * 512 + lane * 8;
                bf16x8 bH = *(const bf16x8*)(WtH + boff);
                bf16x8 bL = *(const bf16x8*)(WtL + boff);
                accH[ctl] = __builtin_amdgcn_mfma_f32_16x16x32_bf16(aH, bH, accH[ctl], 0, 0, 0);
                accL[ctl] = __builtin_amdgcn_mfma_f32_16x16x32_bf16(aH, bL, accL[ctl], 0, 0, 0);
                accL[ctl] = __builtin_amdgcn_mfma_f32_16x16x32_bf16(aL, bH, accL[ctl], 0, 0, 0);
            }
        }
#pragma unroll
        for (int ctl = 0; ctl < 2; ++ctl)
#pragma unroll
            for (int r = 0; r < 4; ++r)
                mean[ctl][r] += fmaxf(accH[ctl][r] + accL[ctl][r], 0.f);
    }

#pragma unroll
    for (int ctl = 0; ctl < 2; ++ctl) {
        int c = cb * 32 + ctl * 16 + row;
#pragma unroll
        for (int r = 0; r < 4; ++r) {
            int gm = m0 + quad * 4 + r;
            out[(size_t)gm * 128 + c] = mean[ctl][r] * (1.f / 16.f);
        }
    }
}

// ---------------- fold for ALL 3 layers ------------------------------------------------
__global__ void fold3_kernel(
    const float* __restrict__ Ws1, const float* __restrict__ Wd1,
    const float* __restrict__ as1, const float* __restrict__ ad1,
    const float* __restrict__ Ws2, const float* __restrict__ Wd2,
    const float* __restrict__ as2, const float* __restrict__ ad2,
    const float* __restrict__ Ws3, const float* __restrict__ Wd3,
    const float* __restrict__ as3, const float* __restrict__ ad3,
    float* __restrict__ fw3)
{
    int gid = blockIdx.x * blockDim.x + threadIdx.x;
    if (gid >= 3 * 4 * 128 * 16) return;
    int l = gid / 8192, rem1 = gid % 8192;
    int f = rem1 / 2048, rem = rem1 % 2048;
    int k = rem >> 4, h = rem & 15;
    int Ntot = (l == 2) ? 512 : 2048;
    int C = Ntot >> 4;
    const float* W;
    const float* a;
    if (l == 0) { W = (f & 1) ? Wd1 : Ws1; a = (f & 1) ? ad1 : as1; }
    else if (l == 1) { W = (f & 1) ? Wd2 : Ws2; a = (f & 1) ? ad2 : as2; }
    else { W = (f & 1) ? Wd3 : Ws3; a = (f & 1) ? ad3 : as3; }
    if (f >= 2) { W += 128 * Ntot; a += 16 * C; }
    float s = 0.f;
    for (int c = 0; c < C; ++c) s += W[(size_t)k * Ntot + h * C + c] * a[h * C + c];
    fw3[gid] = s;
}

// ---------------- score2both: all four folded scores of a layer ------------------------
__global__ __launch_bounds__(256) void score2both_kernel(
    const float* __restrict__ Hd, const float* __restrict__ Hl,
    const float* __restrict__ fw,
    float* __restrict__ ssb0, float* __restrict__ sdb1,
    float* __restrict__ sdb0, float* __restrict__ ssb1)
{
    __shared__ float hs[16 * 128];
    __shared__ float wa[128 * 16];
    __shared__ float wb[128 * 16];
    int b = blockIdx.x;
    const float* Hf; const float* WfA; const float* WfB;
    float* outA; float* outB; int n0;
    if (b < ND / 16) {
        Hf = Hd; WfA = fw; WfB = fw + 3 * 2048; outA = ssb0; outB = sdb1; n0 = b * 16;
    } else {
        Hf = Hl; WfA = fw + 1 * 2048; WfB = fw + 2 * 2048; outA = sdb0; outB = ssb1;
        n0 = (b - ND / 16) * 16;
    }
    int tid = threadIdx.x;
#pragma unroll
    for (int i = 0; i < 8; ++i) {
        int idx = tid + i * 256;
        int nl = idx >> 7, k = idx & 127;
        hs[idx] = Hf[(size_t)(n0 + nl) * 128 + k];
        wa[idx] = WfA[idx];
        wb[idx] = WfB[idx];
    }
    __syncthreads();
    int nl = tid >> 4, h = tid & 15;
    float sa = 0.f, sb = 0.f;
    for (int k = 0; k < 128; ++k) {
        float hv = hs[nl * 128 + k];
        sa += hv * wa[k * 16 + h];
        sb += hv * wb[k * 16 + h];
    }
    int gn = n0 + nl;
    outA[gn * 16 + h] = sa;
    outB[gn * 16 + h] = sb;
}

// ---------------- per-(dst,head) online softmax max/sum, logits recomputed inline ------
// ms layout: [d*32 + h] = m, [d*32 + 16 + h] = s
__global__ void ms_kernel(
    const int* __restrict__ esrc, const int* __restrict__ edst,
    const float* __restrict__ ssb0, const float* __restrict__ sdb0,
    const float* __restrict__ ssb1, const float* __restrict__ sdb1,
    const int* __restrict__ offl, const int* __restrict__ csrl, float* __restrict__ msl,
    const int* __restrict__ offd, const int* __restrict__ csrd, float* __restrict__ msd)
{
    int t = blockIdx.x * 256 + threadIdx.x;
    const int* off; const int* csr; const int* srcidx;
    const float* ss; float sdv; float* ms; int d, h;
    if (t < NL * 16) {
        d = t >> 4; h = t & 15;
        off = offl; csr = csrl; srcidx = esrc; ss = ssb0;
        sdv = sdb0[d * 16 + h]; ms = msl;
    } else {
        t -= NL * 16;
        if (t >= ND * 16) return;
        d = t >> 4; h = t & 15;
        off = offd; csr = csrd; srcidx = edst; ss = ssb1;
        sdv = sdb1[d * 16 + h]; ms = msd;
    }
    int e0 = off[d], e1 = off[d + 1];
    float m = -1e30f, s = 0.f;
    for (int e = e0; e < e1; ++e) {
        int sn = srcidx[csr[e]];
        float a = lrelu(ss[sn * 16 + h] + sdv);
        if (a > m) { s = s * __expf(m - a) + 1.f; m = a; }
        else s += __expf(a - m);
    }
    ms[d * 32 + h] = m;
    ms[d * 32 + 16 + h] = s + 1e-16f;
}

// ---------------- edge-parallel alpha, logits recomputed inline ------------------------
__global__ void alphaw_kernel(
    const int* __restrict__ esrc, const int* __restrict__ edst,
    const float* __restrict__ ssb0, const float* __restrict__ sdb0,
    const float* __restrict__ ssb1, const float* __restrict__ sdb1,
    const float* __restrict__ msl, const float* __restrict__ msd,
    float* __restrict__ al0, float* __restrict__ al1)
{
    int t = blockIdx.x * 256 + threadIdx.x;
    if (t >= NE * 16) return;
    int e = t >> 4, h = t & 15;
    int s = esrc[e], d = edst[e];
    float a0 = lrelu(ssb0[s * 16 + h] + sdb0[d * 16 + h]);
    al0[t] = __expf(a0 - msl[d * 32 + h]) / msl[d * 32 + 16 + h];
    float a1 = lrelu(ssb1[d * 16 + h] + sdb1[s * 16 + h]);
    al1[t] = __expf(a1 - msd[s * 32 + h]) / msd[s * 32 + 16 + h];
}

// ---------------- CSR build ----------------
__global__ void hist_kernel(const int* __restrict__ esrc, const int* __restrict__ edst,
                            int* __restrict__ degl, int* __restrict__ degd)
{
    int e = blockIdx.x * blockDim.x + threadIdx.x;
    if (e >= NE) return;
    atomicAdd(&degl[edst[e]], 1);
    atomicAdd(&degd[esrc[e]], 1);
}

__global__ __launch_bounds__(1024) void scan2_kernel(
    const int* __restrict__ degA, int* __restrict__ offA, int nA,
    const int* __restrict__ degB, int* __restrict__ offB, int nB)
{
    __shared__ int ps[1024];
    const int* deg = blockIdx.x ? degB : degA;
    int* off = blockIdx.x ? offB : offA;
    int n = blockIdx.x ? nB : nA;
    int tid = threadIdx.x;
    int chunk = (n + 1023) >> 10;
    int start = tid * chunk, end = min(start + chunk, n);
    int p = 0;
    for (int i = start; i < end; ++i) p += deg[i];
    ps[tid] = p;
    __syncthreads();
    for (int o = 1; o < 1024; o <<= 1) {
        int v = (tid >= o) ? ps[tid - o] : 0;
        __syncthreads();
        ps[tid] += v;
        __syncthreads();
    }
    int run = ps[tid] - p;
    for (int i = start; i < end; ++i) { off[i] = run; run += deg[i]; }
    if (tid == 1023) off[n] = ps[1023];
}

__global__ void scatter_kernel(const int* __restrict__ esrc, const int* __restrict__ edst,
                               const int* __restrict__ offl, const int* __restrict__ offd,
                               int* __restrict__ curl, int* __restrict__ curd,
                               int* __restrict__ csrl, int* __restrict__ csrd)
{
    int e = blockIdx.x * blockDim.x + threadIdx.x;
    if (e >= NE) return;
    int dl = edst[e]; int p = atomicAdd(&curl[dl], 1); csrl[offl[dl] + p] = e;
    int dd = esrc[e]; int q = atomicAdd(&curd[dd], 1); csrd[offd[dd] + q] = e;
}

// ---------------- fused per-head aggregation -> packed fragment-tiled hagg -------------
__global__ __launch_bounds__(256) void hagg_kernel(
    const float* __restrict__ hsrc,   // [n_src, 128]
    const float* __restrict__ alpha,  // [NE, 16]
    const int* __restrict__ off, const int* __restrict__ csr, const int* __restrict__ srcidx,
    unsigned int* __restrict__ haggP)
{
    __shared__ float alpha_s[2][8][17];
    __shared__ int src_s[2][8];
    const int d0 = blockIdx.x * 2;
    const int tid = threadIdx.x;

    const int half = tid >> 7;
    const int c = tid & 127;
    const int d = d0 + half;
    const int my_e0 = off[d];
    const int my_deg = off[d + 1] - my_e0;
    const int deg0 = off[d0 + 1] - off[d0];
    const int deg1 = off[d0 + 2] - off[d0 + 1];
    const int degmax = deg0 > deg1 ? deg0 : deg1;
    const int ntrip = (degmax + 7) >> 3;

    float acc[16];
#pragma unroll
    for (int h = 0; h < 16; ++h) acc[h] = 0.f;

    for (int trip = 0; trip < ntrip; ++trip) {
        int ce = trip * 8;
        {
            int ei = c >> 4, h = c & 15;
            if (ce + ei < my_deg) {
                int eid = csr[my_e0 + ce + ei];
                alpha_s[half][ei][h] = alpha[(size_t)eid * 16 + h];
                if (h == 0) src_s[half][ei] = srcidx[eid];
            }
        }
        __syncthreads();
        int nc = min(8, my_deg - ce);
        for (int ei = 0; ei < nc; ++ei) {
            float v = hsrc[(size_t)src_s[half][ei] * 128 + c];
#pragma unroll
            for (int h = 0; h < 16; ++h)
                acc[h] += alpha_s[half][ei][h] * v;
        }
        __syncthreads();
    }

    const int t = d >> 4;
    const int lane8 = ((d & 15) + 16 * ((c >> 3) & 3)) * 8 + (c & 7);
    const int kc = c >> 5;
#pragma unroll
    for (int h = 0; h < 16; ++h) {
        float v = acc[h];
        unsigned short hb = f2bf(v);
        unsigned short lb = f2bf(v - bf2f(hb));
        size_t idx = (((size_t)t * 16 + h) * 4 + kc) * 512 + lane8;
        haggP[idx] = (unsigned int)hb | ((unsigned int)lb << 16);
    }
}

// ---------------- layer 3 merged: gather + bias + relu + mean + penalty ----------------
__global__ __launch_bounds__(256) void agg32both_kernel(
    const float* __restrict__ zs3d, const float* __restrict__ zs3l,
    const float* __restrict__ alpha0, const float* __restrict__ alpha1,
    const int* __restrict__ offl, const int* __restrict__ csrl,
    const int* __restrict__ offd, const int* __restrict__ csrd,
    const int* __restrict__ esrc, const int* __restrict__ edst,
    const float* __restrict__ bias512,
    const float* __restrict__ pw, const float* __restrict__ pb,
    float* __restrict__ hlp, float* __restrict__ hdp)
{
    __shared__ float alpha_s[16][17];
    __shared__ int src_s[16];
    __shared__ float lds_out[512];
    __shared__ float hrow[32];
    int d = blockIdx.x;
    const float* zs; const float* alpha;
    const int* off; const int* csr; const int* srcidx;
    const float* bias; const float* pwt; const float* pbt; float* out;
    if (d < NL) {
        zs = zs3d; alpha = alpha0; off = offl; csr = csrl; srcidx = esrc;
        bias = bias512; pwt = pw + 32; pbt = pb + 1; out = hlp;
    } else {
        d -= NL;
        zs = zs3l; alpha = alpha1; off = offd; csr = csrd; srcidx = edst;
        bias = bias512 + 512; pwt = pw; pbt = pb; out = hdp;
    }
    const int tid = threadIdx.x;
    const int e0 = off[d], e1 = off[d + 1];

    float acc0 = 0.f, acc1 = 0.f;
    const int hsel = tid >> 4;

    for (int ce = e0; ce < e1; ce += 16) {
        int nc = min(16, e1 - ce);
        if (tid < nc * 16) {
            int ei = tid >> 4, h = tid & 15;
            int eid = csr[ce + ei];
            alpha_s[ei][h] = alpha[(size_t)eid * 16 + h];
            if (h == 0) src_s[ei] = srcidx[eid];
        }
        __syncthreads();
        for (int ei = 0; ei < nc; ++ei) {
            float a = alpha_s[ei][hsel];
            float2 v = *(const float2*)(zs + (size_t)src_s[ei] * 512 + tid * 2);
            acc0 += a * v.x;
            acc1 += a * v.y;
        }
        __syncthreads();
    }

    lds_out[tid * 2] = fmaxf(acc0 + bias[tid * 2], 0.f);
    lds_out[tid * 2 + 1] = fmaxf(acc1 + bias[tid * 2 + 1], 0.f);
    __syncthreads();
    if (tid < 32) {
        float s = 0.f;
#pragma unroll
        for (int hh = 0; hh < 16; ++hh) s += lds_out[hh * 32 + tid];
        hrow[tid] = s * (1.f / 16.f);
    }
    __syncthreads();
    if (tid < 32) {
        float t = pbt[0];
#pragma unroll
        for (int c = 0; c < 32; ++c) t += hrow[c] * pwt[c];
        out[(size_t)d * 32 + tid] = hrow[tid] * expf(t);
    }
}

// ---------------- final MLP on label edges ----------------
__global__ __launch_bounds__(256) void mlp_kernel(
    const float* __restrict__ hd, const float* __restrict__ hl,
    const int* __restrict__ ls, const int* __restrict__ ld,
    const float* __restrict__ w1, const float* __restrict__ b1,
    const float* __restrict__ w2, const float* __restrict__ b2,
    float* __restrict__ out, int M)
{
    __shared__ float w1s[64 * 64];
    __shared__ float b1s[64];
    __shared__ float w2s[64];
    int tid = threadIdx.x;
#pragma unroll
    for (int i = 0; i < 16; ++i) w1s[tid + i * 256] = w1[tid + i * 256];
    if (tid < 64) { b1s[tid] = b1[tid]; w2s[tid] = w2[tid]; }
    __syncthreads();
    int m = blockIdx.x * 256 + tid;
    if (m >= M) return;
    float f[64];
    const float* hp = hd + (size_t)ls[m] * 32;
    const float* lp = hl + (size_t)ld[m] * 32;
#pragma unroll
    for (int c = 0; c < 32; ++c) { f[c] = hp[c]; f[32 + c] = lp[c]; }
    float o = b2[0];
    for (int j = 0; j < 64; ++j) {
        float hj = b1s[j];
#pragma unroll
        for (int k = 0; k < 64; ++k) hj += f[k] * w1s[k * 64 + j];
        hj = fmaxf(hj, 0.f);
        o += hj * w2s[j];
    }
    out[m] = o;
}

extern "C" void kernel_launch(void* const* d_in, const int* in_sizes, int n_in,
                              void* d_out, int out_size, void* d_ws, size_t ws_size,
                              hipStream_t stream)
{
    const float* x_d = (const float*)d_in[0];
    const float* x_l = (const float*)d_in[1];
    const int* node_id_d = (const int*)d_in[2];
    const int* node_id_l = (const int*)d_in[3];
    const int* edge_src = (const int*)d_in[4];
    const int* edge_dst = (const int*)d_in[5];
    const int* label_src = (const int*)d_in[6];
    const int* label_dst = (const int*)d_in[7];
    const float* emb_d = (const float*)d_in[8];
    const float* emb_l = (const float*)d_in[9];
    const float* lin_dw = (const float*)d_in[10];
    const float* lin_db = (const float*)d_in[11];
    const float* lin_lw = (const float*)d_in[12];
    const float* lin_lb = (const float*)d_in[13];
    const float* Ws[3] = {(const float*)d_in[14], (const float*)d_in[19], (const float*)d_in[24]};
    const float* Wd[3] = {(const float*)d_in[15], (const float*)d_in[20], (const float*)d_in[25]};
    const float* as_[3] = {(const float*)d_in[16], (const float*)d_in[21], (const float*)d_in[26]};
    const float* ad_[3] = {(const float*)d_in[17], (const float*)d_in[22], (const float*)d_in[27]};
    const float* bb[3] = {(const float*)d_in[18], (const float*)d_in[23], (const float*)d_in[28]};
    const float* pw = (const float*)d_in[29];
    const float* pb = (const float*)d_in[30];
    const float* fc1w = (const float*)d_in[31];
    const float* fc1b = (const float*)d_in[32];
    const float* fc2w = (const float*)d_in[33];
    const float* fc2b = (const float*)d_in[34];

    char* wsb = (char*)d_ws;
    size_t woff = 0;
    auto carve = [&](size_t bytes) -> void* {
        woff = (woff + 255) & ~(size_t)255;
        void* p = wsb + woff;
        woff += bytes;
        return p;
    };
    float* hdA = (float*)carve((size_t)ND * 128 * 4);
    float* hlA = (float*)carve((size_t)NL * 128 * 4);
    float* hdB = (float*)carve((size_t)ND * 128 * 4);
    float* hlB = (float*)carve((size_t)NL * 128 * 4);
    unsigned int* haggP = (unsigned int*)carve((size_t)NL * 2048 * 4);  // L3 reuses as zs3d/zs3l
    unsigned short* WtH = (unsigned short*)carve((size_t)2 * 2 * 2048 * 128 * 2);
    unsigned short* WtL = (unsigned short*)carve((size_t)2 * 2 * 2048 * 128 * 2);
    float* ssb0 = (float*)carve((size_t)ND * 16 * 4);
    float* sdb0 = (float*)carve((size_t)NL * 16 * 4);
    float* ssb1 = (float*)carve((size_t)NL * 16 * 4);
    float* sdb1 = (float*)carve((size_t)ND * 16 * 4);
    float* al0 = (float*)carve((size_t)NE * 16 * 4);
    float* al1 = (float*)carve((size_t)NE * 16 * 4);
    float* msl = (float*)carve((size_t)NL * 32 * 4);
    float* msd = (float*)carve((size_t)ND * 32 * 4);
    float* fw3 = (float*)carve((size_t)3 * 4 * 2048 * 4);
    int* degl = (int*)carve((size_t)(2 * (NL + ND)) * 4);
    int* degd = degl + NL;
    int* curl = degd + ND;
    int* curd = curl + NL;
    int* offl = (int*)carve((size_t)(NL + 1) * 4);
    int* offd = (int*)carve((size_t)(ND + 1) * 4);
    int* csrl = (int*)carve((size_t)NE * 4);
    int* csrd = (int*)carve((size_t)NE * 4);
    float* hdp = (float*)carve((size_t)ND * 32 * 4);
    float* hlp = (float*)carve((size_t)NL * 32 * 4);

    hipMemsetAsync(degl, 0, (size_t)2 * (NL + ND) * 4, stream);

    hist_kernel<<<(NE + 255) / 256, 256, 0, stream>>>(edge_src, edge_dst, degl, degd);
    scan2_kernel<<<2, 1024, 0, stream>>>(degl, offl, NL, degd, offd, ND);
    scatter_kernel<<<(NE + 255) / 256, 256, 0, stream>>>(edge_src, edge_dst, offl, offd, curl, curd, csrl, csrd);

    fold3_kernel<<<(3 * 8192 + 255) / 256, 256, 0, stream>>>(
        Ws[0], Wd[0], as_[0], ad_[0], Ws[1], Wd[1], as_[1], ad_[1],
        Ws[2], Wd[2], as_[2], ad_[2], fw3);
    wt2_kernel<<<(2 * 524288 + 255) / 256, 256, 0, stream>>>(Ws[0], Ws[1], WtH, WtL);

    inlin_kernel<<<dim3(2, 750), 256, 0, stream>>>(
        x_d, x_l, lin_dw, lin_lw, lin_db, lin_lb, emb_d, emb_l,
        node_id_d, node_id_l, hdA, hlA);

    float* hd_cur = hdA; float* hd_nxt = hdB;
    float* hl_cur = hlA; float* hl_nxt = hlB;

    const int grid_e16 = (NE * 16 + 255) / 256;
    const int grid_ms = ((NL + ND) * 16 + 255) / 256;
    const int gridNL = ((NL / 64 + 7) / 8) * 32;
    const int gridND = ((ND / 64 + 7) / 8) * 32;

    // ---- layers 1-2: aggregate-then-project (split-bf16 MFMA, fused head-mean) ----
    for (int L = 0; L < 2; ++L) {
        const float* fw = fw3 + (size_t)L * 8192;
        const unsigned short* wtH = WtH + (size_t)L * 524288;
        const unsigned short* wtL = WtL + (size_t)L * 524288;

        score2both_kernel<<<ND / 16 + NL / 16, 256, 0, stream>>>(
            hd_cur, hl_cur, fw, ssb0, sdb1, sdb0, ssb1);
        ms_kernel<<<grid_ms, 256, 0, stream>>>(edge_src, edge_dst, ssb0, sdb0, ssb1, sdb1,
                                               offl, csrl, msl, offd, csrd, msd);
        alphaw_kernel<<<grid_e16, 256, 0, stream>>>(edge_src, edge_dst, ssb0, sdb0, ssb1, sdb1,
                                                    msl, msd, al0, al1);

        // edge type 0: disease -> lncrna (dst = lncrna)
        hagg_kernel<<<NL / 2, 256, 0, stream>>>(hd_cur, al0, offl, csrl, edge_src, haggP);
        gemm2r_kernel<<<gridNL, 256, 0, stream>>>(haggP, wtH, wtL, bb[L], hl_nxt, NL);

        // edge type 1: lncrna -> disease (dst = disease)
        hagg_kernel<<<ND / 2, 256, 0, stream>>>(hl_cur, al1, offd, csrd, edge_dst, haggP);
        gemm2r_kernel<<<gridND, 256, 0, stream>>>(haggP,
                                                  wtH + (size_t)2048 * 128, wtL + (size_t)2048 * 128,
                                                  bb[L] + 2048, hd_nxt, ND);

        float* t;
        t = hd_cur; hd_cur = hd_nxt; hd_nxt = t;
        t = hl_cur; hl_cur = hl_nxt; hl_nxt = t;
    }

    // ---- layer 3: project-then-aggregate (fp32), merged dispatches ----
    {
        const float* fw = fw3 + 2 * 8192;
        float* zs3d = (float*)haggP;
        float* zs3l = (float*)haggP + (size_t)ND * 512;
        score2both_kernel<<<ND / 16 + NL / 16, 256, 0, stream>>>(
            hd_cur, hl_cur, fw, ssb0, sdb1, sdb0, ssb1);
        ms_kernel<<<grid_ms, 256, 0, stream>>>(edge_src, edge_dst, ssb0, sdb0, ssb1, sdb1,
                                               offl, csrl, msl, offd, csrd, msd);
        alphaw_kernel<<<grid_e16, 256, 0, stream>>>(edge_src, edge_dst, ssb0, sdb0, ssb1, sdb1,
                                                    msl, msd, al0, al1);

        gemm3_kernel<<<dim3(512 / BN, 125 + 250), 256, 0, stream>>>(
            hd_cur, hl_cur, Ws[2], zs3d, zs3l);

        agg32both_kernel<<<NL + ND, 256, 0, stream>>>(
            zs3d, zs3l, al0, al1,
            offl, csrl, offd, csrd, edge_src, edge_dst,
            bb[2], pw, pb, hlp, hdp);
    }

    mlp_kernel<<<(NM + 255) / 256, 256, 0, stream>>>(hdp, hlp, label_src, label_dst,
                                                     fc1w, fc1b, fc2w, fc2b, (float*)d_out, NM);
}